// Round 1
// 1815.593 us; speedup vs baseline: 2.0529x; 2.0529x over previous
//
#include <hip/hip_runtime.h>
#include <hip/hip_bf16.h>
#include <cmath>

#define DEV __device__ __forceinline__

namespace {

constexpr int kB = 8, kN = 4096, kD = 512, kH = 8, kDH = 64, kM = 256, kL = 16, kCK = 33;
constexpr int kBN = kB * kN;     // 32768
constexpr int kBH = kB * kH;     // 64
constexpr int kHD = kH * kDH;    // 512
constexpr int kD4 = 4 * kD;      // 2048
constexpr int kQKVC = 3 * kHD;   // 1536

typedef __attribute__((ext_vector_type(8))) short short8;
typedef __attribute__((ext_vector_type(4))) float f32x4;

DEV float toF(float x) { return x; }
DEV float toF(__hip_bfloat16 x) { return __bfloat162float(x); }
DEV __hip_bfloat16 f2b(float f) { return __float2bfloat16(f); }
DEV short f2s(float f) {
  __hip_bfloat16 h = __float2bfloat16(f);
  return *reinterpret_cast<short*>(&h);
}
DEV float us2f(unsigned short u) { return __uint_as_float((unsigned)u << 16); }
DEV unsigned short f2us(float f) {
  __hip_bfloat16 h = __float2bfloat16(f);
  return *reinterpret_cast<unsigned short*>(&h);
}
DEV float lo16(unsigned u) { return __uint_as_float(u << 16); }
DEV float hi16(unsigned u) { return __uint_as_float(u & 0xffff0000u); }

DEV float waveSum(float v) {
#pragma unroll
  for (int o = 32; o > 0; o >>= 1) v += __shfl_down(v, o, 64);
  return v;
}
DEV float waveMax(float v) {
#pragma unroll
  for (int o = 32; o > 0; o >>= 1) v = fmaxf(v, __shfl_down(v, o, 64));
  return v;
}
DEV float blockSum(float v, float* sb) {
  v = waveSum(v);
  int lane = threadIdx.x & 63, w = threadIdx.x >> 6;
  __syncthreads();
  if (lane == 0) sb[w] = v;
  __syncthreads();
  return sb[0] + sb[1] + sb[2] + sb[3];
}
DEV float blockMax(float v, float* sb) {
  v = waveMax(v);
  int lane = threadIdx.x & 63, w = threadIdx.x >> 6;
  __syncthreads();
  if (lane == 0) sb[w] = v;
  __syncthreads();
  return fmaxf(fmaxf(sb[0], sb[1]), fmaxf(sb[2], sb[3]));
}

// ---------------- runtime dtype detection ----------------
__global__ __launch_bounds__(256) void detect_k(const unsigned* __restrict__ x,
                                                int* __restrict__ flag) {
  __shared__ int sc[4];
  int t = threadIdx.x;
  int cb = 0;
  for (int i = t; i < 4096; i += 256) {
    unsigned w = x[i];
    float b0 = __uint_as_float(w << 16);
    float b1 = __uint_as_float(w & 0xffff0000u);
    if (fabsf(b0) < 64.0f && (b0 == 0.0f || fabsf(b0) > 1e-20f)) cb++;
    if (fabsf(b1) < 64.0f && (b1 == 0.0f || fabsf(b1) > 1e-20f)) cb++;
  }
#pragma unroll
  for (int o = 32; o > 0; o >>= 1) cb += __shfl_down(cb, o, 64);
  if ((t & 63) == 0) sc[t >> 6] = cb;
  __syncthreads();
  if (t == 0) flag[0] = (sc[0] + sc[1] + sc[2] + sc[3] > 7373) ? 1 : 0;  // 1 = bf16 inputs
}

__global__ void cvt_any_k(const void* __restrict__ s, float* __restrict__ d, int n,
                          const int* __restrict__ flag) {
  int i = blockIdx.x * 256 + threadIdx.x;
  if (i >= n) return;
  if (*flag)
    d[i] = toF(((const __hip_bfloat16*)s)[i]);
  else
    d[i] = ((const float*)s)[i];
}

// weight [K][N] -> bf16 transposed [N][K]
__global__ void cvtT_k(const void* __restrict__ s, __hip_bfloat16* __restrict__ d, int K, int N,
                       const int* __restrict__ flag) {
  int i = blockIdx.x * 256 + threadIdx.x;
  if (i >= N * K) return;
  int n = i / K, k = i - n * K;
  float v = (*flag) ? toF(((const __hip_bfloat16*)s)[(long)k * N + n])
                    : ((const float*)s)[(long)k * N + n];
  d[i] = f2b(v);
}

__global__ void f32tob16_k(const float* __restrict__ s, __hip_bfloat16* __restrict__ d, int n) {
  int i = blockIdx.x * 256 + threadIdx.x;
  if (i < n) d[i] = f2b(s[i]);
}

// ---------------- LN kernels ----------------

__global__ __launch_bounds__(256) void ln1_k(const void* __restrict__ xv,
                                             const float* __restrict__ g,
                                             const float* __restrict__ be,
                                             __hip_bfloat16* __restrict__ o,
                                             const int* __restrict__ flag) {
  __shared__ float sb[4];
  size_t row = blockIdx.x;
  __hip_bfloat16* po = o + row * kD;
  int t = threadIdx.x;
  float v0, v1;
  if (*flag) {
    const __hip_bfloat16* pr = (const __hip_bfloat16*)xv + row * kD;
    v0 = toF(pr[t]);
    v1 = toF(pr[t + 256]);
  } else {
    const float* pr = (const float*)xv + row * kD;
    v0 = pr[t];
    v1 = pr[t + 256];
  }
  float s = blockSum(v0 + v1, sb);
  float ss = blockSum(v0 * v0 + v1 * v1, sb);
  float mu = s * (1.0f / kD);
  float var = ss * (1.0f / kD) - mu * mu;
  float rs = rsqrtf(var + 1e-5f);
  po[t] = f2b((v0 - mu) * rs * g[t] + be[t]);
  po[t + 256] = f2b((v1 - mu) * rs * g[t + 256] + be[t + 256]);
}

__global__ __launch_bounds__(256) void ln2stats_k(const float* __restrict__ x,
                                                  float* __restrict__ st) {
  __shared__ float sb[4];
  size_t row = blockIdx.x;
  const float* pr = x + row * kD;
  int t = threadIdx.x;
  float v0 = pr[t], v1 = pr[t + 256];
  float s = blockSum(v0 + v1, sb);
  float ss = blockSum(v0 * v0 + v1 * v1, sb);
  if (t == 0) {
    float mu = s * (1.0f / kD);
    float var = ss * (1.0f / kD) - mu * mu;
    st[2 * row] = mu;
    st[2 * row + 1] = rsqrtf(var + 1e-5f);
  }
}

// ---------------- small helpers ----------------

__global__ void landmark_k(const __hip_bfloat16* __restrict__ src, float* __restrict__ dst) {
  int i = blockIdx.x * 256 + threadIdx.x;
  if (i >= kBH * kM * kDH) return;
  int dh = i & 63, m = (i >> 6) & 255, bh = i >> 14;
  const __hip_bfloat16* p = src + ((size_t)bh * kN + m * kL) * kDH + dh;
  float s = 0.f;
#pragma unroll
  for (int l = 0; l < kL; ++l) s += toF(p[l * kDH]);
  dst[i] = s * (1.0f / kL);
}

__global__ __launch_bounds__(256) void softmax_k(float* __restrict__ X, int ncols) {
  __shared__ float sb[4];
  size_t row = blockIdx.x;
  float* p = X + row * ncols;
  int t = threadIdx.x;
  float mx = -1e30f;
  for (int c = t; c < ncols; c += 256) mx = fmaxf(mx, p[c]);
  mx = blockMax(mx, sb);
  float s = 0.f;
  for (int c = t; c < ncols; c += 256) {
    float e = expf(fminf(p[c] - mx, 0.0f));
    p[c] = e;
    s += e;
  }
  s = blockSum(s, sb);
  float inv = 1.0f / s;
  for (int c = t; c < ncols; c += 256) p[c] *= inv;
}

__global__ __launch_bounds__(256) void pinv_rowcol_k(const float* __restrict__ a2,
                                                     float* __restrict__ rsum,
                                                     float* __restrict__ csum) {
  __shared__ float sb[4];
  int bh = blockIdx.x >> 8, i = blockIdx.x & 255;
  const float* base = a2 + ((size_t)bh << 16);
  int t = threadIdx.x;
  float rs = blockSum(fabsf(base[i * kM + t]), sb);
  float cs = blockSum(fabsf(base[t * kM + i]), sb);
  if (t == 0) {
    rsum[blockIdx.x] = rs;
    csum[blockIdx.x] = cs;
  }
}

__global__ __launch_bounds__(256) void pinv_gmax_k(const float* __restrict__ rsum,
                                                   const float* __restrict__ csum,
                                                   float* __restrict__ gmax) {
  __shared__ float sb[4];
  int t = threadIdx.x;
  float a = 0.f, b = 0.f;
  for (int j = t; j < kBH * kM; j += 256) {
    a = fmaxf(a, rsum[j]);
    b = fmaxf(b, csum[j]);
  }
  a = blockMax(a, sb);
  b = blockMax(b, sb);
  if (t == 0) {
    gmax[0] = a;
    gmax[1] = b;
  }
}

__global__ void pinv_init_k(const float* __restrict__ a2, const float* __restrict__ gmax,
                            __hip_bfloat16* __restrict__ z) {
  int i = blockIdx.x * 256 + threadIdx.x;
  if (i >= kBH * kM * kM) return;
  int col = i & 255, r = (i >> 8) & 255, bh = i >> 16;
  float denom = fmaxf(gmax[0] * gmax[1], 1e-30f);
  z[i] = f2b(a2[((size_t)bh << 16) + col * kM + r] / denom);
}

__global__ void conv_add_k(const __hip_bfloat16* __restrict__ v, const float* __restrict__ w,
                           __hip_bfloat16* __restrict__ ao) {
  int i = blockIdx.x * 256 + threadIdx.x;
  if (i >= kBN * kHD) return;
  int dh = i & 63, h = (i >> 6) & 7, n = (i >> 9) & (kN - 1), b = i >> 21;
  const __hip_bfloat16* vp = v + ((size_t)(b * kH + h) * kN) * kDH + dh;
  float s = 0.f;
#pragma unroll
  for (int kk = 0; kk < kCK; ++kk) {
    int nn = n + kk - kCK / 2;
    if (nn >= 0 && nn < kN) s += toF(vp[(size_t)nn * kDH]) * w[h * kCK + kk];
  }
  ao[i] = f2b(toF(ao[i]) + s);
}

// ---------------- MFMA flash attention (replaces scalar attn3v_k / attn1y_k) ----------------
// O = softmax(Q @ K^T) @ V, 64 Q-rows per block, KV tiles of 256, online softmax.
// Fragment conventions identical to mgemm_k (mfma_f32_16x16x32_bf16):
//   A: row = lane&15 (+16i), k = (lane>>4)*8 + e (+32s)
//   B: col = lane&15 (+16j), k = (lane>>4)*8 + e (+32s)
//   C: row = (lane>>4)*4 + rg (+16i), col = lane&15 (+16j)
// Wave w owns KV columns [w*64, w*64+64) of each 256-wide tile; per-wave partial
// (O, l) combined through LDS at the end (m is shared across waves every tile).
constexpr int FP = 72;  // LDS row pad in shorts (144 B stride: 16B-aligned, 2-way max on b128)

template <bool A3>  // true : attn3 — Q=ql f32 [bh][256][64], K/V=kk/vv bf16 [bh][4096][64],
                    //        out w3 f32 [bh][256][64];  grid = kBH*4
                    // false: attn1 — Q=q bf16 [bh][4096][64], K=kl f32, V=y f32 [bh][256][64],
                    //        out ao bf16 scatter [b][n][h*64+dh]; grid = kBH*64
__global__ __launch_bounds__(256, 1) void fattn_k(const void* __restrict__ Qp,
                                                  const void* __restrict__ Kp,
                                                  const void* __restrict__ Vp,
                                                  void* __restrict__ Op) {
  __shared__ __align__(16) char smem[111616];
  short* Ks = (short*)smem;                    // [256][FP]  36864 B
  short* Vs = (short*)(smem + 36864);          // [256][FP]  36864 B
  short* Ps = (short*)(smem + 73728);          // 4 x [64][FP] (per-wave P slab) 36864 B
  float* wred = (float*)(smem + 110592);       // [4][64] cross-wave max / lsum
  float* Comb = (float*)smem;                  // [4][64][64] f32 epilogue alias (64 KB)

  const int t = threadIdx.x;
  const int lane = t & 63, wave = t >> 6;
  const int l15 = lane & 15, quad = lane >> 4;
  const int bh = A3 ? (blockIdx.x >> 2) : (blockIdx.x >> 6);
  const int q0 = A3 ? ((blockIdx.x & 3) * 64) : ((blockIdx.x & 63) * 64);
  const int NTILES = A3 ? (kN / 256) : 1;
  short* Psw = Ps + wave * 64 * FP;

  // ---- Q fragments in registers ----
  short8 aq[4][2];
#pragma unroll
  for (int i = 0; i < 4; ++i) {
    const long qrow = (A3 ? ((long)bh * kM) : ((long)bh * kN)) + q0 + i * 16 + l15;
#pragma unroll
    for (int s = 0; s < 2; ++s) {
      if constexpr (A3) {
        const f32x4* p = (const f32x4*)((const float*)Qp + qrow * kDH + quad * 8 + s * 32);
        f32x4 a = p[0], b = p[1];
        short8 v;
#pragma unroll
        for (int e = 0; e < 4; ++e) { v[e] = f2s(a[e]); v[4 + e] = f2s(b[e]); }
        aq[i][s] = v;
      } else {
        aq[i][s] =
            *(const short8*)((const __hip_bfloat16*)Qp + qrow * kDH + quad * 8 + s * 32);
      }
    }
  }

  f32x4 o[4][4] = {};
  float mrow[4][4], lrow[4][4];
#pragma unroll
  for (int i = 0; i < 4; ++i)
#pragma unroll
    for (int rg = 0; rg < 4; ++rg) {
      mrow[i][rg] = -1e30f;
      lrow[i][rg] = 0.f;
    }

  const long kvbase = (long)bh * (A3 ? kN : kM) * kDH;

  for (int tile = 0; tile < NTILES; ++tile) {
    // ---- stage K,V tile [256][64] -> LDS bf16 ----
    {
      const int r = t >> 2, c = (t & 3) * 16;
#pragma unroll
      for (int p = 0; p < 4; ++p) {
        const int rr = p * 64 + r;
        const long src = kvbase + (long)(tile * 256 + rr) * kDH + c;
        if constexpr (A3) {
          const uint4* ks = (const uint4*)((const __hip_bfloat16*)Kp + src);
          const uint4* vs = (const uint4*)((const __hip_bfloat16*)Vp + src);
          *(uint4*)&Ks[rr * FP + c] = ks[0];
          *(uint4*)&Ks[rr * FP + c + 8] = ks[1];
          *(uint4*)&Vs[rr * FP + c] = vs[0];
          *(uint4*)&Vs[rr * FP + c + 8] = vs[1];
        } else {
          const f32x4* ks = (const f32x4*)((const float*)Kp + src);
          const f32x4* vs = (const f32x4*)((const float*)Vp + src);
          f32x4 k0 = ks[0], k1 = ks[1], k2 = ks[2], k3 = ks[3];
          f32x4 v0 = vs[0], v1 = vs[1], v2 = vs[2], v3 = vs[3];
          short8 ka, kb, va, vb;
#pragma unroll
          for (int e = 0; e < 4; ++e) {
            ka[e] = f2s(k0[e]); ka[4 + e] = f2s(k1[e]);
            kb[e] = f2s(k2[e]); kb[4 + e] = f2s(k3[e]);
            va[e] = f2s(v0[e]); va[4 + e] = f2s(v1[e]);
            vb[e] = f2s(v2[e]); vb[4 + e] = f2s(v3[e]);
          }
          *(short8*)&Ks[rr * FP + c] = ka;
          *(short8*)&Ks[rr * FP + c + 8] = kb;
          *(short8*)&Vs[rr * FP + c] = va;
          *(short8*)&Vs[rr * FP + c + 8] = vb;
        }
      }
    }
    __syncthreads();

    // ---- S = Q @ K^T  (wave's 64x64 slab of the 64x256 tile) ----
    f32x4 sacc[4][4] = {};
#pragma unroll
    for (int s = 0; s < 2; ++s) {
      short8 bk[4];
#pragma unroll
      for (int j = 0; j < 4; ++j)
        bk[j] = *(const short8*)&Ks[(wave * 64 + j * 16 + l15) * FP + quad * 8 + s * 32];
#pragma unroll
      for (int i = 0; i < 4; ++i)
#pragma unroll
        for (int j = 0; j < 4; ++j)
          sacc[i][j] =
              __builtin_amdgcn_mfma_f32_16x16x32_bf16(aq[i][s], bk[j], sacc[i][j], 0, 0, 0);
    }

    // ---- per-row max: lane-local over j, then over l15 group, then cross-wave ----
    float pmax[4][4];
#pragma unroll
    for (int i = 0; i < 4; ++i)
#pragma unroll
      for (int rg = 0; rg < 4; ++rg) {
        float v = fmaxf(fmaxf(sacc[i][0][rg], sacc[i][1][rg]),
                        fmaxf(sacc[i][2][rg], sacc[i][3][rg]));
#pragma unroll
        for (int d = 1; d < 16; d <<= 1) v = fmaxf(v, __shfl_xor(v, d, 64));
        pmax[i][rg] = v;
      }
    if (l15 == 0) {
#pragma unroll
      for (int i = 0; i < 4; ++i)
#pragma unroll
        for (int rg = 0; rg < 4; ++rg)
          wred[wave * 64 + i * 16 + quad * 4 + rg] = pmax[i][rg];
    }
    __syncthreads();

    // ---- online rescale + exp + P repack (bf16, own-wave LDS slab) ----
#pragma unroll
    for (int i = 0; i < 4; ++i)
#pragma unroll
      for (int rg = 0; rg < 4; ++rg) {
        const int row = i * 16 + quad * 4 + rg;
        float tm =
            fmaxf(fmaxf(wred[row], wred[64 + row]), fmaxf(wred[128 + row], wred[192 + row]));
        float mn = fmaxf(mrow[i][rg], tm);
        float c = expf(mrow[i][rg] - mn);
        mrow[i][rg] = mn;
        lrow[i][rg] *= c;
#pragma unroll
        for (int j = 0; j < 4; ++j) o[i][j][rg] *= c;
      }
#pragma unroll
    for (int i = 0; i < 4; ++i)
#pragma unroll
      for (int rg = 0; rg < 4; ++rg) {
        float ls = 0.f;
#pragma unroll
        for (int j = 0; j < 4; ++j) {
          float e = expf(sacc[i][j][rg] - mrow[i][rg]);  // <= 0 exponent by construction
          ls += e;
          Psw[(i * 16 + quad * 4 + rg) * FP + j * 16 + l15] = f2s(e);
        }
#pragma unroll
        for (int d = 1; d < 16; d <<= 1) ls += __shfl_xor(ls, d, 64);
        lrow[i][rg] += ls;
      }

    // ---- O += P @ V  (A from own-wave P slab, B gathered from Vs rows of own slab) ----
#pragma unroll
    for (int s = 0; s < 2; ++s) {
      short8 ap[4];
#pragma unroll
      for (int i = 0; i < 4; ++i)
        ap[i] = *(const short8*)&Psw[(i * 16 + l15) * FP + quad * 8 + s * 32];
      short8 bv[4];
#pragma unroll
      for (int j = 0; j < 4; ++j)
#pragma unroll
        for (int e = 0; e < 8; ++e)
          bv[j][e] = Vs[(wave * 64 + s * 32 + quad * 8 + e) * FP + j * 16 + l15];
#pragma unroll
      for (int i = 0; i < 4; ++i)
#pragma unroll
        for (int j = 0; j < 4; ++j)
          o[i][j] = __builtin_amdgcn_mfma_f32_16x16x32_bf16(ap[i], bv[j], o[i][j], 0, 0, 0);
    }
    __syncthreads();
  }

  // ---- cross-wave combine: O = sum_w O_w, l = sum_w l_w; write out ----
#pragma unroll
  for (int i = 0; i < 4; ++i)
#pragma unroll
    for (int j = 0; j < 4; ++j)
#pragma unroll
      for (int rg = 0; rg < 4; ++rg)
        Comb[wave * 4096 + (i * 16 + quad * 4 + rg) * 64 + j * 16 + l15] = o[i][j][rg];
  if (l15 == 0) {
#pragma unroll
    for (int i = 0; i < 4; ++i)
#pragma unroll
      for (int rg = 0; rg < 4; ++rg)
        wred[wave * 64 + i * 16 + quad * 4 + rg] = lrow[i][rg];
  }
  __syncthreads();
#pragma unroll
  for (int u = 0; u < 16; ++u) {
    const int idx = u * 256 + t;
    const int row = idx >> 6, dh = idx & 63;
    float v = Comb[idx] + Comb[4096 + idx] + Comb[8192 + idx] + Comb[12288 + idx];
    float linv = 1.0f / (wred[row] + wred[64 + row] + wred[128 + row] + wred[192 + row]);
    if constexpr (A3) {
      ((float*)Op)[((size_t)bh * kM + q0 + row) * kDH + dh] = v * linv;
    } else {
      const int b = bh >> 3, h = bh & 7;
      ((__hip_bfloat16*)Op)[((size_t)(b * kN + q0 + row)) * kHD + h * kDH + dh] =
          f2b(v * linv);
    }
  }
}

// ---------------- epilogue / arg pack ----------------
constexpr int EPI_F32 = 0, EPI_QKV = 1, EPI_BIAS_F32 = 2, EPI_GELU_BF16 = 3, EPI_RES_OUT = 4,
              EPI_BF16 = 5;

struct EpiArgs {
  const float* bias;
  const float* res;
  __hip_bfloat16* oq;
  __hip_bfloat16* ok;
  __hip_bfloat16* ov;
  __hip_bfloat16* obf;
  const float* stats;
  const float* g;
  const float* be;
  void* ovoid;
  const int* flag;
  float eyeC;
  float eyeS;
};

// ---------------- MFMA bf16 GEMM: 128x128 tile, BK=32, 4 waves ----------------
// A [M][K] (bf16, or f32 with fused LN when LNA). B bf16: TRB -> [N][K]; else [K][N]
// (gather staging, optional fused (eyeC*I - B)*eyeS transform). f32 accumulate.
template <int EPI, bool TRB, bool BEYE, bool LNA, class TAT>
__global__ __launch_bounds__(256) void mgemm_k(const TAT* __restrict__ A, int lda, long sA,
                                               const __hip_bfloat16* __restrict__ B, int ldb,
                                               long sB, float* __restrict__ C, int ldc, long sC,
                                               int K, EpiArgs ep) {
  __shared__ short As[128 * 40];
  __shared__ short Bs[128 * 40];
  A += (long)blockIdx.z * sA;
  B += (long)blockIdx.z * sB;
  const long cbase = (long)blockIdx.z * sC;
  const int row0 = blockIdx.x * 128, col0 = blockIdx.y * 128;
  const int t = threadIdx.x;
  const int lane = t & 63, wave = t >> 6;
  const int wr = (wave >> 1) * 64, wc = (wave & 1) * 64;
  const int l15 = lane & 15, quad = lane >> 4;
  f32x4 acc[4][4] = {};
  for (int k0 = 0; k0 < K; k0 += 32) {
    // ---- stage A (128x32) ----
    {
      const int kc = (t & 3) * 8;
#pragma unroll
      for (int p = 0; p < 2; ++p) {
        const int m = p * 64 + (t >> 2);
        const long r = row0 + m;
        if constexpr (LNA) {
          const float* ap = (const float*)A + r * lda + k0 + kc;
          float mu = ep.stats[2 * r], rs = ep.stats[2 * r + 1];
          short8 vv;
#pragma unroll
          for (int e = 0; e < 8; ++e)
            vv[e] = f2s((ap[e] - mu) * rs * ep.g[k0 + kc + e] + ep.be[k0 + kc + e]);
          *(short8*)(&As[m * 40 + kc]) = vv;
        } else {
          uint4 u = *(const uint4*)((const __hip_bfloat16*)A + r * lda + k0 + kc);
          *(uint4*)(&As[m * 40 + kc]) = u;
        }
      }
    }
    // ---- stage B (as [n][k]) ----
    if (TRB) {
      const int kc = (t & 3) * 8;
#pragma unroll
      for (int p = 0; p < 2; ++p) {
        const int n = p * 64 + (t >> 2);
        uint4 u = *(const uint4*)(B + (long)(col0 + n) * ldb + k0 + kc);
        *(uint4*)(&Bs[n * 40 + kc]) = u;
      }
    } else {
      const int k8 = (t & 3) * 8;
#pragma unroll
      for (int p = 0; p < 2; ++p) {
        const int n = p * 64 + (t >> 2);
        short8 vv;
#pragma unroll
        for (int e = 0; e < 8; ++e) {
          float v = toF(B[(long)(k0 + k8 + e) * ldb + col0 + n]);
          if constexpr (BEYE) v = (((k0 + k8 + e) == (col0 + n)) ? ep.eyeC : 0.0f) - v;
          vv[e] = f2s(BEYE ? v * ep.eyeS : v);
        }
        *(short8*)(&Bs[n * 40 + k8]) = vv;
      }
    }
    __syncthreads();
    short8 af[4], bf[4];
#pragma unroll
    for (int i = 0; i < 4; ++i)
      af[i] = *(const short8*)(&As[(wr + i * 16 + l15) * 40 + quad * 8]);
#pragma unroll
    for (int j = 0; j < 4; ++j)
      bf[j] = *(const short8*)(&Bs[(wc + j * 16 + l15) * 40 + quad * 8]);
#pragma unroll
    for (int i = 0; i < 4; ++i)
#pragma unroll
      for (int j = 0; j < 4; ++j)
        acc[i][j] = __builtin_amdgcn_mfma_f32_16x16x32_bf16(af[i], bf[j], acc[i][j], 0, 0, 0);
    __syncthreads();
  }
  // ---- epilogue (C/D: col=lane&15, row=quad*4+reg) ----
#pragma unroll
  for (int i = 0; i < 4; ++i) {
#pragma unroll
    for (int j = 0; j < 4; ++j) {
#pragma unroll
      for (int rg = 0; rg < 4; ++rg) {
        int r = row0 + wr + i * 16 + quad * 4 + rg;
        int c = col0 + wc + j * 16 + l15;
        float v = acc[i][j][rg];
        if (EPI == EPI_BF16) {
          ep.obf[cbase + (long)r * ldc + c] = f2b(v);
        } else if (EPI == EPI_QKV) {
          int three = c >> 9, h = (c >> 6) & 7, dh = c & 63;
          int b = r >> 12, n = r & (kN - 1);
          long dst = ((long)(b * kH + h) * kN + n) * kDH + dh;
          if (three == 0)
            ep.oq[dst] = f2b(v * 0.125f);
          else if (three == 1)
            ep.ok[dst] = f2b(v);
          else
            ep.ov[dst] = f2b(v);
        } else if (EPI == EPI_BIAS_F32) {
          C[cbase + (long)r * ldc + c] = v + ep.bias[c];
        } else if (EPI == EPI_GELU_BF16) {
          v += ep.bias[c];
          ep.obf[cbase + (long)r * ldc + c] =
              f2b(0.5f * v * (1.0f + erff(v * 0.70710678118654752f)));
        } else if (EPI == EPI_RES_OUT) {
          long idx = cbase + (long)r * ldc + c;
          float v2 = v + ep.bias[c] + ep.res[idx];
          if (!(v2 == v2)) v2 = 0.0f;
          if (*ep.flag)
            ((__hip_bfloat16*)ep.ovoid)[idx] = f2b(v2);
          else
            ((float*)ep.ovoid)[idx] = v2;
        }
      }
    }
  }
}

// ---------------- fp32 vector GEMM (for small/odd shapes: sim2, y) ----------------
template <int EPI, bool TRB, class TAT, class TBT>
__global__ __launch_bounds__(256) void gemm_k(const TAT* __restrict__ A, int lda, long sA,
                                              const TBT* __restrict__ B, int ldb, long sB,
                                              float* __restrict__ C, int ldc, long sC, int K,
                                              EpiArgs ep) {
  __shared__ float As[16][68];
  __shared__ float Bs[16][68];
  A += (long)blockIdx.z * sA;
  B += (long)blockIdx.z * sB;
  const long cbase = (long)blockIdx.z * sC;
  const int row0 = blockIdx.x * 64, col0 = blockIdx.y * 64;
  const int t = threadIdx.x;
  const int ty = t >> 4, tx = t & 15;
  float acc[4][4] = {{0.f, 0.f, 0.f, 0.f}, {0.f, 0.f, 0.f, 0.f},
                     {0.f, 0.f, 0.f, 0.f}, {0.f, 0.f, 0.f, 0.f}};
  const int ka = t & 15, ra = t >> 4;
  for (int k0 = 0; k0 < K; k0 += 16) {
#pragma unroll
    for (int j = 0; j < 4; ++j)
      As[ka][ra + 16 * j] = toF(A[(long)(row0 + ra + 16 * j) * lda + (k0 + ka)]);
    if (TRB) {
#pragma unroll
      for (int j = 0; j < 4; ++j)
        Bs[ka][ra + 16 * j] = toF(B[(long)(col0 + ra + 16 * j) * ldb + (k0 + ka)]);
    } else {
      const int jb = t & 63, kb = t >> 6;
#pragma unroll
      for (int j = 0; j < 4; ++j)
        Bs[kb + 4 * j][jb] = toF(B[(long)(k0 + kb + 4 * j) * ldb + (col0 + jb)]);
    }
    __syncthreads();
#pragma unroll
    for (int kk = 0; kk < 16; ++kk) {
      float av[4], bv[4];
#pragma unroll
      for (int i = 0; i < 4; ++i) av[i] = As[kk][ty * 4 + i];
#pragma unroll
      for (int j = 0; j < 4; ++j) bv[j] = Bs[kk][tx * 4 + j];
#pragma unroll
      for (int i = 0; i < 4; ++i)
#pragma unroll
        for (int j = 0; j < 4; ++j) acc[i][j] += av[i] * bv[j];
    }
    __syncthreads();
  }
#pragma unroll
  for (int i = 0; i < 4; ++i) {
    int r = row0 + ty * 4 + i;
#pragma unroll
    for (int j = 0; j < 4; ++j) {
      int c = col0 + tx * 4 + j;
      C[cbase + (long)r * ldc + c] = acc[i][j];
    }
  }
}

}  // namespace

extern "C" void kernel_launch(void* const* d_in, const int* in_sizes, int n_in, void* d_out,
                              int out_size, void* d_ws, size_t ws_size, hipStream_t stream) {
  (void)in_sizes; (void)n_in; (void)out_size;

  char* base = (char*)d_ws;
  size_t off = 0;
  auto alloc = [&](size_t bytes) {
    char* p = base + off;
    off = (off + bytes + 255) & ~(size_t)255;
    return p;
  };
  // a2 + 4 pinv slots (slots sized for f32 to keep hbuf contiguity; used as bf16)
  float* a2 = (float*)alloc((size_t)kBH * kM * kM * 4);  // 16.78 MB
  __hip_bfloat16* zs0 = (__hip_bfloat16*)alloc((size_t)kBH * kM * kM * 4);
  __hip_bfloat16* zs1 = (__hip_bfloat16*)alloc((size_t)kBH * kM * kM * 4);
  __hip_bfloat16* zs2 = (__hip_bfloat16*)alloc((size_t)kBH * kM * kM * 4);
  __hip_bfloat16* zs3 = (__hip_bfloat16*)alloc((size_t)kBH * kM * kM * 4);
  __hip_bfloat16* a2b = (__hip_bfloat16*)alloc((size_t)kBH * kM * kM * 2);  // 8.39 MB
  // bf16 qkv + attn-out region (hosts MLP hidden late: 134.2 MB contiguous)
  __hip_bfloat16* q = (__hip_bfloat16*)alloc((size_t)kBH * kN * kDH * 2);
  __hip_bfloat16* kk = (__hip_bfloat16*)alloc((size_t)kBH * kN * kDH * 2);
  __hip_bfloat16* vv = (__hip_bfloat16*)alloc((size_t)kBH * kN * kDH * 2);
  __hip_bfloat16* ao = (__hip_bfloat16*)alloc((size_t)kBN * kHD * 2);
  float* ql = (float*)alloc((size_t)kBH * kM * kDH * 4);
  float* kl = (float*)alloc((size_t)kBH * kM * kDH * 4);
  float* w3 = (float*)alloc((size_t)kBH * kM * kDH * 4);
  float* y = (float*)alloc((size_t)kBH * kM * kDH * 4);
  float* st2 = (float*)alloc((size_t)kBN * 2 * 4);
  float* rsum = (float*)alloc((size_t)kBH * kM * 4);
  float* csum = (float*)alloc((size_t)kBH * kM * 4);
  float* gmax = (float*)alloc(256);
  int* dflag = (int*)alloc(256);
  // transposed bf16 weights
  __hip_bfloat16* WqkvT = (__hip_bfloat16*)alloc((size_t)kQKVC * kD * 2);
  __hip_bfloat16* WoutT = (__hip_bfloat16*)alloc((size_t)kD * kHD * 2);
  __hip_bfloat16* W1T = (__hip_bfloat16*)alloc((size_t)kD4 * kD * 2);
  __hip_bfloat16* W2T = (__hip_bfloat16*)alloc((size_t)kD * kD4 * 2);
  float* bout_f = (float*)alloc(kD * 4);
  float* b1_f = (float*)alloc(kD4 * 4);
  float* b2_f = (float*)alloc(kD * 4);
  float* convw_f = (float*)alloc(kH * kCK * 4);
  float* g1_f = (float*)alloc(kD * 4);
  float* be1_f = (float*)alloc(kD * 4);
  float* g2_f = (float*)alloc(kD * 4);
  float* be2_f = (float*)alloc(kD * 4);
  // lifetime-disjoint aliases
  __hip_bfloat16* hln = (__hip_bfloat16*)a2;  // LN1 out, spans a2+zs0+half zs1, dead pre-sim2
  float* hbuf = a2;                           // Wout out f32 67.1MB, spans a2+zs0..zs2
  __hip_bfloat16* hidden = q;                 // MLP hidden bf16 134.2MB, spans q..ao

  if (off > ws_size) return;  // deterministic guard

  detect_k<<<1, 256, 0, stream>>>((const unsigned*)d_in[0], dflag);

  auto cvt = [&](const void* src, float* dst, int n) {
    cvt_any_k<<<(n + 255) / 256, 256, 0, stream>>>(src, dst, n, dflag);
  };
  cvtT_k<<<(kD * kQKVC + 255) / 256, 256, 0, stream>>>(d_in[1], WqkvT, kD, kQKVC, dflag);
  cvtT_k<<<(kHD * kD + 255) / 256, 256, 0, stream>>>(d_in[2], WoutT, kHD, kD, dflag);
  cvtT_k<<<(kD * kD4 + 255) / 256, 256, 0, stream>>>(d_in[9], W1T, kD, kD4, dflag);
  cvtT_k<<<(kD4 * kD + 255) / 256, 256, 0, stream>>>(d_in[11], W2T, kD4, kD, dflag);
  cvt(d_in[3], bout_f, kD);
  cvt(d_in[4], convw_f, kH * kCK);
  cvt(d_in[5], g1_f, kD);
  cvt(d_in[6], be1_f, kD);
  cvt(d_in[7], g2_f, kD);
  cvt(d_in[8], be2_f, kD);
  cvt(d_in[10], b1_f, kD4);
  cvt(d_in[12], b2_f, kD);

  EpiArgs e0 = {};

  // LN1 -> hln (bf16)
  ln1_k<<<kBN, 256, 0, stream>>>(d_in[0], g1_f, be1_f, hln, dflag);

  // QKV: hln @ WqkvT^T (MFMA, scatter epilogue)
  EpiArgs eq = {};
  eq.oq = q; eq.ok = kk; eq.ov = vv;
  mgemm_k<EPI_QKV, true, false, false, __hip_bfloat16>
      <<<dim3(kBN / 128, kQKVC / 128, 1), 256, 0, stream>>>(hln, kD, 0, WqkvT, kD, 0, nullptr, 0,
                                                            0, kD, eq);

  landmark_k<<<(kBH * kM * kDH + 255) / 256, 256, 0, stream>>>(q, ql);
  landmark_k<<<(kBH * kM * kDH + 255) / 256, 256, 0, stream>>>(kk, kl);

  const long sQL = (long)kM * kDH, sA2 = (long)kM * kM;

  // sim2 = q_l @ k_l^T (f32) ; softmax
  gemm_k<EPI_F32, true, float, float><<<dim3(kM / 64, kM / 64, kBH), 256, 0, stream>>>(
      ql, kDH, sQL, kl, kDH, sQL, a2, kM, sA2, kDH, e0);
  softmax_k<<<kBH * kM, 256, 0, stream>>>(a2, kM);

  // pinv setup
  f32tob16_k<<<(kBH * kM * kM + 255) / 256, 256, 0, stream>>>(a2, a2b, kBH * kM * kM);
  pinv_rowcol_k<<<kBH * kM, 256, 0, stream>>>(a2, rsum, csum);
  pinv_gmax_k<<<1, 256, 0, stream>>>(rsum, csum, gmax);
  pinv_init_k<<<(kBH * kM * kM + 255) / 256, 256, 0, stream>>>(a2, gmax, zs0);

  // Newton-Schulz: 4 MFMA GEMMs/iter, eye-ops fused into B staging
  __hip_bfloat16* bufs[4] = {zs0, zs1, zs2, zs3};
  int zi = 0;
  dim3 gP(kM / 128, kM / 128, kBH);
  for (int it = 0; it < 6; ++it) {
    int o0 = (zi + 1) & 3, o1 = (zi + 2) & 3, o2 = (zi + 3) & 3;
    __hip_bfloat16* Z = bufs[zi];
    __hip_bfloat16* T1 = bufs[o0];
    __hip_bfloat16* T3 = bufs[o1];
    __hip_bfloat16* P3 = bufs[o2];
    EpiArgs ep1 = {}; ep1.obf = T1;
    mgemm_k<EPI_BF16, false, false, false, __hip_bfloat16><<<gP, 256, 0, stream>>>(
        a2b, kM, sA2, Z, kM, sA2, nullptr, kM, sA2, kM, ep1);
    EpiArgs ep2 = {}; ep2.obf = T3; ep2.eyeC = 7.0f; ep2.eyeS = 1.0f;
    mgemm_k<EPI_BF16, false, true, false, __hip_bfloat16><<<gP, 256, 0, stream>>>(
        T1, kM, sA2, T1, kM, sA2, nullptr, kM, sA2, kM, ep2);
    EpiArgs ep3 = {}; ep3.obf = P3; ep3.eyeC = 15.0f; ep3.eyeS = 1.0f;
    mgemm_k<EPI_BF16, false, true, false, __hip_bfloat16><<<gP, 256, 0, stream>>>(
        T1, kM, sA2, T3, kM, sA2, nullptr, kM, sA2, kM, ep3);
    EpiArgs ep4 = {}; ep4.obf = T3; ep4.eyeC = 13.0f; ep4.eyeS = 0.25f;
    mgemm_k<EPI_BF16, false, true, false, __hip_bfloat16><<<gP, 256, 0, stream>>>(
        Z, kM, sA2, P3, kM, sA2, nullptr, kM, sA2, kM, ep4);
    zi = o1;
  }
  __hip_bfloat16* zfin = bufs[zi];

  // w3 = softmax(q_l @ k^T) @ v  (MFMA flash attention)
  fattn_k<true><<<kBH * (kM / 64), 256, 0, stream>>>(ql, kk, vv, w3);

  // y = z @ w3 (f32 vector gemm; N=64)
  gemm_k<EPI_F32, false, __hip_bfloat16, float><<<dim3(kM / 64, 1, kBH), 256, 0, stream>>>(
      zfin, kM, sA2, w3, kDH, sQL, y, kDH, sQL, kM, e0);

  // ao = softmax(q @ k_l^T) @ y  (MFMA flash attention, merged layout)
  fattn_k<false><<<kBH * (kN / 64), 256, 0, stream>>>(q, kl, y, ao);

  // + depthwise conv residual
  conv_add_k<<<(kBN * kHD + 255) / 256, 256, 0, stream>>>(vv, convw_f, ao);

  // hbuf = ao @ WoutT^T + bout (MFMA, f32 out)
  EpiArgs ew = {}; ew.bias = bout_f;
  mgemm_k<EPI_BIAS_F32, true, false, false, __hip_bfloat16>
      <<<dim3(kBN / 128, kD / 128, 1), 256, 0, stream>>>(ao, kHD, 0, WoutT, kHD, 0, hbuf, kD, 0,
                                                         kHD, ew);

  // LN2 stats; MLP1 (LN fused in A-staging, +bias+GELU -> bf16 hidden)
  ln2stats_k<<<kBN, 256, 0, stream>>>(hbuf, st2);
  EpiArgs e1 = {}; e1.bias = b1_f; e1.stats = st2; e1.g = g2_f; e1.be = be2_f; e1.obf = hidden;
  mgemm_k<EPI_GELU_BF16, true, false, true, float>
      <<<dim3(kBN / 128, kD4 / 128, 1), 256, 0, stream>>>(hbuf, kD, 0, W1T, kD, 0, nullptr, kD4,
                                                          0, kD, e1);

  // MLP2 (+bias+residual -> flag-typed out)
  EpiArgs e2 = {}; e2.bias = b2_f; e2.res = hbuf; e2.ovoid = d_out; e2.flag = dflag;
  mgemm_k<EPI_RES_OUT, true, false, false, __hip_bfloat16>
      <<<dim3(kBN / 128, kD / 128, 1), 256, 0, stream>>>(hidden, kD4, 0, W2T, kD4, 0, nullptr,
                                                         kD, 0, kD4, e2);
}

// Round 2
// 1603.669 us; speedup vs baseline: 2.3242x; 1.1321x over previous
//
#include <hip/hip_runtime.h>
#include <hip/hip_bf16.h>
#include <cmath>

#define DEV __device__ __forceinline__

namespace {

constexpr int kB = 8, kN = 4096, kD = 512, kH = 8, kDH = 64, kM = 256, kL = 16, kCK = 33;
constexpr int kBN = kB * kN;     // 32768
constexpr int kBH = kB * kH;     // 64
constexpr int kHD = kH * kDH;    // 512
constexpr int kD4 = 4 * kD;      // 2048
constexpr int kQKVC = 3 * kHD;   // 1536

typedef __attribute__((ext_vector_type(8))) short short8;
typedef __attribute__((ext_vector_type(4))) float f32x4;

DEV float toF(float x) { return x; }
DEV float toF(__hip_bfloat16 x) { return __bfloat162float(x); }
DEV __hip_bfloat16 f2b(float f) { return __float2bfloat16(f); }
DEV short f2s(float f) {
  __hip_bfloat16 h = __float2bfloat16(f);
  return *reinterpret_cast<short*>(&h);
}
DEV float us2f(unsigned short u) { return __uint_as_float((unsigned)u << 16); }
DEV unsigned short f2us(float f) {
  __hip_bfloat16 h = __float2bfloat16(f);
  return *reinterpret_cast<unsigned short*>(&h);
}
DEV float lo16(unsigned u) { return __uint_as_float(u << 16); }
DEV float hi16(unsigned u) { return __uint_as_float(u & 0xffff0000u); }

DEV float waveSum(float v) {
#pragma unroll
  for (int o = 32; o > 0; o >>= 1) v += __shfl_down(v, o, 64);
  return v;
}
DEV float waveMax(float v) {
#pragma unroll
  for (int o = 32; o > 0; o >>= 1) v = fmaxf(v, __shfl_down(v, o, 64));
  return v;
}
DEV float blockSum(float v, float* sb) {
  v = waveSum(v);
  int lane = threadIdx.x & 63, w = threadIdx.x >> 6;
  __syncthreads();
  if (lane == 0) sb[w] = v;
  __syncthreads();
  return sb[0] + sb[1] + sb[2] + sb[3];
}
DEV float blockMax(float v, float* sb) {
  v = waveMax(v);
  int lane = threadIdx.x & 63, w = threadIdx.x >> 6;
  __syncthreads();
  if (lane == 0) sb[w] = v;
  __syncthreads();
  return fmaxf(fmaxf(sb[0], sb[1]), fmaxf(sb[2], sb[3]));
}

// ---------------- runtime dtype detection ----------------
__global__ __launch_bounds__(256) void detect_k(const unsigned* __restrict__ x,
                                                int* __restrict__ flag) {
  __shared__ int sc[4];
  int t = threadIdx.x;
  int cb = 0;
  for (int i = t; i < 4096; i += 256) {
    unsigned w = x[i];
    float b0 = __uint_as_float(w << 16);
    float b1 = __uint_as_float(w & 0xffff0000u);
    if (fabsf(b0) < 64.0f && (b0 == 0.0f || fabsf(b0) > 1e-20f)) cb++;
    if (fabsf(b1) < 64.0f && (b1 == 0.0f || fabsf(b1) > 1e-20f)) cb++;
  }
#pragma unroll
  for (int o = 32; o > 0; o >>= 1) cb += __shfl_down(cb, o, 64);
  if ((t & 63) == 0) sc[t >> 6] = cb;
  __syncthreads();
  if (t == 0) flag[0] = (sc[0] + sc[1] + sc[2] + sc[3] > 7373) ? 1 : 0;  // 1 = bf16 inputs
}

__global__ void cvt_any_k(const void* __restrict__ s, float* __restrict__ d, int n,
                          const int* __restrict__ flag) {
  int i = blockIdx.x * 256 + threadIdx.x;
  if (i >= n) return;
  if (*flag)
    d[i] = toF(((const __hip_bfloat16*)s)[i]);
  else
    d[i] = ((const float*)s)[i];
}

// weight [K][N] -> bf16 transposed [N][K]
__global__ void cvtT_k(const void* __restrict__ s, __hip_bfloat16* __restrict__ d, int K, int N,
                       const int* __restrict__ flag) {
  int i = blockIdx.x * 256 + threadIdx.x;
  if (i >= N * K) return;
  int n = i / K, k = i - n * K;
  float v = (*flag) ? toF(((const __hip_bfloat16*)s)[(long)k * N + n])
                    : ((const float*)s)[(long)k * N + n];
  d[i] = f2b(v);
}

__global__ void f32tob16_k(const float* __restrict__ s, __hip_bfloat16* __restrict__ d, int n) {
  int i = blockIdx.x * 256 + threadIdx.x;
  if (i < n) d[i] = f2b(s[i]);
}

// ---------------- LN kernels ----------------

__global__ __launch_bounds__(256) void ln1_k(const void* __restrict__ xv,
                                             const float* __restrict__ g,
                                             const float* __restrict__ be,
                                             __hip_bfloat16* __restrict__ o,
                                             const int* __restrict__ flag) {
  __shared__ float sb[4];
  size_t row = blockIdx.x;
  __hip_bfloat16* po = o + row * kD;
  int t = threadIdx.x;
  float v0, v1;
  if (*flag) {
    const __hip_bfloat16* pr = (const __hip_bfloat16*)xv + row * kD;
    v0 = toF(pr[t]);
    v1 = toF(pr[t + 256]);
  } else {
    const float* pr = (const float*)xv + row * kD;
    v0 = pr[t];
    v1 = pr[t + 256];
  }
  float s = blockSum(v0 + v1, sb);
  float ss = blockSum(v0 * v0 + v1 * v1, sb);
  float mu = s * (1.0f / kD);
  float var = ss * (1.0f / kD) - mu * mu;
  float rs = rsqrtf(var + 1e-5f);
  po[t] = f2b((v0 - mu) * rs * g[t] + be[t]);
  po[t + 256] = f2b((v1 - mu) * rs * g[t + 256] + be[t + 256]);
}

__global__ __launch_bounds__(256) void ln2stats_k(const float* __restrict__ x,
                                                  float* __restrict__ st) {
  __shared__ float sb[4];
  size_t row = blockIdx.x;
  const float* pr = x + row * kD;
  int t = threadIdx.x;
  float v0 = pr[t], v1 = pr[t + 256];
  float s = blockSum(v0 + v1, sb);
  float ss = blockSum(v0 * v0 + v1 * v1, sb);
  if (t == 0) {
    float mu = s * (1.0f / kD);
    float var = ss * (1.0f / kD) - mu * mu;
    st[2 * row] = mu;
    st[2 * row + 1] = rsqrtf(var + 1e-5f);
  }
}

// ---------------- small helpers ----------------

__global__ void landmark_k(const __hip_bfloat16* __restrict__ src, float* __restrict__ dst) {
  int i = blockIdx.x * 256 + threadIdx.x;
  if (i >= kBH * kM * kDH) return;
  int dh = i & 63, m = (i >> 6) & 255, bh = i >> 14;
  const __hip_bfloat16* p = src + ((size_t)bh * kN + m * kL) * kDH + dh;
  float s = 0.f;
#pragma unroll
  for (int l = 0; l < kL; ++l) s += toF(p[l * kDH]);
  dst[i] = s * (1.0f / kL);
}

__global__ __launch_bounds__(256) void softmax_k(float* __restrict__ X, int ncols) {
  __shared__ float sb[4];
  size_t row = blockIdx.x;
  float* p = X + row * ncols;
  int t = threadIdx.x;
  float mx = -1e30f;
  for (int c = t; c < ncols; c += 256) mx = fmaxf(mx, p[c]);
  mx = blockMax(mx, sb);
  float s = 0.f;
  for (int c = t; c < ncols; c += 256) {
    float e = expf(fminf(p[c] - mx, 0.0f));
    p[c] = e;
    s += e;
  }
  s = blockSum(s, sb);
  float inv = 1.0f / s;
  for (int c = t; c < ncols; c += 256) p[c] *= inv;
}

__global__ __launch_bounds__(256) void pinv_rowcol_k(const float* __restrict__ a2,
                                                     float* __restrict__ rsum,
                                                     float* __restrict__ csum) {
  __shared__ float sb[4];
  int bh = blockIdx.x >> 8, i = blockIdx.x & 255;
  const float* base = a2 + ((size_t)bh << 16);
  int t = threadIdx.x;
  float rs = blockSum(fabsf(base[i * kM + t]), sb);
  float cs = blockSum(fabsf(base[t * kM + i]), sb);
  if (t == 0) {
    rsum[blockIdx.x] = rs;
    csum[blockIdx.x] = cs;
  }
}

__global__ __launch_bounds__(256) void pinv_gmax_k(const float* __restrict__ rsum,
                                                   const float* __restrict__ csum,
                                                   float* __restrict__ gmax) {
  __shared__ float sb[4];
  int t = threadIdx.x;
  float a = 0.f, b = 0.f;
  for (int j = t; j < kBH * kM; j += 256) {
    a = fmaxf(a, rsum[j]);
    b = fmaxf(b, csum[j]);
  }
  a = blockMax(a, sb);
  b = blockMax(b, sb);
  if (t == 0) {
    gmax[0] = a;
    gmax[1] = b;
  }
}

__global__ void pinv_init_k(const float* __restrict__ a2, const float* __restrict__ gmax,
                            __hip_bfloat16* __restrict__ z) {
  int i = blockIdx.x * 256 + threadIdx.x;
  if (i >= kBH * kM * kM) return;
  int col = i & 255, r = (i >> 8) & 255, bh = i >> 16;
  float denom = fmaxf(gmax[0] * gmax[1], 1e-30f);
  z[i] = f2b(a2[((size_t)bh << 16) + col * kM + r] / denom);
}

// ---------------- depthwise conv residual (LDS-tiled, vectorized) ----------------
// ao[b][n][h*64+dh] += sum_kk vv[bh][n+kk-16][dh] * w[h][kk]
// Block: one (bh, 128-row segment). Stage [160][64] bf16 window in LDS (row stride 72
// shorts = 144 B, breaks 32-bank period -> <=2-way conflicts). Each thread: 4 rows x 8 dh
// via a sliding 36-row window (36 ds_read_b128, 1056 FMA).
constexpr int kCR = 128;            // output rows per block
constexpr int kCHA = kCK / 2;       // 16 halo
constexpr int kCW = kCR + 2 * kCHA; // 160 staged rows
constexpr int kCP = 72;             // LDS row stride in shorts

__global__ __launch_bounds__(256) void conv_add2_k(const __hip_bfloat16* __restrict__ v,
                                                   const float* __restrict__ w,
                                                   __hip_bfloat16* __restrict__ ao) {
  __shared__ short Vt[kCW * kCP];
  __shared__ float wsh[kCK];
  const int t = threadIdx.x;
  const int bh = blockIdx.x >> 5;            // kN / kCR = 32 segments
  const int n0 = (blockIdx.x & 31) * kCR;
  const int b = bh >> 3, h = bh & 7;
  if (t < kCK) wsh[t] = w[h * kCK + t];
  const __hip_bfloat16* vbase = v + (size_t)bh * kN * kDH;
#pragma unroll
  for (int u = 0; u < (kCW * 8 + 255) / 256; ++u) {
    const int idx = u * 256 + t;
    if (idx < kCW * 8) {
      const int r = idx >> 3, c8 = (idx & 7) * 8;
      const int n = n0 - kCHA + r;
      uint4 d = {0u, 0u, 0u, 0u};
      if (n >= 0 && n < kN) d = *(const uint4*)(vbase + (size_t)n * kDH + c8);
      *(uint4*)&Vt[r * kCP + c8] = d;
    }
  }
  __syncthreads();
  const int dh8 = (t & 7) * 8;
  const int rg = (t >> 3) * 4;               // 32 row-groups x 4 rows = 128
  float acc[4][8] = {};
#pragma unroll
  for (int wd = 0; wd < kCK + 3; ++wd) {     // 36-row sliding window
    short8 v8 = *(const short8*)&Vt[(rg + wd) * kCP + dh8];
    float f[8];
#pragma unroll
    for (int e = 0; e < 8; ++e) f[e] = us2f((unsigned short)v8[e]);
#pragma unroll
    for (int i = 0; i < 4; ++i) {
      const int tap = wd - i;
      if (tap >= 0 && tap < kCK) {
        const float wt = wsh[tap];
#pragma unroll
        for (int e = 0; e < 8; ++e) acc[i][e] = fmaf(f[e], wt, acc[i][e]);
      }
    }
  }
#pragma unroll
  for (int i = 0; i < 4; ++i) {
    const int n = n0 + rg + i;
    __hip_bfloat16* ap = ao + ((size_t)(b * kN + n)) * kHD + h * kDH + dh8;
    uint4 d = *(const uint4*)ap;
    const unsigned short* us = (const unsigned short*)&d;
    unsigned short ov[8];
#pragma unroll
    for (int e = 0; e < 8; ++e) ov[e] = f2us(us2f(us[e]) + acc[i][e]);
    *(uint4*)ap = *(const uint4*)ov;
  }
}

// ---------------- MFMA flash attention ----------------
// O = softmax(Q @ K^T) @ V, 64 Q-rows per block, KV tiles of 256, online softmax.
// Fragment conventions identical to mgemm_k (mfma_f32_16x16x32_bf16):
//   A: row = lane&15 (+16i), k = (lane>>4)*8 + e (+32s)
//   B: col = lane&15 (+16j), k = (lane>>4)*8 + e (+32s)
//   C: row = (lane>>4)*4 + rg (+16i), col = lane&15 (+16j)
// Wave w owns KV columns [w*64, w*64+64) of each 256-wide tile; per-wave partial
// (O, l) combined through LDS at the end (m is shared across waves every tile).
constexpr int FP = 72;  // LDS row pad in shorts (144 B stride: 16B-aligned, 2-way max on b128)

template <bool A3>  // true : attn3 — Q=ql f32 [bh][256][64], K/V=kk/vv bf16 [bh][4096][64],
                    //        out w3 f32 [bh][256][64];  grid = kBH*4
                    // false: attn1 — Q=q bf16 [bh][4096][64], K=kl f32, V=y f32 [bh][256][64],
                    //        out ao bf16 scatter [b][n][h*64+dh]; grid = kBH*64
__global__ __launch_bounds__(256, 1) void fattn_k(const void* __restrict__ Qp,
                                                  const void* __restrict__ Kp,
                                                  const void* __restrict__ Vp,
                                                  void* __restrict__ Op) {
  __shared__ __align__(16) char smem[111616];
  short* Ks = (short*)smem;                    // [256][FP]  36864 B
  short* Vs = (short*)(smem + 36864);          // [256][FP]  36864 B
  short* Ps = (short*)(smem + 73728);          // 4 x [64][FP] (per-wave P slab) 36864 B
  float* wred = (float*)(smem + 110592);       // [4][64] cross-wave max / lsum
  float* Comb = (float*)smem;                  // [4][64][64] f32 epilogue alias (64 KB)

  const int t = threadIdx.x;
  const int lane = t & 63, wave = t >> 6;
  const int l15 = lane & 15, quad = lane >> 4;
  const int bh = A3 ? (blockIdx.x >> 2) : (blockIdx.x >> 6);
  const int q0 = A3 ? ((blockIdx.x & 3) * 64) : ((blockIdx.x & 63) * 64);
  const int NTILES = A3 ? (kN / 256) : 1;
  short* Psw = Ps + wave * 64 * FP;

  // ---- Q fragments in registers ----
  short8 aq[4][2];
#pragma unroll
  for (int i = 0; i < 4; ++i) {
    const long qrow = (A3 ? ((long)bh * kM) : ((long)bh * kN)) + q0 + i * 16 + l15;
#pragma unroll
    for (int s = 0; s < 2; ++s) {
      if constexpr (A3) {
        const f32x4* p = (const f32x4*)((const float*)Qp + qrow * kDH + quad * 8 + s * 32);
        f32x4 a = p[0], b = p[1];
        short8 v;
#pragma unroll
        for (int e = 0; e < 4; ++e) { v[e] = f2s(a[e]); v[4 + e] = f2s(b[e]); }
        aq[i][s] = v;
      } else {
        aq[i][s] =
            *(const short8*)((const __hip_bfloat16*)Qp + qrow * kDH + quad * 8 + s * 32);
      }
    }
  }

  f32x4 o[4][4] = {};
  float mrow[4][4], lrow[4][4];
#pragma unroll
  for (int i = 0; i < 4; ++i)
#pragma unroll
    for (int rg = 0; rg < 4; ++rg) {
      mrow[i][rg] = -1e30f;
      lrow[i][rg] = 0.f;
    }

  const long kvbase = (long)bh * (A3 ? kN : kM) * kDH;

  for (int tile = 0; tile < NTILES; ++tile) {
    // ---- stage K,V tile [256][64] -> LDS bf16 ----
    {
      const int r = t >> 2, c = (t & 3) * 16;
#pragma unroll
      for (int p = 0; p < 4; ++p) {
        const int rr = p * 64 + r;
        const long src = kvbase + (long)(tile * 256 + rr) * kDH + c;
        if constexpr (A3) {
          const uint4* ks = (const uint4*)((const __hip_bfloat16*)Kp + src);
          const uint4* vs = (const uint4*)((const __hip_bfloat16*)Vp + src);
          *(uint4*)&Ks[rr * FP + c] = ks[0];
          *(uint4*)&Ks[rr * FP + c + 8] = ks[1];
          *(uint4*)&Vs[rr * FP + c] = vs[0];
          *(uint4*)&Vs[rr * FP + c + 8] = vs[1];
        } else {
          const f32x4* ks = (const f32x4*)((const float*)Kp + src);
          const f32x4* vs = (const f32x4*)((const float*)Vp + src);
          f32x4 k0 = ks[0], k1 = ks[1], k2 = ks[2], k3 = ks[3];
          f32x4 v0 = vs[0], v1 = vs[1], v2 = vs[2], v3 = vs[3];
          short8 ka, kb, va, vb;
#pragma unroll
          for (int e = 0; e < 4; ++e) {
            ka[e] = f2s(k0[e]); ka[4 + e] = f2s(k1[e]);
            kb[e] = f2s(k2[e]); kb[4 + e] = f2s(k3[e]);
            va[e] = f2s(v0[e]); va[4 + e] = f2s(v1[e]);
            vb[e] = f2s(v2[e]); vb[4 + e] = f2s(v3[e]);
          }
          *(short8*)&Ks[rr * FP + c] = ka;
          *(short8*)&Ks[rr * FP + c + 8] = kb;
          *(short8*)&Vs[rr * FP + c] = va;
          *(short8*)&Vs[rr * FP + c + 8] = vb;
        }
      }
    }
    __syncthreads();

    // ---- S = Q @ K^T  (wave's 64x64 slab of the 64x256 tile) ----
    f32x4 sacc[4][4] = {};
#pragma unroll
    for (int s = 0; s < 2; ++s) {
      short8 bk[4];
#pragma unroll
      for (int j = 0; j < 4; ++j)
        bk[j] = *(const short8*)&Ks[(wave * 64 + j * 16 + l15) * FP + quad * 8 + s * 32];
#pragma unroll
      for (int i = 0; i < 4; ++i)
#pragma unroll
        for (int j = 0; j < 4; ++j)
          sacc[i][j] =
              __builtin_amdgcn_mfma_f32_16x16x32_bf16(aq[i][s], bk[j], sacc[i][j], 0, 0, 0);
    }

    // ---- per-row max: lane-local over j, then over l15 group, then cross-wave ----
    float pmax[4][4];
#pragma unroll
    for (int i = 0; i < 4; ++i)
#pragma unroll
      for (int rg = 0; rg < 4; ++rg) {
        float v = fmaxf(fmaxf(sacc[i][0][rg], sacc[i][1][rg]),
                        fmaxf(sacc[i][2][rg], sacc[i][3][rg]));
#pragma unroll
        for (int d = 1; d < 16; d <<= 1) v = fmaxf(v, __shfl_xor(v, d, 64));
        pmax[i][rg] = v;
      }
    if (l15 == 0) {
#pragma unroll
      for (int i = 0; i < 4; ++i)
#pragma unroll
        for (int rg = 0; rg < 4; ++rg)
          wred[wave * 64 + i * 16 + quad * 4 + rg] = pmax[i][rg];
    }
    __syncthreads();

    // ---- online rescale + exp + P repack (bf16, own-wave LDS slab) ----
#pragma unroll
    for (int i = 0; i < 4; ++i)
#pragma unroll
      for (int rg = 0; rg < 4; ++rg) {
        const int row = i * 16 + quad * 4 + rg;
        float tm =
            fmaxf(fmaxf(wred[row], wred[64 + row]), fmaxf(wred[128 + row], wred[192 + row]));
        float mn = fmaxf(mrow[i][rg], tm);
        float c = expf(mrow[i][rg] - mn);
        mrow[i][rg] = mn;
        lrow[i][rg] *= c;
#pragma unroll
        for (int j = 0; j < 4; ++j) o[i][j][rg] *= c;
      }
#pragma unroll
    for (int i = 0; i < 4; ++i)
#pragma unroll
      for (int rg = 0; rg < 4; ++rg) {
        float ls = 0.f;
#pragma unroll
        for (int j = 0; j < 4; ++j) {
          float e = expf(sacc[i][j][rg] - mrow[i][rg]);  // <= 0 exponent by construction
          ls += e;
          Psw[(i * 16 + quad * 4 + rg) * FP + j * 16 + l15] = f2s(e);
        }
#pragma unroll
        for (int d = 1; d < 16; d <<= 1) ls += __shfl_xor(ls, d, 64);
        lrow[i][rg] += ls;
      }

    // ---- O += P @ V  (A from own-wave P slab, B gathered from Vs rows of own slab) ----
#pragma unroll
    for (int s = 0; s < 2; ++s) {
      short8 ap[4];
#pragma unroll
      for (int i = 0; i < 4; ++i)
        ap[i] = *(const short8*)&Psw[(i * 16 + l15) * FP + quad * 8 + s * 32];
      short8 bv[4];
#pragma unroll
      for (int j = 0; j < 4; ++j)
#pragma unroll
        for (int e = 0; e < 8; ++e)
          bv[j][e] = Vs[(wave * 64 + s * 32 + quad * 8 + e) * FP + j * 16 + l15];
#pragma unroll
      for (int i = 0; i < 4; ++i)
#pragma unroll
        for (int j = 0; j < 4; ++j)
          o[i][j] = __builtin_amdgcn_mfma_f32_16x16x32_bf16(ap[i], bv[j], o[i][j], 0, 0, 0);
    }
    __syncthreads();
  }

  // ---- cross-wave combine: O = sum_w O_w, l = sum_w l_w; write out ----
#pragma unroll
  for (int i = 0; i < 4; ++i)
#pragma unroll
    for (int j = 0; j < 4; ++j)
#pragma unroll
      for (int rg = 0; rg < 4; ++rg)
        Comb[wave * 4096 + (i * 16 + quad * 4 + rg) * 64 + j * 16 + l15] = o[i][j][rg];
  if (l15 == 0) {
#pragma unroll
    for (int i = 0; i < 4; ++i)
#pragma unroll
      for (int rg = 0; rg < 4; ++rg)
        wred[wave * 64 + i * 16 + quad * 4 + rg] = lrow[i][rg];
  }
  __syncthreads();
#pragma unroll
  for (int u = 0; u < 16; ++u) {
    const int idx = u * 256 + t;
    const int row = idx >> 6, dh = idx & 63;
    float v = Comb[idx] + Comb[4096 + idx] + Comb[8192 + idx] + Comb[12288 + idx];
    float linv = 1.0f / (wred[row] + wred[64 + row] + wred[128 + row] + wred[192 + row]);
    if constexpr (A3) {
      ((float*)Op)[((size_t)bh * kM + q0 + row) * kDH + dh] = v * linv;
    } else {
      const int b = bh >> 3, h = bh & 7;
      ((__hip_bfloat16*)Op)[((size_t)(b * kN + q0 + row)) * kHD + h * kDH + dh] =
          f2b(v * linv);
    }
  }
}

// ---------------- epilogue / arg pack ----------------
constexpr int EPI_F32 = 0, EPI_QKV = 1, EPI_BIAS_F32 = 2, EPI_GELU_BF16 = 3, EPI_RES_OUT = 4,
              EPI_BF16 = 5;

struct EpiArgs {
  const float* bias;
  const float* res;
  __hip_bfloat16* oq;
  __hip_bfloat16* ok;
  __hip_bfloat16* ov;
  __hip_bfloat16* obf;
  const float* stats;
  const float* g;
  const float* be;
  void* ovoid;
  const int* flag;
  float eyeC;
  float eyeS;
};

// ---------------- MFMA bf16 GEMM: 128x128 tile, BK=32, 4 waves ----------------
// A [M][K] (bf16, or f32 with fused LN when LNA). B bf16: TRB -> [N][K]; else [K][N]
// (gather staging, optional fused (eyeC*I - B)*eyeS transform). f32 accumulate.
template <int EPI, bool TRB, bool BEYE, bool LNA, class TAT>
__global__ __launch_bounds__(256) void mgemm_k(const TAT* __restrict__ A, int lda, long sA,
                                               const __hip_bfloat16* __restrict__ B, int ldb,
                                               long sB, float* __restrict__ C, int ldc, long sC,
                                               int K, EpiArgs ep) {
  __shared__ short As[128 * 40];
  __shared__ short Bs[128 * 40];
  A += (long)blockIdx.z * sA;
  B += (long)blockIdx.z * sB;
  const long cbase = (long)blockIdx.z * sC;
  const int row0 = blockIdx.x * 128, col0 = blockIdx.y * 128;
  const int t = threadIdx.x;
  const int lane = t & 63, wave = t >> 6;
  const int wr = (wave >> 1) * 64, wc = (wave & 1) * 64;
  const int l15 = lane & 15, quad = lane >> 4;
  f32x4 acc[4][4] = {};
  for (int k0 = 0; k0 < K; k0 += 32) {
    // ---- stage A (128x32) ----
    {
      const int kc = (t & 3) * 8;
#pragma unroll
      for (int p = 0; p < 2; ++p) {
        const int m = p * 64 + (t >> 2);
        const long r = row0 + m;
        if constexpr (LNA) {
          const float* ap = (const float*)A + r * lda + k0 + kc;
          float mu = ep.stats[2 * r], rs = ep.stats[2 * r + 1];
          short8 vv;
#pragma unroll
          for (int e = 0; e < 8; ++e)
            vv[e] = f2s((ap[e] - mu) * rs * ep.g[k0 + kc + e] + ep.be[k0 + kc + e]);
          *(short8*)(&As[m * 40 + kc]) = vv;
        } else {
          uint4 u = *(const uint4*)((const __hip_bfloat16*)A + r * lda + k0 + kc);
          *(uint4*)(&As[m * 40 + kc]) = u;
        }
      }
    }
    // ---- stage B (as [n][k]) ----
    if (TRB) {
      const int kc = (t & 3) * 8;
#pragma unroll
      for (int p = 0; p < 2; ++p) {
        const int n = p * 64 + (t >> 2);
        uint4 u = *(const uint4*)(B + (long)(col0 + n) * ldb + k0 + kc);
        *(uint4*)(&Bs[n * 40 + kc]) = u;
      }
    } else {
      const int k8 = (t & 3) * 8;
#pragma unroll
      for (int p = 0; p < 2; ++p) {
        const int n = p * 64 + (t >> 2);
        short8 vv;
#pragma unroll
        for (int e = 0; e < 8; ++e) {
          float v = toF(B[(long)(k0 + k8 + e) * ldb + col0 + n]);
          if constexpr (BEYE) v = (((k0 + k8 + e) == (col0 + n)) ? ep.eyeC : 0.0f) - v;
          vv[e] = f2s(BEYE ? v * ep.eyeS : v);
        }
        *(short8*)(&Bs[n * 40 + k8]) = vv;
      }
    }
    __syncthreads();
    short8 af[4], bf[4];
#pragma unroll
    for (int i = 0; i < 4; ++i)
      af[i] = *(const short8*)(&As[(wr + i * 16 + l15) * 40 + quad * 8]);
#pragma unroll
    for (int j = 0; j < 4; ++j)
      bf[j] = *(const short8*)(&Bs[(wc + j * 16 + l15) * 40 + quad * 8]);
#pragma unroll
    for (int i = 0; i < 4; ++i)
#pragma unroll
      for (int j = 0; j < 4; ++j)
        acc[i][j] = __builtin_amdgcn_mfma_f32_16x16x32_bf16(af[i], bf[j], acc[i][j], 0, 0, 0);
    __syncthreads();
  }
  // ---- epilogue (C/D: col=lane&15, row=quad*4+reg) ----
#pragma unroll
  for (int i = 0; i < 4; ++i) {
#pragma unroll
    for (int j = 0; j < 4; ++j) {
#pragma unroll
      for (int rg = 0; rg < 4; ++rg) {
        int r = row0 + wr + i * 16 + quad * 4 + rg;
        int c = col0 + wc + j * 16 + l15;
        float v = acc[i][j][rg];
        if (EPI == EPI_BF16) {
          ep.obf[cbase + (long)r * ldc + c] = f2b(v);
        } else if (EPI == EPI_QKV) {
          int three = c >> 9, h = (c >> 6) & 7, dh = c & 63;
          int b = r >> 12, n = r & (kN - 1);
          long dst = ((long)(b * kH + h) * kN + n) * kDH + dh;
          if (three == 0)
            ep.oq[dst] = f2b(v * 0.125f);
          else if (three == 1)
            ep.ok[dst] = f2b(v);
          else
            ep.ov[dst] = f2b(v);
        } else if (EPI == EPI_BIAS_F32) {
          C[cbase + (long)r * ldc + c] = v + ep.bias[c];
        } else if (EPI == EPI_GELU_BF16) {
          v += ep.bias[c];
          ep.obf[cbase + (long)r * ldc + c] =
              f2b(0.5f * v * (1.0f + erff(v * 0.70710678118654752f)));
        } else if (EPI == EPI_RES_OUT) {
          long idx = cbase + (long)r * ldc + c;
          float v2 = v + ep.bias[c] + ep.res[idx];
          if (!(v2 == v2)) v2 = 0.0f;
          if (*ep.flag)
            ((__hip_bfloat16*)ep.ovoid)[idx] = f2b(v2);
          else
            ((float*)ep.ovoid)[idx] = v2;
        }
      }
    }
  }
}

// ---------------- fp32 vector GEMM (for small/odd shapes: sim2, y) ----------------
template <int EPI, bool TRB, class TAT, class TBT>
__global__ __launch_bounds__(256) void gemm_k(const TAT* __restrict__ A, int lda, long sA,
                                              const TBT* __restrict__ B, int ldb, long sB,
                                              float* __restrict__ C, int ldc, long sC, int K,
                                              EpiArgs ep) {
  __shared__ float As[16][68];
  __shared__ float Bs[16][68];
  A += (long)blockIdx.z * sA;
  B += (long)blockIdx.z * sB;
  const long cbase = (long)blockIdx.z * sC;
  const int row0 = blockIdx.x * 64, col0 = blockIdx.y * 64;
  const int t = threadIdx.x;
  const int ty = t >> 4, tx = t & 15;
  float acc[4][4] = {{0.f, 0.f, 0.f, 0.f}, {0.f, 0.f, 0.f, 0.f},
                     {0.f, 0.f, 0.f, 0.f}, {0.f, 0.f, 0.f, 0.f}};
  const int ka = t & 15, ra = t >> 4;
  for (int k0 = 0; k0 < K; k0 += 16) {
#pragma unroll
    for (int j = 0; j < 4; ++j)
      As[ka][ra + 16 * j] = toF(A[(long)(row0 + ra + 16 * j) * lda + (k0 + ka)]);
    if (TRB) {
#pragma unroll
      for (int j = 0; j < 4; ++j)
        Bs[ka][ra + 16 * j] = toF(B[(long)(col0 + ra + 16 * j) * ldb + (k0 + ka)]);
    } else {
      const int jb = t & 63, kb = t >> 6;
#pragma unroll
      for (int j = 0; j < 4; ++j)
        Bs[kb + 4 * j][jb] = toF(B[(long)(k0 + kb + 4 * j) * ldb + (col0 + jb)]);
    }
    __syncthreads();
#pragma unroll
    for (int kk = 0; kk < 16; ++kk) {
      float av[4], bv[4];
#pragma unroll
      for (int i = 0; i < 4; ++i) av[i] = As[kk][ty * 4 + i];
#pragma unroll
      for (int j = 0; j < 4; ++j) bv[j] = Bs[kk][tx * 4 + j];
#pragma unroll
      for (int i = 0; i < 4; ++i)
#pragma unroll
        for (int j = 0; j < 4; ++j) acc[i][j] += av[i] * bv[j];
    }
    __syncthreads();
  }
#pragma unroll
  for (int i = 0; i < 4; ++i) {
    int r = row0 + ty * 4 + i;
#pragma unroll
    for (int j = 0; j < 4; ++j) {
      int c = col0 + tx * 4 + j;
      C[cbase + (long)r * ldc + c] = acc[i][j];
    }
  }
}

}  // namespace

extern "C" void kernel_launch(void* const* d_in, const int* in_sizes, int n_in, void* d_out,
                              int out_size, void* d_ws, size_t ws_size, hipStream_t stream) {
  (void)in_sizes; (void)n_in; (void)out_size;

  char* base = (char*)d_ws;
  size_t off = 0;
  auto alloc = [&](size_t bytes) {
    char* p = base + off;
    off = (off + bytes + 255) & ~(size_t)255;
    return p;
  };
  // a2 + 4 pinv slots (slots sized for f32 to keep hbuf contiguity; used as bf16)
  float* a2 = (float*)alloc((size_t)kBH * kM * kM * 4);  // 16.78 MB
  __hip_bfloat16* zs0 = (__hip_bfloat16*)alloc((size_t)kBH * kM * kM * 4);
  __hip_bfloat16* zs1 = (__hip_bfloat16*)alloc((size_t)kBH * kM * kM * 4);
  __hip_bfloat16* zs2 = (__hip_bfloat16*)alloc((size_t)kBH * kM * kM * 4);
  __hip_bfloat16* zs3 = (__hip_bfloat16*)alloc((size_t)kBH * kM * kM * 4);
  __hip_bfloat16* a2b = (__hip_bfloat16*)alloc((size_t)kBH * kM * kM * 2);  // 8.39 MB
  // bf16 qkv + attn-out region (hosts MLP hidden late: 134.2 MB contiguous)
  __hip_bfloat16* q = (__hip_bfloat16*)alloc((size_t)kBH * kN * kDH * 2);
  __hip_bfloat16* kk = (__hip_bfloat16*)alloc((size_t)kBH * kN * kDH * 2);
  __hip_bfloat16* vv = (__hip_bfloat16*)alloc((size_t)kBH * kN * kDH * 2);
  __hip_bfloat16* ao = (__hip_bfloat16*)alloc((size_t)kBN * kHD * 2);
  float* ql = (float*)alloc((size_t)kBH * kM * kDH * 4);
  float* kl = (float*)alloc((size_t)kBH * kM * kDH * 4);
  float* w3 = (float*)alloc((size_t)kBH * kM * kDH * 4);
  float* y = (float*)alloc((size_t)kBH * kM * kDH * 4);
  float* st2 = (float*)alloc((size_t)kBN * 2 * 4);
  float* rsum = (float*)alloc((size_t)kBH * kM * 4);
  float* csum = (float*)alloc((size_t)kBH * kM * 4);
  float* gmax = (float*)alloc(256);
  int* dflag = (int*)alloc(256);
  // transposed bf16 weights
  __hip_bfloat16* WqkvT = (__hip_bfloat16*)alloc((size_t)kQKVC * kD * 2);
  __hip_bfloat16* WoutT = (__hip_bfloat16*)alloc((size_t)kD * kHD * 2);
  __hip_bfloat16* W1T = (__hip_bfloat16*)alloc((size_t)kD4 * kD * 2);
  __hip_bfloat16* W2T = (__hip_bfloat16*)alloc((size_t)kD * kD4 * 2);
  float* bout_f = (float*)alloc(kD * 4);
  float* b1_f = (float*)alloc(kD4 * 4);
  float* b2_f = (float*)alloc(kD * 4);
  float* convw_f = (float*)alloc(kH * kCK * 4);
  float* g1_f = (float*)alloc(kD * 4);
  float* be1_f = (float*)alloc(kD * 4);
  float* g2_f = (float*)alloc(kD * 4);
  float* be2_f = (float*)alloc(kD * 4);
  // lifetime-disjoint aliases
  __hip_bfloat16* hln = (__hip_bfloat16*)a2;  // LN1 out, spans a2+zs0+half zs1, dead pre-sim2
  float* hbuf = a2;                           // Wout out f32 67.1MB, spans a2+zs0..zs2
  __hip_bfloat16* hidden = q;                 // MLP hidden bf16 134.2MB, spans q..ao

  if (off > ws_size) return;  // deterministic guard

  detect_k<<<1, 256, 0, stream>>>((const unsigned*)d_in[0], dflag);

  auto cvt = [&](const void* src, float* dst, int n) {
    cvt_any_k<<<(n + 255) / 256, 256, 0, stream>>>(src, dst, n, dflag);
  };
  cvtT_k<<<(kD * kQKVC + 255) / 256, 256, 0, stream>>>(d_in[1], WqkvT, kD, kQKVC, dflag);
  cvtT_k<<<(kHD * kD + 255) / 256, 256, 0, stream>>>(d_in[2], WoutT, kHD, kD, dflag);
  cvtT_k<<<(kD * kD4 + 255) / 256, 256, 0, stream>>>(d_in[9], W1T, kD, kD4, dflag);
  cvtT_k<<<(kD4 * kD + 255) / 256, 256, 0, stream>>>(d_in[11], W2T, kD4, kD, dflag);
  cvt(d_in[3], bout_f, kD);
  cvt(d_in[4], convw_f, kH * kCK);
  cvt(d_in[5], g1_f, kD);
  cvt(d_in[6], be1_f, kD);
  cvt(d_in[7], g2_f, kD);
  cvt(d_in[8], be2_f, kD);
  cvt(d_in[10], b1_f, kD4);
  cvt(d_in[12], b2_f, kD);

  EpiArgs e0 = {};

  // LN1 -> hln (bf16)
  ln1_k<<<kBN, 256, 0, stream>>>(d_in[0], g1_f, be1_f, hln, dflag);

  // QKV: hln @ WqkvT^T (MFMA, scatter epilogue)
  EpiArgs eq = {};
  eq.oq = q; eq.ok = kk; eq.ov = vv;
  mgemm_k<EPI_QKV, true, false, false, __hip_bfloat16>
      <<<dim3(kBN / 128, kQKVC / 128, 1), 256, 0, stream>>>(hln, kD, 0, WqkvT, kD, 0, nullptr, 0,
                                                            0, kD, eq);

  landmark_k<<<(kBH * kM * kDH + 255) / 256, 256, 0, stream>>>(q, ql);
  landmark_k<<<(kBH * kM * kDH + 255) / 256, 256, 0, stream>>>(kk, kl);

  const long sQL = (long)kM * kDH, sA2 = (long)kM * kM;

  // sim2 = q_l @ k_l^T (f32) ; softmax
  gemm_k<EPI_F32, true, float, float><<<dim3(kM / 64, kM / 64, kBH), 256, 0, stream>>>(
      ql, kDH, sQL, kl, kDH, sQL, a2, kM, sA2, kDH, e0);
  softmax_k<<<kBH * kM, 256, 0, stream>>>(a2, kM);

  // pinv setup
  f32tob16_k<<<(kBH * kM * kM + 255) / 256, 256, 0, stream>>>(a2, a2b, kBH * kM * kM);
  pinv_rowcol_k<<<kBH * kM, 256, 0, stream>>>(a2, rsum, csum);
  pinv_gmax_k<<<1, 256, 0, stream>>>(rsum, csum, gmax);
  pinv_init_k<<<(kBH * kM * kM + 255) / 256, 256, 0, stream>>>(a2, gmax, zs0);

  // Newton-Schulz: 4 MFMA GEMMs/iter, eye-ops fused into B staging
  __hip_bfloat16* bufs[4] = {zs0, zs1, zs2, zs3};
  int zi = 0;
  dim3 gP(kM / 128, kM / 128, kBH);
  for (int it = 0; it < 6; ++it) {
    int o0 = (zi + 1) & 3, o1 = (zi + 2) & 3, o2 = (zi + 3) & 3;
    __hip_bfloat16* Z = bufs[zi];
    __hip_bfloat16* T1 = bufs[o0];
    __hip_bfloat16* T3 = bufs[o1];
    __hip_bfloat16* P3 = bufs[o2];
    EpiArgs ep1 = {}; ep1.obf = T1;
    mgemm_k<EPI_BF16, false, false, false, __hip_bfloat16><<<gP, 256, 0, stream>>>(
        a2b, kM, sA2, Z, kM, sA2, nullptr, kM, sA2, kM, ep1);
    EpiArgs ep2 = {}; ep2.obf = T3; ep2.eyeC = 7.0f; ep2.eyeS = 1.0f;
    mgemm_k<EPI_BF16, false, true, false, __hip_bfloat16><<<gP, 256, 0, stream>>>(
        T1, kM, sA2, T1, kM, sA2, nullptr, kM, sA2, kM, ep2);
    EpiArgs ep3 = {}; ep3.obf = P3; ep3.eyeC = 15.0f; ep3.eyeS = 1.0f;
    mgemm_k<EPI_BF16, false, true, false, __hip_bfloat16><<<gP, 256, 0, stream>>>(
        T1, kM, sA2, T3, kM, sA2, nullptr, kM, sA2, kM, ep3);
    EpiArgs ep4 = {}; ep4.obf = T3; ep4.eyeC = 13.0f; ep4.eyeS = 0.25f;
    mgemm_k<EPI_BF16, false, true, false, __hip_bfloat16><<<gP, 256, 0, stream>>>(
        Z, kM, sA2, P3, kM, sA2, nullptr, kM, sA2, kM, ep4);
    zi = o1;
  }
  __hip_bfloat16* zfin = bufs[zi];

  // w3 = softmax(q_l @ k^T) @ v  (MFMA flash attention)
  fattn_k<true><<<kBH * (kM / 64), 256, 0, stream>>>(ql, kk, vv, w3);

  // y = z @ w3 (f32 vector gemm; N=64)
  gemm_k<EPI_F32, false, __hip_bfloat16, float><<<dim3(kM / 64, 1, kBH), 256, 0, stream>>>(
      zfin, kM, sA2, w3, kDH, sQL, y, kDH, sQL, kM, e0);

  // ao = softmax(q @ k_l^T) @ y  (MFMA flash attention, merged layout)
  fattn_k<false><<<kBH * (kN / 64), 256, 0, stream>>>(q, kl, y, ao);

  // + depthwise conv residual (LDS-tiled)
  conv_add2_k<<<kBH * (kN / kCR), 256, 0, stream>>>(vv, convw_f, ao);

  // hbuf = ao @ WoutT^T + bout (MFMA, f32 out)
  EpiArgs ew = {}; ew.bias = bout_f;
  mgemm_k<EPI_BIAS_F32, true, false, false, __hip_bfloat16>
      <<<dim3(kBN / 128, kD / 128, 1), 256, 0, stream>>>(ao, kHD, 0, WoutT, kHD, 0, hbuf, kD, 0,
                                                         kHD, ew);

  // LN2 stats; MLP1 (LN fused in A-staging, +bias+GELU -> bf16 hidden)
  ln2stats_k<<<kBN, 256, 0, stream>>>(hbuf, st2);
  EpiArgs e1 = {}; e1.bias = b1_f; e1.stats = st2; e1.g = g2_f; e1.be = be2_f; e1.obf = hidden;
  mgemm_k<EPI_GELU_BF16, true, false, true, float>
      <<<dim3(kBN / 128, kD4 / 128, 1), 256, 0, stream>>>(hbuf, kD, 0, W1T, kD, 0, nullptr, kD4,
                                                          0, kD, e1);

  // MLP2 (+bias+residual -> flag-typed out)
  EpiArgs e2 = {}; e2.bias = b2_f; e2.res = hbuf; e2.ovoid = d_out; e2.flag = dflag;
  mgemm_k<EPI_RES_OUT, true, false, false, __hip_bfloat16>
      <<<dim3(kBN / 128, kD / 128, 1), 256, 0, stream>>>(hidden, kD4, 0, W2T, kD4, 0, nullptr,
                                                         kD, 0, kD4, e2);
}

// Round 4
// 1586.965 us; speedup vs baseline: 2.3486x; 1.0105x over previous
//
#include <hip/hip_runtime.h>
#include <hip/hip_bf16.h>
#include <cmath>

#define DEV __device__ __forceinline__

namespace {

constexpr int kB = 8, kN = 4096, kD = 512, kH = 8, kDH = 64, kM = 256, kL = 16, kCK = 33;
constexpr int kBN = kB * kN;     // 32768
constexpr int kBH = kB * kH;     // 64
constexpr int kHD = kH * kDH;    // 512
constexpr int kD4 = 4 * kD;      // 2048
constexpr int kQKVC = 3 * kHD;   // 1536

typedef __attribute__((ext_vector_type(8))) short short8;
typedef __attribute__((ext_vector_type(4))) float f32x4;

DEV float toF(float x) { return x; }
DEV float toF(__hip_bfloat16 x) { return __bfloat162float(x); }
DEV __hip_bfloat16 f2b(float f) { return __float2bfloat16(f); }
DEV short f2s(float f) {
  __hip_bfloat16 h = __float2bfloat16(f);
  return *reinterpret_cast<short*>(&h);
}
DEV float us2f(unsigned short u) { return __uint_as_float((unsigned)u << 16); }
DEV unsigned short f2us(float f) {
  __hip_bfloat16 h = __float2bfloat16(f);
  return *reinterpret_cast<unsigned short*>(&h);
}

// async global->LDS, 16 B per lane; dest must be wave-linear (base + lane*16)
DEV void gload16(const void* g, void* l) {
  __builtin_amdgcn_global_load_lds(
      (const __attribute__((address_space(1))) unsigned*)g,
      (__attribute__((address_space(3))) unsigned*)l, 16, 0, 0);
}

DEV float waveSum(float v) {
#pragma unroll
  for (int o = 32; o > 0; o >>= 1) v += __shfl_down(v, o, 64);
  return v;
}
DEV float waveMax(float v) {
#pragma unroll
  for (int o = 32; o > 0; o >>= 1) v = fmaxf(v, __shfl_down(v, o, 64));
  return v;
}
DEV float blockSum(float v, float* sb) {
  v = waveSum(v);
  int lane = threadIdx.x & 63, w = threadIdx.x >> 6;
  __syncthreads();
  if (lane == 0) sb[w] = v;
  __syncthreads();
  return sb[0] + sb[1] + sb[2] + sb[3];
}
DEV float blockMax(float v, float* sb) {
  v = waveMax(v);
  int lane = threadIdx.x & 63, w = threadIdx.x >> 6;
  __syncthreads();
  if (lane == 0) sb[w] = v;
  __syncthreads();
  return fmaxf(fmaxf(sb[0], sb[1]), fmaxf(sb[2], sb[3]));
}

// ---------------- runtime dtype detection ----------------
__global__ __launch_bounds__(256) void detect_k(const unsigned* __restrict__ x,
                                                int* __restrict__ flag) {
  __shared__ int sc[4];
  int t = threadIdx.x;
  int cb = 0;
  for (int i = t; i < 4096; i += 256) {
    unsigned w = x[i];
    float b0 = __uint_as_float(w << 16);
    float b1 = __uint_as_float(w & 0xffff0000u);
    if (fabsf(b0) < 64.0f && (b0 == 0.0f || fabsf(b0) > 1e-20f)) cb++;
    if (fabsf(b1) < 64.0f && (b1 == 0.0f || fabsf(b1) > 1e-20f)) cb++;
  }
#pragma unroll
  for (int o = 32; o > 0; o >>= 1) cb += __shfl_down(cb, o, 64);
  if ((t & 63) == 0) sc[t >> 6] = cb;
  __syncthreads();
  if (t == 0) flag[0] = (sc[0] + sc[1] + sc[2] + sc[3] > 7373) ? 1 : 0;  // 1 = bf16 inputs
}

__global__ void cvt_any_k(const void* __restrict__ s, float* __restrict__ d, int n,
                          const int* __restrict__ flag) {
  int i = blockIdx.x * 256 + threadIdx.x;
  if (i >= n) return;
  if (*flag)
    d[i] = toF(((const __hip_bfloat16*)s)[i]);
  else
    d[i] = ((const float*)s)[i];
}

// weight [K][N] -> bf16 transposed [N][K]
__global__ void cvtT_k(const void* __restrict__ s, __hip_bfloat16* __restrict__ d, int K, int N,
                       const int* __restrict__ flag) {
  int i = blockIdx.x * 256 + threadIdx.x;
  if (i >= N * K) return;
  int n = i / K, k = i - n * K;
  float v = (*flag) ? toF(((const __hip_bfloat16*)s)[(long)k * N + n])
                    : ((const float*)s)[(long)k * N + n];
  d[i] = f2b(v);
}

__global__ void f32tob16_k(const float* __restrict__ s, __hip_bfloat16* __restrict__ d, int n) {
  int i = blockIdx.x * 256 + threadIdx.x;
  if (i < n) d[i] = f2b(s[i]);
}

// ---------------- LN kernels ----------------

__global__ __launch_bounds__(256) void ln1_k(const void* __restrict__ xv,
                                             const float* __restrict__ g,
                                             const float* __restrict__ be,
                                             __hip_bfloat16* __restrict__ o,
                                             const int* __restrict__ flag) {
  __shared__ float sb[4];
  size_t row = blockIdx.x;
  __hip_bfloat16* po = o + row * kD;
  int t = threadIdx.x;
  float v0, v1;
  if (*flag) {
    const __hip_bfloat16* pr = (const __hip_bfloat16*)xv + row * kD;
    v0 = toF(pr[t]);
    v1 = toF(pr[t + 256]);
  } else {
    const float* pr = (const float*)xv + row * kD;
    v0 = pr[t];
    v1 = pr[t + 256];
  }
  float s = blockSum(v0 + v1, sb);
  float ss = blockSum(v0 * v0 + v1 * v1, sb);
  float mu = s * (1.0f / kD);
  float var = ss * (1.0f / kD) - mu * mu;
  float rs = rsqrtf(var + 1e-5f);
  po[t] = f2b((v0 - mu) * rs * g[t] + be[t]);
  po[t + 256] = f2b((v1 - mu) * rs * g[t + 256] + be[t + 256]);
}

// LN2: f32 in -> bf16 out (materialized once; MLP1 consumes as plain bf16 GEMM A)
__global__ __launch_bounds__(256) void ln2_k(const float* __restrict__ x,
                                             const float* __restrict__ g,
                                             const float* __restrict__ be,
                                             __hip_bfloat16* __restrict__ o) {
  __shared__ float sb[4];
  size_t row = blockIdx.x;
  const float* pr = x + row * kD;
  __hip_bfloat16* po = o + row * kD;
  int t = threadIdx.x;
  float v0 = pr[t], v1 = pr[t + 256];
  float s = blockSum(v0 + v1, sb);
  float ss = blockSum(v0 * v0 + v1 * v1, sb);
  float mu = s * (1.0f / kD);
  float var = ss * (1.0f / kD) - mu * mu;
  float rs = rsqrtf(var + 1e-5f);
  po[t] = f2b((v0 - mu) * rs * g[t] + be[t]);
  po[t + 256] = f2b((v1 - mu) * rs * g[t + 256] + be[t + 256]);
}

// ---------------- small helpers ----------------

__global__ void landmark_k(const __hip_bfloat16* __restrict__ src, float* __restrict__ dst) {
  int i = blockIdx.x * 256 + threadIdx.x;
  if (i >= kBH * kM * kDH) return;
  int dh = i & 63, m = (i >> 6) & 255, bh = i >> 14;
  const __hip_bfloat16* p = src + ((size_t)bh * kN + m * kL) * kDH + dh;
  float s = 0.f;
#pragma unroll
  for (int l = 0; l < kL; ++l) s += toF(p[l * kDH]);
  dst[i] = s * (1.0f / kL);
}

__global__ __launch_bounds__(256) void softmax_k(float* __restrict__ X, int ncols) {
  __shared__ float sb[4];
  size_t row = blockIdx.x;
  float* p = X + row * ncols;
  int t = threadIdx.x;
  float mx = -1e30f;
  for (int c = t; c < ncols; c += 256) mx = fmaxf(mx, p[c]);
  mx = blockMax(mx, sb);
  float s = 0.f;
  for (int c = t; c < ncols; c += 256) {
    float e = expf(fminf(p[c] - mx, 0.0f));
    p[c] = e;
    s += e;
  }
  s = blockSum(s, sb);
  float inv = 1.0f / s;
  for (int c = t; c < ncols; c += 256) p[c] *= inv;
}

__global__ __launch_bounds__(256) void pinv_rowcol_k(const float* __restrict__ a2,
                                                     float* __restrict__ rsum,
                                                     float* __restrict__ csum) {
  __shared__ float sb[4];
  int bh = blockIdx.x >> 8, i = blockIdx.x & 255;
  const float* base = a2 + ((size_t)bh << 16);
  int t = threadIdx.x;
  float rs = blockSum(fabsf(base[i * kM + t]), sb);
  float cs = blockSum(fabsf(base[t * kM + i]), sb);
  if (t == 0) {
    rsum[blockIdx.x] = rs;
    csum[blockIdx.x] = cs;
  }
}

__global__ __launch_bounds__(256) void pinv_gmax_k(const float* __restrict__ rsum,
                                                   const float* __restrict__ csum,
                                                   float* __restrict__ gmax) {
  __shared__ float sb[4];
  int t = threadIdx.x;
  float a = 0.f, b = 0.f;
  for (int j = t; j < kBH * kM; j += 256) {
    a = fmaxf(a, rsum[j]);
    b = fmaxf(b, csum[j]);
  }
  a = blockMax(a, sb);
  b = blockMax(b, sb);
  if (t == 0) {
    gmax[0] = a;
    gmax[1] = b;
  }
}

__global__ void pinv_init_k(const float* __restrict__ a2, const float* __restrict__ gmax,
                            __hip_bfloat16* __restrict__ z) {
  int i = blockIdx.x * 256 + threadIdx.x;
  if (i >= kBH * kM * kM) return;
  int col = i & 255, r = (i >> 8) & 255, bh = i >> 16;
  float denom = fmaxf(gmax[0] * gmax[1], 1e-30f);
  z[i] = f2b(a2[((size_t)bh << 16) + col * kM + r] / denom);
}

// ---------------- depthwise conv residual (LDS-tiled, vectorized) ----------------
constexpr int kCR = 128;            // output rows per block
constexpr int kCHA = kCK / 2;       // 16 halo
constexpr int kCW = kCR + 2 * kCHA; // 160 staged rows
constexpr int kCP = 72;             // LDS row stride in shorts

__global__ __launch_bounds__(256) void conv_add2_k(const __hip_bfloat16* __restrict__ v,
                                                   const float* __restrict__ w,
                                                   __hip_bfloat16* __restrict__ ao) {
  __shared__ short Vt[kCW * kCP];
  __shared__ float wsh[kCK];
  const int t = threadIdx.x;
  const int bh = blockIdx.x >> 5;            // kN / kCR = 32 segments
  const int n0 = (blockIdx.x & 31) * kCR;
  const int b = bh >> 3, h = bh & 7;
  if (t < kCK) wsh[t] = w[h * kCK + t];
  const __hip_bfloat16* vbase = v + (size_t)bh * kN * kDH;
#pragma unroll
  for (int u = 0; u < (kCW * 8 + 255) / 256; ++u) {
    const int idx = u * 256 + t;
    if (idx < kCW * 8) {
      const int r = idx >> 3, c8 = (idx & 7) * 8;
      const int n = n0 - kCHA + r;
      uint4 d = {0u, 0u, 0u, 0u};
      if (n >= 0 && n < kN) d = *(const uint4*)(vbase + (size_t)n * kDH + c8);
      *(uint4*)&Vt[r * kCP + c8] = d;
    }
  }
  __syncthreads();
  const int dh8 = (t & 7) * 8;
  const int rg = (t >> 3) * 4;               // 32 row-groups x 4 rows = 128
  float acc[4][8] = {};
#pragma unroll
  for (int wd = 0; wd < kCK + 3; ++wd) {     // 36-row sliding window
    short8 v8 = *(const short8*)&Vt[(rg + wd) * kCP + dh8];
    float f[8];
#pragma unroll
    for (int e = 0; e < 8; ++e) f[e] = us2f((unsigned short)v8[e]);
#pragma unroll
    for (int i = 0; i < 4; ++i) {
      const int tap = wd - i;
      if (tap >= 0 && tap < kCK) {
        const float wt = wsh[tap];
#pragma unroll
        for (int e = 0; e < 8; ++e) acc[i][e] = fmaf(f[e], wt, acc[i][e]);
      }
    }
  }
#pragma unroll
  for (int i = 0; i < 4; ++i) {
    const int n = n0 + rg + i;
    __hip_bfloat16* ap = ao + ((size_t)(b * kN + n)) * kHD + h * kDH + dh8;
    uint4 d = *(const uint4*)ap;
    const unsigned short* us = (const unsigned short*)&d;
    unsigned short ov[8];
#pragma unroll
    for (int e = 0; e < 8; ++e) ov[e] = f2us(us2f(us[e]) + acc[i][e]);
    *(uint4*)ap = *(const uint4*)ov;
  }
}

// ---------------- MFMA flash attention ----------------
// O = softmax(Q @ K^T) @ V, 64 Q-rows per block, KV tiles of 256, online softmax.
// All operands bf16 (f32 side-inputs pre-converted on device).
constexpr int FP = 72;  // LDS row pad in shorts (144 B stride: 16B-aligned, 2-way max on b128)

template <bool A3>  // true : attn3 — Q [bh][256][64], K/V [bh][4096][64], out w3 f32; grid kBH*4
                    // false: attn1 — Q [bh][4096][64], K/V [bh][256][64],
                    //        out ao bf16 scatter [b][n][h*64+dh]; grid kBH*64
__global__ __launch_bounds__(256, 1) void fattn_k(const __hip_bfloat16* __restrict__ Qp,
                                                  const __hip_bfloat16* __restrict__ Kp,
                                                  const __hip_bfloat16* __restrict__ Vp,
                                                  void* __restrict__ Op) {
  __shared__ __align__(16) char smem[111616];
  short* Ks = (short*)smem;                    // [256][FP]  36864 B
  short* Vs = (short*)(smem + 36864);          // [256][FP]  36864 B
  short* Ps = (short*)(smem + 73728);          // 4 x [64][FP] (per-wave P slab) 36864 B
  float* wred = (float*)(smem + 110592);       // [4][64] cross-wave max / lsum
  float* Comb = (float*)smem;                  // [4][64][64] f32 epilogue alias (64 KB)

  const int t = threadIdx.x;
  const int lane = t & 63, wave = t >> 6;
  const int l15 = lane & 15, quad = lane >> 4;
  const int bh = A3 ? (blockIdx.x >> 2) : (blockIdx.x >> 6);
  const int q0 = A3 ? ((blockIdx.x & 3) * 64) : ((blockIdx.x & 63) * 64);
  const int NTILES = A3 ? (kN / 256) : 1;
  short* Psw = Ps + wave * 64 * FP;

  // ---- Q fragments in registers ----
  short8 aq[4][2];
#pragma unroll
  for (int i = 0; i < 4; ++i) {
    const long qrow = (A3 ? ((long)bh * kM) : ((long)bh * kN)) + q0 + i * 16 + l15;
#pragma unroll
    for (int s = 0; s < 2; ++s)
      aq[i][s] = *(const short8*)(Qp + qrow * kDH + quad * 8 + s * 32);
  }

  f32x4 o[4][4] = {};
  float mrow[4][4], lrow[4][4];
#pragma unroll
  for (int i = 0; i < 4; ++i)
#pragma unroll
    for (int rg = 0; rg < 4; ++rg) {
      mrow[i][rg] = -1e30f;
      lrow[i][rg] = 0.f;
    }

  const long kvbase = (long)bh * (A3 ? kN : kM) * kDH;

  for (int tile = 0; tile < NTILES; ++tile) {
    // ---- stage K,V tile [256][64] -> LDS ----
    {
      const int r = t >> 2, c = (t & 3) * 16;
#pragma unroll
      for (int p = 0; p < 4; ++p) {
        const int rr = p * 64 + r;
        const long src = kvbase + (long)(tile * 256 + rr) * kDH + c;
        const uint4* ks = (const uint4*)(Kp + src);
        const uint4* vs = (const uint4*)(Vp + src);
        *(uint4*)&Ks[rr * FP + c] = ks[0];
        *(uint4*)&Ks[rr * FP + c + 8] = ks[1];
        *(uint4*)&Vs[rr * FP + c] = vs[0];
        *(uint4*)&Vs[rr * FP + c + 8] = vs[1];
      }
    }
    __syncthreads();

    // ---- S = Q @ K^T  (wave's 64x64 slab of the 64x256 tile) ----
    f32x4 sacc[4][4] = {};
#pragma unroll
    for (int s = 0; s < 2; ++s) {
      short8 bk[4];
#pragma unroll
      for (int j = 0; j < 4; ++j)
        bk[j] = *(const short8*)&Ks[(wave * 64 + j * 16 + l15) * FP + quad * 8 + s * 32];
#pragma unroll
      for (int i = 0; i < 4; ++i)
#pragma unroll
        for (int j = 0; j < 4; ++j)
          sacc[i][j] =
              __builtin_amdgcn_mfma_f32_16x16x32_bf16(aq[i][s], bk[j], sacc[i][j], 0, 0, 0);
    }

    // ---- per-row max: lane-local over j, then over l15 group, then cross-wave ----
    float pmax[4][4];
#pragma unroll
    for (int i = 0; i < 4; ++i)
#pragma unroll
      for (int rg = 0; rg < 4; ++rg) {
        float v = fmaxf(fmaxf(sacc[i][0][rg], sacc[i][1][rg]),
                        fmaxf(sacc[i][2][rg], sacc[i][3][rg]));
#pragma unroll
        for (int d = 1; d < 16; d <<= 1) v = fmaxf(v, __shfl_xor(v, d, 64));
        pmax[i][rg] = v;
      }
    if (l15 == 0) {
#pragma unroll
      for (int i = 0; i < 4; ++i)
#pragma unroll
        for (int rg = 0; rg < 4; ++rg)
          wred[wave * 64 + i * 16 + quad * 4 + rg] = pmax[i][rg];
    }
    __syncthreads();

    // ---- online rescale + exp + P repack (bf16, own-wave LDS slab) ----
#pragma unroll
    for (int i = 0; i < 4; ++i)
#pragma unroll
      for (int rg = 0; rg < 4; ++rg) {
        const int row = i * 16 + quad * 4 + rg;
        float tm =
            fmaxf(fmaxf(wred[row], wred[64 + row]), fmaxf(wred[128 + row], wred[192 + row]));
        float mn = fmaxf(mrow[i][rg], tm);
        float c = expf(mrow[i][rg] - mn);
        mrow[i][rg] = mn;
        lrow[i][rg] *= c;
#pragma unroll
        for (int j = 0; j < 4; ++j) o[i][j][rg] *= c;
      }
#pragma unroll
    for (int i = 0; i < 4; ++i)
#pragma unroll
      for (int rg = 0; rg < 4; ++rg) {
        float ls = 0.f;
#pragma unroll
        for (int j = 0; j < 4; ++j) {
          float e = expf(sacc[i][j][rg] - mrow[i][rg]);  // <= 0 exponent by construction
          ls += e;
          Psw[(i * 16 + quad * 4 + rg) * FP + j * 16 + l15] = f2s(e);
        }
#pragma unroll
        for (int d = 1; d < 16; d <<= 1) ls += __shfl_xor(ls, d, 64);
        lrow[i][rg] += ls;
      }

    // ---- O += P @ V ----
#pragma unroll
    for (int s = 0; s < 2; ++s) {
      short8 ap[4];
#pragma unroll
      for (int i = 0; i < 4; ++i)
        ap[i] = *(const short8*)&Psw[(i * 16 + l15) * FP + quad * 8 + s * 32];
      short8 bv[4];
#pragma unroll
      for (int j = 0; j < 4; ++j)
#pragma unroll
        for (int e = 0; e < 8; ++e)
          bv[j][e] = Vs[(wave * 64 + s * 32 + quad * 8 + e) * FP + j * 16 + l15];
#pragma unroll
      for (int i = 0; i < 4; ++i)
#pragma unroll
        for (int j = 0; j < 4; ++j)
          o[i][j] = __builtin_amdgcn_mfma_f32_16x16x32_bf16(ap[i], bv[j], o[i][j], 0, 0, 0);
    }
    __syncthreads();
  }

  // ---- cross-wave combine: O = sum_w O_w, l = sum_w l_w; write out ----
#pragma unroll
  for (int i = 0; i < 4; ++i)
#pragma unroll
    for (int j = 0; j < 4; ++j)
#pragma unroll
      for (int rg = 0; rg < 4; ++rg)
        Comb[wave * 4096 + (i * 16 + quad * 4 + rg) * 64 + j * 16 + l15] = o[i][j][rg];
  if (l15 == 0) {
#pragma unroll
    for (int i = 0; i < 4; ++i)
#pragma unroll
      for (int rg = 0; rg < 4; ++rg)
        wred[wave * 64 + i * 16 + quad * 4 + rg] = lrow[i][rg];
  }
  __syncthreads();
#pragma unroll
  for (int u = 0; u < 16; ++u) {
    const int idx = u * 256 + t;
    const int row = idx >> 6, dh = idx & 63;
    float v = Comb[idx] + Comb[4096 + idx] + Comb[8192 + idx] + Comb[12288 + idx];
    float linv = 1.0f / (wred[row] + wred[64 + row] + wred[128 + row] + wred[192 + row]);
    if constexpr (A3) {
      ((float*)Op)[((size_t)bh * kM + q0 + row) * kDH + dh] = v * linv;
    } else {
      const int b = bh >> 3, h = bh & 7;
      ((__hip_bfloat16*)Op)[((size_t)(b * kN + q0 + row)) * kHD + h * kDH + dh] =
          f2b(v * linv);
    }
  }
}

// ---------------- epilogue / arg pack ----------------
constexpr int EPI_F32 = 0, EPI_QKV = 1, EPI_BIAS_F32 = 2, EPI_GELU_BF16 = 3, EPI_RES_OUT = 4,
              EPI_BF16 = 5;

struct EpiArgs {
  const float* bias;
  const float* res;
  __hip_bfloat16* oq;
  __hip_bfloat16* ok;
  __hip_bfloat16* ov;
  __hip_bfloat16* obf;
  void* ovoid;
  const int* flag;
  float eyeC;
  float eyeS;
};

// ---------------- MFMA bf16 GEMM: 128x128 tile, BK=32, 4 waves ----------------
// Copy paths (A always; B when TRB) stage via global_load_lds width 16 into LINEAR
// stride-32 LDS (m97 recipe). Gather/eye B staging keeps reg path at stride 40.
template <int EPI, bool TRB, bool BEYE>
__global__ __launch_bounds__(256) void mgemm_k(const __hip_bfloat16* __restrict__ A, int lda,
                                               long sA, const __hip_bfloat16* __restrict__ B,
                                               int ldb, long sB, float* __restrict__ C, int ldc,
                                               long sC, int K, EpiArgs ep) {
  constexpr int LSA = 32;
  constexpr int LSB = TRB ? 32 : 40;
  __shared__ short As[128 * 32];
  __shared__ short Bs[128 * 40];
  A += (long)blockIdx.z * sA;
  B += (long)blockIdx.z * sB;
  const long cbase = (long)blockIdx.z * sC;
  const int row0 = blockIdx.x * 128, col0 = blockIdx.y * 128;
  const int t = threadIdx.x;
  const int lane = t & 63, wave = t >> 6;
  const int wr = (wave >> 1) * 64, wc = (wave & 1) * 64;
  const int l15 = lane & 15, quad = lane >> 4;
  f32x4 acc[4][4] = {};
  for (int k0 = 0; k0 < K; k0 += 32) {
    // ---- stage A (128x32), async direct-to-LDS, wave-linear dest ----
    {
      const int kc = (t & 3) * 8;
#pragma unroll
      for (int p = 0; p < 2; ++p) {
        const int m = p * 64 + (t >> 2);
        gload16(A + (long)(row0 + m) * lda + k0 + kc, &As[p * 2048 + t * 8]);
      }
    }
    // ---- stage B (as [n][k]) ----
    if (TRB) {
      const int kc = (t & 3) * 8;
#pragma unroll
      for (int p = 0; p < 2; ++p) {
        const int n = p * 64 + (t >> 2);
        gload16(B + (long)(col0 + n) * ldb + k0 + kc, &Bs[p * 2048 + t * 8]);
      }
    } else {
      const int k8 = (t & 3) * 8;
#pragma unroll
      for (int p = 0; p < 2; ++p) {
        const int n = p * 64 + (t >> 2);
        short8 vv;
#pragma unroll
        for (int e = 0; e < 8; ++e) {
          float v = toF(B[(long)(k0 + k8 + e) * ldb + col0 + n]);
          if constexpr (BEYE) v = (((k0 + k8 + e) == (col0 + n)) ? ep.eyeC : 0.0f) - v;
          vv[e] = f2s(BEYE ? v * ep.eyeS : v);
        }
        *(short8*)(&Bs[n * LSB + k8]) = vv;
      }
    }
    __syncthreads();
    short8 af[4], bf[4];
#pragma unroll
    for (int i = 0; i < 4; ++i)
      af[i] = *(const short8*)(&As[(wr + i * 16 + l15) * LSA + quad * 8]);
#pragma unroll
    for (int j = 0; j < 4; ++j)
      bf[j] = *(const short8*)(&Bs[(wc + j * 16 + l15) * LSB + quad * 8]);
#pragma unroll
    for (int i = 0; i < 4; ++i)
#pragma unroll
      for (int j = 0; j < 4; ++j)
        acc[i][j] = __builtin_amdgcn_mfma_f32_16x16x32_bf16(af[i], bf[j], acc[i][j], 0, 0, 0);
    __syncthreads();
  }
  // ---- epilogue (C/D: col=lane&15, row=quad*4+reg) ----
#pragma unroll
  for (int i = 0; i < 4; ++i) {
#pragma unroll
    for (int j = 0; j < 4; ++j) {
#pragma unroll
      for (int rg = 0; rg < 4; ++rg) {
        int r = row0 + wr + i * 16 + quad * 4 + rg;
        int c = col0 + wc + j * 16 + l15;
        float v = acc[i][j][rg];
        if (EPI == EPI_BF16) {
          ep.obf[cbase + (long)r * ldc + c] = f2b(v);
        } else if (EPI == EPI_QKV) {
          int three = c >> 9, h = (c >> 6) & 7, dh = c & 63;
          int b = r >> 12, n = r & (kN - 1);
          long dst = ((long)(b * kH + h) * kN + n) * kDH + dh;
          if (three == 0)
            ep.oq[dst] = f2b(v * 0.125f);
          else if (three == 1)
            ep.ok[dst] = f2b(v);
          else
            ep.ov[dst] = f2b(v);
        } else if (EPI == EPI_BIAS_F32) {
          C[cbase + (long)r * ldc + c] = v + ep.bias[c];
        } else if (EPI == EPI_GELU_BF16) {
          v += ep.bias[c];
          ep.obf[cbase + (long)r * ldc + c] =
              f2b(0.5f * v * (1.0f + erff(v * 0.70710678118654752f)));
        } else if (EPI == EPI_RES_OUT) {
          long idx = cbase + (long)r * ldc + c;
          float v2 = v + ep.bias[c] + ep.res[idx];
          if (!(v2 == v2)) v2 = 0.0f;
          if (*ep.flag)
            ((__hip_bfloat16*)ep.ovoid)[idx] = f2b(v2);
          else
            ((float*)ep.ovoid)[idx] = v2;
        }
      }
    }
  }
}

// ---------------- fp32 vector GEMM (for small/odd shapes: sim2, y) ----------------
template <int EPI, bool TRB, class TAT, class TBT>
__global__ __launch_bounds__(256) void gemm_k(const TAT* __restrict__ A, int lda, long sA,
                                              const TBT* __restrict__ B, int ldb, long sB,
                                              float* __restrict__ C, int ldc, long sC, int K,
                                              EpiArgs ep) {
  __shared__ float As[16][68];
  __shared__ float Bs[16][68];
  A += (long)blockIdx.z * sA;
  B += (long)blockIdx.z * sB;
  const long cbase = (long)blockIdx.z * sC;
  const int row0 = blockIdx.x * 64, col0 = blockIdx.y * 64;
  const int t = threadIdx.x;
  const int ty = t >> 4, tx = t & 15;
  float acc[4][4] = {{0.f, 0.f, 0.f, 0.f}, {0.f, 0.f, 0.f, 0.f},
                     {0.f, 0.f, 0.f, 0.f}, {0.f, 0.f, 0.f, 0.f}};
  const int ka = t & 15, ra = t >> 4;
  for (int k0 = 0; k0 < K; k0 += 16) {
#pragma unroll
    for (int j = 0; j < 4; ++j)
      As[ka][ra + 16 * j] = toF(A[(long)(row0 + ra + 16 * j) * lda + (k0 + ka)]);
    if (TRB) {
#pragma unroll
      for (int j = 0; j < 4; ++j)
        Bs[ka][ra + 16 * j] = toF(B[(long)(col0 + ra + 16 * j) * ldb + (k0 + ka)]);
    } else {
      const int jb = t & 63, kb = t >> 6;
#pragma unroll
      for (int j = 0; j < 4; ++j)
        Bs[kb + 4 * j][jb] = toF(B[(long)(k0 + kb + 4 * j) * ldb + (col0 + jb)]);
    }
    __syncthreads();
#pragma unroll
    for (int kk = 0; kk < 16; ++kk) {
      float av[4], bv[4];
#pragma unroll
      for (int i = 0; i < 4; ++i) av[i] = As[kk][ty * 4 + i];
#pragma unroll
      for (int j = 0; j < 4; ++j) bv[j] = Bs[kk][tx * 4 + j];
#pragma unroll
      for (int i = 0; i < 4; ++i)
#pragma unroll
        for (int j = 0; j < 4; ++j) acc[i][j] += av[i] * bv[j];
    }
    __syncthreads();
  }
#pragma unroll
  for (int i = 0; i < 4; ++i) {
    int r = row0 + ty * 4 + i;
#pragma unroll
    for (int j = 0; j < 4; ++j) {
      int c = col0 + tx * 4 + j;
      C[cbase + (long)r * ldc + c] = acc[i][j];
    }
  }
}

}  // namespace

extern "C" void kernel_launch(void* const* d_in, const int* in_sizes, int n_in, void* d_out,
                              int out_size, void* d_ws, size_t ws_size, hipStream_t stream) {
  (void)in_sizes; (void)n_in; (void)out_size;

  char* base = (char*)d_ws;
  size_t off = 0;
  auto alloc = [&](size_t bytes) {
    char* p = base + off;
    off = (off + bytes + 255) & ~(size_t)255;
    return p;
  };
  // a2 + 4 pinv slots (slots sized for f32 to keep hbuf contiguity; used as bf16)
  float* a2 = (float*)alloc((size_t)kBH * kM * kM * 4);  // 16.78 MB
  __hip_bfloat16* zs0 = (__hip_bfloat16*)alloc((size_t)kBH * kM * kM * 4);
  __hip_bfloat16* zs1 = (__hip_bfloat16*)alloc((size_t)kBH * kM * kM * 4);
  __hip_bfloat16* zs2 = (__hip_bfloat16*)alloc((size_t)kBH * kM * kM * 4);
  __hip_bfloat16* zs3 = (__hip_bfloat16*)alloc((size_t)kBH * kM * kM * 4);
  __hip_bfloat16* a2b = (__hip_bfloat16*)alloc((size_t)kBH * kM * kM * 2);  // 8.39 MB
  // bf16 qkv + attn-out region (hosts MLP hidden late: 134.2 MB contiguous)
  __hip_bfloat16* q = (__hip_bfloat16*)alloc((size_t)kBH * kN * kDH * 2);
  __hip_bfloat16* kk = (__hip_bfloat16*)alloc((size_t)kBH * kN * kDH * 2);
  __hip_bfloat16* vv = (__hip_bfloat16*)alloc((size_t)kBH * kN * kDH * 2);
  __hip_bfloat16* ao = (__hip_bfloat16*)alloc((size_t)kBN * kHD * 2);
  float* ql = (float*)alloc((size_t)kBH * kM * kDH * 4);
  float* kl = (float*)alloc((size_t)kBH * kM * kDH * 4);
  float* w3 = (float*)alloc((size_t)kBH * kM * kDH * 4);
  float* y = (float*)alloc((size_t)kBH * kM * kDH * 4);
  float* rsum = (float*)alloc((size_t)kBH * kM * 4);
  float* csum = (float*)alloc((size_t)kBH * kM * 4);
  float* gmax = (float*)alloc(256);
  int* dflag = (int*)alloc(256);
  // transposed bf16 weights
  __hip_bfloat16* WqkvT = (__hip_bfloat16*)alloc((size_t)kQKVC * kD * 2);
  __hip_bfloat16* WoutT = (__hip_bfloat16*)alloc((size_t)kD * kHD * 2);
  __hip_bfloat16* W1T = (__hip_bfloat16*)alloc((size_t)kD4 * kD * 2);
  __hip_bfloat16* W2T = (__hip_bfloat16*)alloc((size_t)kD * kD4 * 2);
  float* bout_f = (float*)alloc(kD * 4);
  float* b1_f = (float*)alloc(kD4 * 4);
  float* b2_f = (float*)alloc(kD * 4);
  float* convw_f = (float*)alloc(kH * kCK * 4);
  float* g1_f = (float*)alloc(kD * 4);
  float* be1_f = (float*)alloc(kD * 4);
  float* g2_f = (float*)alloc(kD * 4);
  float* be2_f = (float*)alloc(kD * 4);
  // lifetime-disjoint aliases
  __hip_bfloat16* hln = (__hip_bfloat16*)a2;  // LN1 out, spans a2+zs0+half zs1, dead pre-sim2
  float* hbuf = a2;                           // Wout out f32 67.1MB, spans a2+zs0..zs2
  __hip_bfloat16* hidden = q;                 // MLP hidden bf16 134.2MB, spans q..ao
  // bf16 copies of ql/kl/y for fattn, in a2b (a2b dead after last pinv iter's 1st GEMM)
  __hip_bfloat16* qlb = a2b;
  __hip_bfloat16* klb = a2b + (size_t)kBH * kM * kDH;
  __hip_bfloat16* ylb = a2b + 2 * (size_t)kBH * kM * kDH;
  // LN2 bf16 output: d_out is free scratch until MLP2's final write (>= 33.5 MB)
  __hip_bfloat16* hln2 = (__hip_bfloat16*)d_out;

  if (off > ws_size) return;  // deterministic guard

  detect_k<<<1, 256, 0, stream>>>((const unsigned*)d_in[0], dflag);

  auto cvt = [&](const void* src, float* dst, int n) {
    cvt_any_k<<<(n + 255) / 256, 256, 0, stream>>>(src, dst, n, dflag);
  };
  cvtT_k<<<(kD * kQKVC + 255) / 256, 256, 0, stream>>>(d_in[1], WqkvT, kD, kQKVC, dflag);
  cvtT_k<<<(kHD * kD + 255) / 256, 256, 0, stream>>>(d_in[2], WoutT, kHD, kD, dflag);
  cvtT_k<<<(kD * kD4 + 255) / 256, 256, 0, stream>>>(d_in[9], W1T, kD, kD4, dflag);
  cvtT_k<<<(kD4 * kD + 255) / 256, 256, 0, stream>>>(d_in[11], W2T, kD4, kD, dflag);
  cvt(d_in[3], bout_f, kD);
  cvt(d_in[4], convw_f, kH * kCK);
  cvt(d_in[5], g1_f, kD);
  cvt(d_in[6], be1_f, kD);
  cvt(d_in[7], g2_f, kD);
  cvt(d_in[8], be2_f, kD);
  cvt(d_in[10], b1_f, kD4);
  cvt(d_in[12], b2_f, kD);

  EpiArgs e0 = {};

  // LN1 -> hln (bf16)
  ln1_k<<<kBN, 256, 0, stream>>>(d_in[0], g1_f, be1_f, hln, dflag);

  // QKV: hln @ WqkvT^T (MFMA, scatter epilogue)
  EpiArgs eq = {};
  eq.oq = q; eq.ok = kk; eq.ov = vv;
  mgemm_k<EPI_QKV, true, false>
      <<<dim3(kBN / 128, kQKVC / 128, 1), 256, 0, stream>>>(hln, kD, 0, WqkvT, kD, 0, nullptr, 0,
                                                            0, kD, eq);

  landmark_k<<<(kBH * kM * kDH + 255) / 256, 256, 0, stream>>>(q, ql);
  landmark_k<<<(kBH * kM * kDH + 255) / 256, 256, 0, stream>>>(kk, kl);

  const long sQL = (long)kM * kDH, sA2 = (long)kM * kM;

  // sim2 = q_l @ k_l^T (f32) ; softmax
  gemm_k<EPI_F32, true, float, float><<<dim3(kM / 64, kM / 64, kBH), 256, 0, stream>>>(
      ql, kDH, sQL, kl, kDH, sQL, a2, kM, sA2, kDH, e0);
  softmax_k<<<kBH * kM, 256, 0, stream>>>(a2, kM);

  // pinv setup
  f32tob16_k<<<(kBH * kM * kM + 255) / 256, 256, 0, stream>>>(a2, a2b, kBH * kM * kM);
  pinv_rowcol_k<<<kBH * kM, 256, 0, stream>>>(a2, rsum, csum);
  pinv_gmax_k<<<1, 256, 0, stream>>>(rsum, csum, gmax);
  pinv_init_k<<<(kBH * kM * kM + 255) / 256, 256, 0, stream>>>(a2, gmax, zs0);

  // Newton-Schulz: 4 MFMA GEMMs/iter, eye-ops fused into B staging
  __hip_bfloat16* bufs[4] = {zs0, zs1, zs2, zs3};
  int zi = 0;
  dim3 gP(kM / 128, kM / 128, kBH);
  for (int it = 0; it < 6; ++it) {
    int o0 = (zi + 1) & 3, o1 = (zi + 2) & 3, o2 = (zi + 3) & 3;
    __hip_bfloat16* Z = bufs[zi];
    __hip_bfloat16* T1 = bufs[o0];
    __hip_bfloat16* T3 = bufs[o1];
    __hip_bfloat16* P3 = bufs[o2];
    EpiArgs ep1 = {}; ep1.obf = T1;
    mgemm_k<EPI_BF16, false, false><<<gP, 256, 0, stream>>>(
        a2b, kM, sA2, Z, kM, sA2, nullptr, kM, sA2, kM, ep1);
    EpiArgs ep2 = {}; ep2.obf = T3; ep2.eyeC = 7.0f; ep2.eyeS = 1.0f;
    mgemm_k<EPI_BF16, false, true><<<gP, 256, 0, stream>>>(
        T1, kM, sA2, T1, kM, sA2, nullptr, kM, sA2, kM, ep2);
    EpiArgs ep3 = {}; ep3.obf = P3; ep3.eyeC = 15.0f; ep3.eyeS = 1.0f;
    mgemm_k<EPI_BF16, false, true><<<gP, 256, 0, stream>>>(
        T1, kM, sA2, T3, kM, sA2, nullptr, kM, sA2, kM, ep3);
    EpiArgs ep4 = {}; ep4.obf = T3; ep4.eyeC = 13.0f; ep4.eyeS = 0.25f;
    mgemm_k<EPI_BF16, false, true><<<gP, 256, 0, stream>>>(
        Z, kM, sA2, P3, kM, sA2, nullptr, kM, sA2, kM, ep4);
    zi = o1;
  }
  __hip_bfloat16* zfin = bufs[zi];

  // bf16 copies for fattn (a2b now dead)
  f32tob16_k<<<(kBH * kM * kDH + 255) / 256, 256, 0, stream>>>(ql, qlb, kBH * kM * kDH);
  f32tob16_k<<<(kBH * kM * kDH + 255) / 256, 256, 0, stream>>>(kl, klb, kBH * kM * kDH);

  // w3 = softmax(q_l @ k^T) @ v  (MFMA flash attention)
  fattn_k<true><<<kBH * (kM / 64), 256, 0, stream>>>(qlb, kk, vv, w3);

  // y = z @ w3 (f32 vector gemm; N=64)
  gemm_k<EPI_F32, false, __hip_bfloat16, float><<<dim3(kM / 64, 1, kBH), 256, 0, stream>>>(
      zfin, kM, sA2, w3, kDH, sQL, y, kDH, sQL, kM, e0);
  f32tob16_k<<<(kBH * kM * kDH + 255) / 256, 256, 0, stream>>>(y, ylb, kBH * kM * kDH);

  // ao = softmax(q @ k_l^T) @ y  (MFMA flash attention, merged layout)
  fattn_k<false><<<kBH * (kN / 64), 256, 0, stream>>>(q, klb, ylb, ao);

  // + depthwise conv residual (LDS-tiled)
  conv_add2_k<<<kBH * (kN / kCR), 256, 0, stream>>>(vv, convw_f, ao);

  // hbuf = ao @ WoutT^T + bout (MFMA, f32 out)
  EpiArgs ew = {}; ew.bias = bout_f;
  mgemm_k<EPI_BIAS_F32, true, false>
      <<<dim3(kBN / 128, kD / 128, 1), 256, 0, stream>>>(ao, kHD, 0, WoutT, kHD, 0, hbuf, kD, 0,
                                                         kHD, ew);

  // LN2 materialized once as bf16 (d_out scratch); MLP1 = pure bf16 GEMM (+bias+GELU)
  ln2_k<<<kBN, 256, 0, stream>>>(hbuf, g2_f, be2_f, hln2);
  EpiArgs e1 = {}; e1.bias = b1_f; e1.obf = hidden;
  mgemm_k<EPI_GELU_BF16, true, false>
      <<<dim3(kBN / 128, kD4 / 128, 1), 256, 0, stream>>>(hln2, kD, 0, W1T, kD, 0, nullptr, kD4,
                                                          0, kD, e1);

  // MLP2 (+bias+residual -> flag-typed out)
  EpiArgs e2 = {}; e2.bias = b2_f; e2.res = hbuf; e2.ovoid = d_out; e2.flag = dflag;
  mgemm_k<EPI_RES_OUT, true, false>
      <<<dim3(kBN / 128, kD / 128, 1), 256, 0, stream>>>(hidden, kD4, 0, W2T, kD4, 0, nullptr,
                                                         kD, 0, kD4, e2);
}

// Round 5
// 1452.080 us; speedup vs baseline: 2.5668x; 1.0929x over previous
//
#include <hip/hip_runtime.h>
#include <hip/hip_bf16.h>
#include <cmath>

#define DEV __device__ __forceinline__

namespace {

constexpr int kB = 8, kN = 4096, kD = 512, kH = 8, kDH = 64, kM = 256, kL = 16, kCK = 33;
constexpr int kBN = kB * kN;     // 32768
constexpr int kBH = kB * kH;     // 64
constexpr int kHD = kH * kDH;    // 512
constexpr int kD4 = 4 * kD;      // 2048
constexpr int kQKVC = 3 * kHD;   // 1536

typedef __attribute__((ext_vector_type(8))) short short8;
typedef __attribute__((ext_vector_type(4))) float f32x4;

DEV float toF(float x) { return x; }
DEV float toF(__hip_bfloat16 x) { return __bfloat162float(x); }
DEV __hip_bfloat16 f2b(float f) { return __float2bfloat16(f); }
DEV short f2s(float f) {
  __hip_bfloat16 h = __float2bfloat16(f);
  return *reinterpret_cast<short*>(&h);
}
DEV float us2f(unsigned short u) { return __uint_as_float((unsigned)u << 16); }
DEV unsigned short f2us(float f) {
  __hip_bfloat16 h = __float2bfloat16(f);
  return *reinterpret_cast<unsigned short*>(&h);
}

// async global->LDS, 16 B per lane; dest must be wave-linear (base + lane*16)
DEV void gload16(const void* g, void* l) {
  __builtin_amdgcn_global_load_lds(
      (const __attribute__((address_space(1))) unsigned*)g,
      (__attribute__((address_space(3))) unsigned*)l, 16, 0, 0);
}

DEV float waveSum(float v) {
#pragma unroll
  for (int o = 32; o > 0; o >>= 1) v += __shfl_down(v, o, 64);
  return v;
}
DEV float waveMax(float v) {
#pragma unroll
  for (int o = 32; o > 0; o >>= 1) v = fmaxf(v, __shfl_down(v, o, 64));
  return v;
}
DEV float blockSum(float v, float* sb) {
  v = waveSum(v);
  int lane = threadIdx.x & 63, w = threadIdx.x >> 6;
  __syncthreads();
  if (lane == 0) sb[w] = v;
  __syncthreads();
  return sb[0] + sb[1] + sb[2] + sb[3];
}
DEV float blockMax(float v, float* sb) {
  v = waveMax(v);
  int lane = threadIdx.x & 63, w = threadIdx.x >> 6;
  __syncthreads();
  if (lane == 0) sb[w] = v;
  __syncthreads();
  return fmaxf(fmaxf(sb[0], sb[1]), fmaxf(sb[2], sb[3]));
}

// ---------------- runtime dtype detection ----------------
__global__ __launch_bounds__(256) void detect_k(const unsigned* __restrict__ x,
                                                int* __restrict__ flag) {
  __shared__ int sc[4];
  int t = threadIdx.x;
  int cb = 0;
  for (int i = t; i < 4096; i += 256) {
    unsigned w = x[i];
    float b0 = __uint_as_float(w << 16);
    float b1 = __uint_as_float(w & 0xffff0000u);
    if (fabsf(b0) < 64.0f && (b0 == 0.0f || fabsf(b0) > 1e-20f)) cb++;
    if (fabsf(b1) < 64.0f && (b1 == 0.0f || fabsf(b1) > 1e-20f)) cb++;
  }
#pragma unroll
  for (int o = 32; o > 0; o >>= 1) cb += __shfl_down(cb, o, 64);
  if ((t & 63) == 0) sc[t >> 6] = cb;
  __syncthreads();
  if (t == 0) flag[0] = (sc[0] + sc[1] + sc[2] + sc[3] > 7373) ? 1 : 0;  // 1 = bf16 inputs
}

__global__ void cvt_any_k(const void* __restrict__ s, float* __restrict__ d, int n,
                          const int* __restrict__ flag) {
  int i = blockIdx.x * 256 + threadIdx.x;
  if (i >= n) return;
  if (*flag)
    d[i] = toF(((const __hip_bfloat16*)s)[i]);
  else
    d[i] = ((const float*)s)[i];
}

// weight [K][N] -> bf16 transposed [N][K]
__global__ void cvtT_k(const void* __restrict__ s, __hip_bfloat16* __restrict__ d, int K, int N,
                       const int* __restrict__ flag) {
  int i = blockIdx.x * 256 + threadIdx.x;
  if (i >= N * K) return;
  int n = i / K, k = i - n * K;
  float v = (*flag) ? toF(((const __hip_bfloat16*)s)[(long)k * N + n])
                    : ((const float*)s)[(long)k * N + n];
  d[i] = f2b(v);
}

__global__ void f32tob16_k(const float* __restrict__ s, __hip_bfloat16* __restrict__ d, int n) {
  int i = blockIdx.x * 256 + threadIdx.x;
  if (i < n) d[i] = f2b(s[i]);
}

// ---------------- LN kernels ----------------

__global__ __launch_bounds__(256) void ln1_k(const void* __restrict__ xv,
                                             const float* __restrict__ g,
                                             const float* __restrict__ be,
                                             __hip_bfloat16* __restrict__ o,
                                             const int* __restrict__ flag) {
  __shared__ float sb[4];
  size_t row = blockIdx.x;
  __hip_bfloat16* po = o + row * kD;
  int t = threadIdx.x;
  float v0, v1;
  if (*flag) {
    const __hip_bfloat16* pr = (const __hip_bfloat16*)xv + row * kD;
    v0 = toF(pr[t]);
    v1 = toF(pr[t + 256]);
  } else {
    const float* pr = (const float*)xv + row * kD;
    v0 = pr[t];
    v1 = pr[t + 256];
  }
  float s = blockSum(v0 + v1, sb);
  float ss = blockSum(v0 * v0 + v1 * v1, sb);
  float mu = s * (1.0f / kD);
  float var = ss * (1.0f / kD) - mu * mu;
  float rs = rsqrtf(var + 1e-5f);
  po[t] = f2b((v0 - mu) * rs * g[t] + be[t]);
  po[t + 256] = f2b((v1 - mu) * rs * g[t + 256] + be[t + 256]);
}

// LN2: f32 in -> bf16 out (materialized once; MLP1 consumes as plain bf16 GEMM A)
__global__ __launch_bounds__(256) void ln2_k(const float* __restrict__ x,
                                             const float* __restrict__ g,
                                             const float* __restrict__ be,
                                             __hip_bfloat16* __restrict__ o) {
  __shared__ float sb[4];
  size_t row = blockIdx.x;
  const float* pr = x + row * kD;
  __hip_bfloat16* po = o + row * kD;
  int t = threadIdx.x;
  float v0 = pr[t], v1 = pr[t + 256];
  float s = blockSum(v0 + v1, sb);
  float ss = blockSum(v0 * v0 + v1 * v1, sb);
  float mu = s * (1.0f / kD);
  float var = ss * (1.0f / kD) - mu * mu;
  float rs = rsqrtf(var + 1e-5f);
  po[t] = f2b((v0 - mu) * rs * g[t] + be[t]);
  po[t + 256] = f2b((v1 - mu) * rs * g[t + 256] + be[t + 256]);
}

// ---------------- small helpers ----------------

__global__ void landmark_k(const __hip_bfloat16* __restrict__ src, float* __restrict__ dst) {
  int i = blockIdx.x * 256 + threadIdx.x;
  if (i >= kBH * kM * kDH) return;
  int dh = i & 63, m = (i >> 6) & 255, bh = i >> 14;
  const __hip_bfloat16* p = src + ((size_t)bh * kN + m * kL) * kDH + dh;
  float s = 0.f;
#pragma unroll
  for (int l = 0; l < kL; ++l) s += toF(p[l * kDH]);
  dst[i] = s * (1.0f / kL);
}

__global__ __launch_bounds__(256) void softmax_k(float* __restrict__ X, int ncols) {
  __shared__ float sb[4];
  size_t row = blockIdx.x;
  float* p = X + row * ncols;
  int t = threadIdx.x;
  float mx = -1e30f;
  for (int c = t; c < ncols; c += 256) mx = fmaxf(mx, p[c]);
  mx = blockMax(mx, sb);
  float s = 0.f;
  for (int c = t; c < ncols; c += 256) {
    float e = expf(fminf(p[c] - mx, 0.0f));
    p[c] = e;
    s += e;
  }
  s = blockSum(s, sb);
  float inv = 1.0f / s;
  for (int c = t; c < ncols; c += 256) p[c] *= inv;
}

__global__ __launch_bounds__(256) void pinv_rowcol_k(const float* __restrict__ a2,
                                                     float* __restrict__ rsum,
                                                     float* __restrict__ csum) {
  __shared__ float sb[4];
  int bh = blockIdx.x >> 8, i = blockIdx.x & 255;
  const float* base = a2 + ((size_t)bh << 16);
  int t = threadIdx.x;
  float rs = blockSum(fabsf(base[i * kM + t]), sb);
  float cs = blockSum(fabsf(base[t * kM + i]), sb);
  if (t == 0) {
    rsum[blockIdx.x] = rs;
    csum[blockIdx.x] = cs;
  }
}

__global__ __launch_bounds__(256) void pinv_gmax_k(const float* __restrict__ rsum,
                                                   const float* __restrict__ csum,
                                                   float* __restrict__ gmax) {
  __shared__ float sb[4];
  int t = threadIdx.x;
  float a = 0.f, b = 0.f;
  for (int j = t; j < kBH * kM; j += 256) {
    a = fmaxf(a, rsum[j]);
    b = fmaxf(b, csum[j]);
  }
  a = blockMax(a, sb);
  b = blockMax(b, sb);
  if (t == 0) {
    gmax[0] = a;
    gmax[1] = b;
  }
}

// Z0 = a2^T * s (normal) and Z0^T = a2 * s (transposed copy for TRB consumption)
__global__ void pinv_init2_k(const float* __restrict__ a2, const float* __restrict__ gmax,
                             __hip_bfloat16* __restrict__ zn, __hip_bfloat16* __restrict__ zt) {
  int i = blockIdx.x * 256 + threadIdx.x;
  if (i >= kBH * kM * kM) return;
  int col = i & 255, r = (i >> 8) & 255, bh = i >> 16;
  float s = 1.0f / fmaxf(gmax[0] * gmax[1], 1e-30f);
  zn[i] = f2b(a2[((size_t)bh << 16) + col * kM + r] * s);
  zt[i] = f2b(a2[i] * s);
}

// ---------------- depthwise conv residual (LDS-tiled, vectorized) ----------------
constexpr int kCR = 128;            // output rows per block
constexpr int kCHA = kCK / 2;       // 16 halo
constexpr int kCW = kCR + 2 * kCHA; // 160 staged rows
constexpr int kCP = 72;             // LDS row stride in shorts

__global__ __launch_bounds__(256) void conv_add2_k(const __hip_bfloat16* __restrict__ v,
                                                   const float* __restrict__ w,
                                                   __hip_bfloat16* __restrict__ ao) {
  __shared__ short Vt[kCW * kCP];
  __shared__ float wsh[kCK];
  const int t = threadIdx.x;
  const int bh = blockIdx.x >> 5;            // kN / kCR = 32 segments
  const int n0 = (blockIdx.x & 31) * kCR;
  const int b = bh >> 3, h = bh & 7;
  if (t < kCK) wsh[t] = w[h * kCK + t];
  const __hip_bfloat16* vbase = v + (size_t)bh * kN * kDH;
#pragma unroll
  for (int u = 0; u < (kCW * 8 + 255) / 256; ++u) {
    const int idx = u * 256 + t;
    if (idx < kCW * 8) {
      const int r = idx >> 3, c8 = (idx & 7) * 8;
      const int n = n0 - kCHA + r;
      uint4 d = {0u, 0u, 0u, 0u};
      if (n >= 0 && n < kN) d = *(const uint4*)(vbase + (size_t)n * kDH + c8);
      *(uint4*)&Vt[r * kCP + c8] = d;
    }
  }
  __syncthreads();
  const int dh8 = (t & 7) * 8;
  const int rg = (t >> 3) * 4;               // 32 row-groups x 4 rows = 128
  float acc[4][8] = {};
#pragma unroll
  for (int wd = 0; wd < kCK + 3; ++wd) {     // 36-row sliding window
    short8 v8 = *(const short8*)&Vt[(rg + wd) * kCP + dh8];
    float f[8];
#pragma unroll
    for (int e = 0; e < 8; ++e) f[e] = us2f((unsigned short)v8[e]);
#pragma unroll
    for (int i = 0; i < 4; ++i) {
      const int tap = wd - i;
      if (tap >= 0 && tap < kCK) {
        const float wt = wsh[tap];
#pragma unroll
        for (int e = 0; e < 8; ++e) acc[i][e] = fmaf(f[e], wt, acc[i][e]);
      }
    }
  }
#pragma unroll
  for (int i = 0; i < 4; ++i) {
    const int n = n0 + rg + i;
    __hip_bfloat16* ap = ao + ((size_t)(b * kN + n)) * kHD + h * kDH + dh8;
    uint4 d = *(const uint4*)ap;
    const unsigned short* us = (const unsigned short*)&d;
    unsigned short ov[8];
#pragma unroll
    for (int e = 0; e < 8; ++e) ov[e] = f2us(us2f(us[e]) + acc[i][e]);
    *(uint4*)ap = *(const uint4*)ov;
  }
}

// ---------------- MFMA flash attention ----------------
// O = softmax(Q @ K^T) @ V, 64 Q-rows per block, KV tiles of 256, online softmax.
constexpr int FP = 72;  // LDS row pad in shorts (144 B stride: 16B-aligned, 2-way max on b128)

template <bool A3>  // true : attn3 — Q [bh][256][64], K/V [bh][4096][64], out w3 f32; grid kBH*4
                    // false: attn1 — Q [bh][4096][64], K/V [bh][256][64],
                    //        out ao bf16 scatter [b][n][h*64+dh]; grid kBH*64
__global__ __launch_bounds__(256, 1) void fattn_k(const __hip_bfloat16* __restrict__ Qp,
                                                  const __hip_bfloat16* __restrict__ Kp,
                                                  const __hip_bfloat16* __restrict__ Vp,
                                                  void* __restrict__ Op) {
  __shared__ __align__(16) char smem[111616];
  short* Ks = (short*)smem;                    // [256][FP]  36864 B
  short* Vs = (short*)(smem + 36864);          // [256][FP]  36864 B
  short* Ps = (short*)(smem + 73728);          // 4 x [64][FP] (per-wave P slab) 36864 B
  float* wred = (float*)(smem + 110592);       // [4][64] cross-wave max / lsum
  float* Comb = (float*)smem;                  // [4][64][64] f32 epilogue alias (64 KB)

  const int t = threadIdx.x;
  const int lane = t & 63, wave = t >> 6;
  const int l15 = lane & 15, quad = lane >> 4;
  const int bh = A3 ? (blockIdx.x >> 2) : (blockIdx.x >> 6);
  const int q0 = A3 ? ((blockIdx.x & 3) * 64) : ((blockIdx.x & 63) * 64);
  const int NTILES = A3 ? (kN / 256) : 1;
  short* Psw = Ps + wave * 64 * FP;

  // ---- Q fragments in registers ----
  short8 aq[4][2];
#pragma unroll
  for (int i = 0; i < 4; ++i) {
    const long qrow = (A3 ? ((long)bh * kM) : ((long)bh * kN)) + q0 + i * 16 + l15;
#pragma unroll
    for (int s = 0; s < 2; ++s)
      aq[i][s] = *(const short8*)(Qp + qrow * kDH + quad * 8 + s * 32);
  }

  f32x4 o[4][4] = {};
  float mrow[4][4], lrow[4][4];
#pragma unroll
  for (int i = 0; i < 4; ++i)
#pragma unroll
    for (int rg = 0; rg < 4; ++rg) {
      mrow[i][rg] = -1e30f;
      lrow[i][rg] = 0.f;
    }

  const long kvbase = (long)bh * (A3 ? kN : kM) * kDH;

  for (int tile = 0; tile < NTILES; ++tile) {
    // ---- stage K,V tile [256][64] -> LDS ----
    {
      const int r = t >> 2, c = (t & 3) * 16;
#pragma unroll
      for (int p = 0; p < 4; ++p) {
        const int rr = p * 64 + r;
        const long src = kvbase + (long)(tile * 256 + rr) * kDH + c;
        const uint4* ks = (const uint4*)(Kp + src);
        const uint4* vs = (const uint4*)(Vp + src);
        *(uint4*)&Ks[rr * FP + c] = ks[0];
        *(uint4*)&Ks[rr * FP + c + 8] = ks[1];
        *(uint4*)&Vs[rr * FP + c] = vs[0];
        *(uint4*)&Vs[rr * FP + c + 8] = vs[1];
      }
    }
    __syncthreads();

    // ---- S = Q @ K^T  (wave's 64x64 slab of the 64x256 tile) ----
    f32x4 sacc[4][4] = {};
#pragma unroll
    for (int s = 0; s < 2; ++s) {
      short8 bk[4];
#pragma unroll
      for (int j = 0; j < 4; ++j)
        bk[j] = *(const short8*)&Ks[(wave * 64 + j * 16 + l15) * FP + quad * 8 + s * 32];
#pragma unroll
      for (int i = 0; i < 4; ++i)
#pragma unroll
        for (int j = 0; j < 4; ++j)
          sacc[i][j] =
              __builtin_amdgcn_mfma_f32_16x16x32_bf16(aq[i][s], bk[j], sacc[i][j], 0, 0, 0);
    }

    // ---- per-row max: lane-local over j, then over l15 group, then cross-wave ----
    float pmax[4][4];
#pragma unroll
    for (int i = 0; i < 4; ++i)
#pragma unroll
      for (int rg = 0; rg < 4; ++rg) {
        float v = fmaxf(fmaxf(sacc[i][0][rg], sacc[i][1][rg]),
                        fmaxf(sacc[i][2][rg], sacc[i][3][rg]));
#pragma unroll
        for (int d = 1; d < 16; d <<= 1) v = fmaxf(v, __shfl_xor(v, d, 64));
        pmax[i][rg] = v;
      }
    if (l15 == 0) {
#pragma unroll
      for (int i = 0; i < 4; ++i)
#pragma unroll
        for (int rg = 0; rg < 4; ++rg)
          wred[wave * 64 + i * 16 + quad * 4 + rg] = pmax[i][rg];
    }
    __syncthreads();

    // ---- online rescale + exp + P repack (bf16, own-wave LDS slab) ----
#pragma unroll
    for (int i = 0; i < 4; ++i)
#pragma unroll
      for (int rg = 0; rg < 4; ++rg) {
        const int row = i * 16 + quad * 4 + rg;
        float tm =
            fmaxf(fmaxf(wred[row], wred[64 + row]), fmaxf(wred[128 + row], wred[192 + row]));
        float mn = fmaxf(mrow[i][rg], tm);
        float c = expf(mrow[i][rg] - mn);
        mrow[i][rg] = mn;
        lrow[i][rg] *= c;
#pragma unroll
        for (int j = 0; j < 4; ++j) o[i][j][rg] *= c;
      }
#pragma unroll
    for (int i = 0; i < 4; ++i)
#pragma unroll
      for (int rg = 0; rg < 4; ++rg) {
        float ls = 0.f;
#pragma unroll
        for (int j = 0; j < 4; ++j) {
          float e = expf(sacc[i][j][rg] - mrow[i][rg]);  // <= 0 exponent by construction
          ls += e;
          Psw[(i * 16 + quad * 4 + rg) * FP + j * 16 + l15] = f2s(e);
        }
#pragma unroll
        for (int d = 1; d < 16; d <<= 1) ls += __shfl_xor(ls, d, 64);
        lrow[i][rg] += ls;
      }

    // ---- O += P @ V ----
#pragma unroll
    for (int s = 0; s < 2; ++s) {
      short8 ap[4];
#pragma unroll
      for (int i = 0; i < 4; ++i)
        ap[i] = *(const short8*)&Psw[(i * 16 + l15) * FP + quad * 8 + s * 32];
      short8 bv[4];
#pragma unroll
      for (int j = 0; j < 4; ++j)
#pragma unroll
        for (int e = 0; e < 8; ++e)
          bv[j][e] = Vs[(wave * 64 + s * 32 + quad * 8 + e) * FP + j * 16 + l15];
#pragma unroll
      for (int i = 0; i < 4; ++i)
#pragma unroll
        for (int j = 0; j < 4; ++j)
          o[i][j] = __builtin_amdgcn_mfma_f32_16x16x32_bf16(ap[i], bv[j], o[i][j], 0, 0, 0);
    }
    __syncthreads();
  }

  // ---- cross-wave combine: O = sum_w O_w, l = sum_w l_w; write out ----
#pragma unroll
  for (int i = 0; i < 4; ++i)
#pragma unroll
    for (int j = 0; j < 4; ++j)
#pragma unroll
      for (int rg = 0; rg < 4; ++rg)
        Comb[wave * 4096 + (i * 16 + quad * 4 + rg) * 64 + j * 16 + l15] = o[i][j][rg];
  if (l15 == 0) {
#pragma unroll
    for (int i = 0; i < 4; ++i)
#pragma unroll
      for (int rg = 0; rg < 4; ++rg)
        wred[wave * 64 + i * 16 + quad * 4 + rg] = lrow[i][rg];
  }
  __syncthreads();
#pragma unroll
  for (int u = 0; u < 16; ++u) {
    const int idx = u * 256 + t;
    const int row = idx >> 6, dh = idx & 63;
    float v = Comb[idx] + Comb[4096 + idx] + Comb[8192 + idx] + Comb[12288 + idx];
    float linv = 1.0f / (wred[row] + wred[64 + row] + wred[128 + row] + wred[192 + row]);
    if constexpr (A3) {
      ((float*)Op)[((size_t)bh * kM + q0 + row) * kDH + dh] = v * linv;
    } else {
      const int b = bh >> 3, h = bh & 7;
      ((__hip_bfloat16*)Op)[((size_t)(b * kN + q0 + row)) * kHD + h * kDH + dh] =
          f2b(v * linv);
    }
  }
}

// ---------------- epilogue / arg pack ----------------
constexpr int EPI_QKV = 1, EPI_BIAS_F32 = 2, EPI_GELU_BF16 = 3, EPI_RES_OUT = 4;
constexpr int EPI_F32 = 0;

struct EpiArgs {
  const float* bias;
  const float* res;
  __hip_bfloat16* oq;
  __hip_bfloat16* ok;
  __hip_bfloat16* ov;
  __hip_bfloat16* obf;
  void* ovoid;
  const int* flag;
};

// ---------------- MFMA bf16 GEMM: 128x128 tile, BK=32, 4 waves, TRB only ----------------
// Both operands staged via global_load_lds width 16 into LINEAR stride-32 LDS (m97 recipe).
template <int EPI>
__global__ __launch_bounds__(256) void mgemm_k(const __hip_bfloat16* __restrict__ A, int lda,
                                               const __hip_bfloat16* __restrict__ B, int ldb,
                                               float* __restrict__ C, int ldc, int K,
                                               EpiArgs ep) {
  __shared__ short As[128 * 32];
  __shared__ short Bs[128 * 32];
  const int row0 = blockIdx.x * 128, col0 = blockIdx.y * 128;
  const int t = threadIdx.x;
  const int lane = t & 63, wave = t >> 6;
  const int wr = (wave >> 1) * 64, wc = (wave & 1) * 64;
  const int l15 = lane & 15, quad = lane >> 4;
  f32x4 acc[4][4] = {};
  for (int k0 = 0; k0 < K; k0 += 32) {
    const int kc = (t & 3) * 8;
#pragma unroll
    for (int p = 0; p < 2; ++p) {
      const int m = p * 64 + (t >> 2);
      gload16(A + (long)(row0 + m) * lda + k0 + kc, &As[p * 2048 + t * 8]);
      gload16(B + (long)(col0 + m) * ldb + k0 + kc, &Bs[p * 2048 + t * 8]);
    }
    __syncthreads();
    short8 af[4], bf[4];
#pragma unroll
    for (int i = 0; i < 4; ++i)
      af[i] = *(const short8*)(&As[(wr + i * 16 + l15) * 32 + quad * 8]);
#pragma unroll
    for (int j = 0; j < 4; ++j)
      bf[j] = *(const short8*)(&Bs[(wc + j * 16 + l15) * 32 + quad * 8]);
#pragma unroll
    for (int i = 0; i < 4; ++i)
#pragma unroll
      for (int j = 0; j < 4; ++j)
        acc[i][j] = __builtin_amdgcn_mfma_f32_16x16x32_bf16(af[i], bf[j], acc[i][j], 0, 0, 0);
    __syncthreads();
  }
  // ---- epilogue (C/D: col=lane&15, row=quad*4+reg) ----
#pragma unroll
  for (int i = 0; i < 4; ++i) {
#pragma unroll
    for (int j = 0; j < 4; ++j) {
#pragma unroll
      for (int rg = 0; rg < 4; ++rg) {
        int r = row0 + wr + i * 16 + quad * 4 + rg;
        int c = col0 + wc + j * 16 + l15;
        float v = acc[i][j][rg];
        if (EPI == EPI_QKV) {
          int three = c >> 9, h = (c >> 6) & 7, dh = c & 63;
          int b = r >> 12, n = r & (kN - 1);
          long dst = ((long)(b * kH + h) * kN + n) * kDH + dh;
          if (three == 0)
            ep.oq[dst] = f2b(v * 0.125f);
          else if (three == 1)
            ep.ok[dst] = f2b(v);
          else
            ep.ov[dst] = f2b(v);
        } else if (EPI == EPI_BIAS_F32) {
          C[(long)r * ldc + c] = v + ep.bias[c];
        } else if (EPI == EPI_GELU_BF16) {
          v += ep.bias[c];
          ep.obf[(long)r * ldc + c] =
              f2b(0.5f * v * (1.0f + erff(v * 0.70710678118654752f)));
        } else if (EPI == EPI_RES_OUT) {
          long idx = (long)r * ldc + c;
          float v2 = v + ep.bias[c] + ep.res[idx];
          if (!(v2 == v2)) v2 = 0.0f;
          if (*ep.flag)
            ((__hip_bfloat16*)ep.ovoid)[idx] = f2b(v2);
          else
            ((float*)ep.ovoid)[idx] = v2;
        }
      }
    }
  }
}

// ---------------- pinv MFMA GEMM: C = A @ Bst^T, batched over bh ----------------
// A [256][256] row-major, Bst [256][256] row-major (= mathematical B transposed).
// Outputs: optional normal C*oscl (bf16), and always the eye-transposed
//   Ct[c][r] = ((r==c)*eyeC - C[r][c]) * eyeS   (coalesced via LDS transpose).
template <bool WN>
__global__ __launch_bounds__(256) void mgemmT_k(const __hip_bfloat16* __restrict__ A,
                                                const __hip_bfloat16* __restrict__ B,
                                                __hip_bfloat16* __restrict__ Cn,
                                                __hip_bfloat16* __restrict__ Ct,
                                                float eyeC, float eyeS, float oscl) {
  constexpr int TS = 136;  // transpose buffer row stride (shorts)
  __shared__ short sm[128 * TS];  // 34816 B; aliases staging (16 KB) then transpose buf
  short* As = sm;
  short* Bs = sm + 4096;
  const long mbase = (long)blockIdx.z * ((long)kM * kM);
  const int row0 = blockIdx.x * 128, col0 = blockIdx.y * 128;
  const int t = threadIdx.x;
  const int lane = t & 63, wave = t >> 6;
  const int wr = (wave >> 1) * 64, wc = (wave & 1) * 64;
  const int l15 = lane & 15, quad = lane >> 4;
  f32x4 acc[4][4] = {};
  for (int k0 = 0; k0 < kM; k0 += 32) {
    const int kc = (t & 3) * 8;
#pragma unroll
    for (int p = 0; p < 2; ++p) {
      const int m = p * 64 + (t >> 2);
      gload16(A + mbase + (long)(row0 + m) * kM + k0 + kc, &As[p * 2048 + t * 8]);
      gload16(B + mbase + (long)(col0 + m) * kM + k0 + kc, &Bs[p * 2048 + t * 8]);
    }
    __syncthreads();
    short8 af[4], bf[4];
#pragma unroll
    for (int i = 0; i < 4; ++i)
      af[i] = *(const short8*)(&As[(wr + i * 16 + l15) * 32 + quad * 8]);
#pragma unroll
    for (int j = 0; j < 4; ++j)
      bf[j] = *(const short8*)(&Bs[(wc + j * 16 + l15) * 32 + quad * 8]);
#pragma unroll
    for (int i = 0; i < 4; ++i)
#pragma unroll
      for (int j = 0; j < 4; ++j)
        acc[i][j] = __builtin_amdgcn_mfma_f32_16x16x32_bf16(af[i], bf[j], acc[i][j], 0, 0, 0);
    __syncthreads();
  }
  // optional normal write
  if (WN) {
#pragma unroll
    for (int i = 0; i < 4; ++i)
#pragma unroll
      for (int j = 0; j < 4; ++j)
#pragma unroll
        for (int rg = 0; rg < 4; ++rg) {
          int r = row0 + wr + i * 16 + quad * 4 + rg;
          int c = col0 + wc + j * 16 + l15;
          Cn[mbase + (long)r * kM + c] = f2b(acc[i][j][rg] * oscl);
        }
  }
  // eye-transform + transpose deposit (packed b64: rg 0..3 contiguous along rl axis)
#pragma unroll
  for (int i = 0; i < 4; ++i)
#pragma unroll
    for (int j = 0; j < 4; ++j) {
      const int rl0 = wr + i * 16 + quad * 4;
      const int cl = wc + j * 16 + l15;
      const int r0 = row0 + rl0, c = col0 + cl;
      short pk[4];
#pragma unroll
      for (int rg = 0; rg < 4; ++rg) {
        float v = (((r0 + rg) == c) ? eyeC : 0.0f) - acc[i][j][rg];
        pk[rg] = f2s(v * eyeS);
      }
      *(ulong1*)&sm[cl * TS + rl0] = *(const ulong1*)pk;
    }
  __syncthreads();
#pragma unroll
  for (int u = 0; u < 8; ++u) {
    const int rowt = u * 16 + (t >> 4);   // row of C^T tile (= col of C), 0..127
    const int c8 = (t & 15) * 8;          // along r axis
    uint4 d = *(const uint4*)&sm[rowt * TS + c8];
    *(uint4*)(Ct + mbase + (long)(col0 + rowt) * kM + row0 + c8) = d;
  }
}

// ---------------- fp32 vector GEMM (for small/odd shapes: sim2, y) ----------------
template <int EPI, bool TRB, class TAT, class TBT>
__global__ __launch_bounds__(256) void gemm_k(const TAT* __restrict__ A, int lda, long sA,
                                              const TBT* __restrict__ B, int ldb, long sB,
                                              float* __restrict__ C, int ldc, long sC, int K,
                                              EpiArgs ep) {
  __shared__ float As[16][68];
  __shared__ float Bs[16][68];
  A += (long)blockIdx.z * sA;
  B += (long)blockIdx.z * sB;
  const long cbase = (long)blockIdx.z * sC;
  const int row0 = blockIdx.x * 64, col0 = blockIdx.y * 64;
  const int t = threadIdx.x;
  const int ty = t >> 4, tx = t & 15;
  float acc[4][4] = {{0.f, 0.f, 0.f, 0.f}, {0.f, 0.f, 0.f, 0.f},
                     {0.f, 0.f, 0.f, 0.f}, {0.f, 0.f, 0.f, 0.f}};
  const int ka = t & 15, ra = t >> 4;
  for (int k0 = 0; k0 < K; k0 += 16) {
#pragma unroll
    for (int j = 0; j < 4; ++j)
      As[ka][ra + 16 * j] = toF(A[(long)(row0 + ra + 16 * j) * lda + (k0 + ka)]);
    if (TRB) {
#pragma unroll
      for (int j = 0; j < 4; ++j)
        Bs[ka][ra + 16 * j] = toF(B[(long)(col0 + ra + 16 * j) * ldb + (k0 + ka)]);
    } else {
      const int jb = t & 63, kb = t >> 6;
#pragma unroll
      for (int j = 0; j < 4; ++j)
        Bs[kb + 4 * j][jb] = toF(B[(long)(k0 + kb + 4 * j) * ldb + (col0 + jb)]);
    }
    __syncthreads();
#pragma unroll
    for (int kk = 0; kk < 16; ++kk) {
      float av[4], bv[4];
#pragma unroll
      for (int i = 0; i < 4; ++i) av[i] = As[kk][ty * 4 + i];
#pragma unroll
      for (int j = 0; j < 4; ++j) bv[j] = Bs[kk][tx * 4 + j];
#pragma unroll
      for (int i = 0; i < 4; ++i)
#pragma unroll
        for (int j = 0; j < 4; ++j) acc[i][j] += av[i] * bv[j];
    }
    __syncthreads();
  }
#pragma unroll
  for (int i = 0; i < 4; ++i) {
    int r = row0 + ty * 4 + i;
#pragma unroll
    for (int j = 0; j < 4; ++j) {
      int c = col0 + tx * 4 + j;
      C[cbase + (long)r * ldc + c] = acc[i][j];
    }
  }
}

}  // namespace

extern "C" void kernel_launch(void* const* d_in, const int* in_sizes, int n_in, void* d_out,
                              int out_size, void* d_ws, size_t ws_size, hipStream_t stream) {
  (void)in_sizes; (void)n_in; (void)out_size;

  char* base = (char*)d_ws;
  size_t off = 0;
  auto alloc = [&](size_t bytes) {
    char* p = base + off;
    off = (off + bytes + 255) & ~(size_t)255;
    return p;
  };
  const size_t kMat = (size_t)kBH * kM * kM;  // elements per pinv matrix set
  float* a2 = (float*)alloc(kMat * 4);        // 16.78 MB
  __hip_bfloat16* mb0 = (__hip_bfloat16*)alloc(kMat * 2 * 8);  // 8 bf16 matrix sets, 67.1 MB
  __hip_bfloat16* a2b = (__hip_bfloat16*)alloc(kMat * 2);      // 8.39 MB
  // bf16 qkv + attn-out region (hosts MLP hidden late: 134.2 MB contiguous)
  __hip_bfloat16* q = (__hip_bfloat16*)alloc((size_t)kBH * kN * kDH * 2);
  __hip_bfloat16* kk = (__hip_bfloat16*)alloc((size_t)kBH * kN * kDH * 2);
  __hip_bfloat16* vv = (__hip_bfloat16*)alloc((size_t)kBH * kN * kDH * 2);
  __hip_bfloat16* ao = (__hip_bfloat16*)alloc((size_t)kBN * kHD * 2);
  float* ql = (float*)alloc((size_t)kBH * kM * kDH * 4);
  float* kl = (float*)alloc((size_t)kBH * kM * kDH * 4);
  float* w3 = (float*)alloc((size_t)kBH * kM * kDH * 4);
  float* y = (float*)alloc((size_t)kBH * kM * kDH * 4);
  float* rsum = (float*)alloc((size_t)kBH * kM * 4);
  float* csum = (float*)alloc((size_t)kBH * kM * 4);
  float* gmax = (float*)alloc(256);
  int* dflag = (int*)alloc(256);
  // transposed bf16 weights
  __hip_bfloat16* WqkvT = (__hip_bfloat16*)alloc((size_t)kQKVC * kD * 2);
  __hip_bfloat16* WoutT = (__hip_bfloat16*)alloc((size_t)kD * kHD * 2);
  __hip_bfloat16* W1T = (__hip_bfloat16*)alloc((size_t)kD4 * kD * 2);
  __hip_bfloat16* W2T = (__hip_bfloat16*)alloc((size_t)kD * kD4 * 2);
  float* bout_f = (float*)alloc(kD * 4);
  float* b1_f = (float*)alloc(kD4 * 4);
  float* b2_f = (float*)alloc(kD * 4);
  float* convw_f = (float*)alloc(kH * kCK * 4);
  float* g1_f = (float*)alloc(kD * 4);
  float* be1_f = (float*)alloc(kD * 4);
  float* g2_f = (float*)alloc(kD * 4);
  float* be2_f = (float*)alloc(kD * 4);
  auto mb = [&](int i) { return mb0 + (size_t)i * kMat; };
  // lifetime-disjoint aliases
  __hip_bfloat16* hln = (__hip_bfloat16*)a2;  // LN1 out 33.5MB: a2+mb0+mb1, dead pre-sim2
  float* hbuf = a2;                           // Wout out f32 67.1MB: a2+mb0..mb5
  __hip_bfloat16* hidden = q;                 // MLP hidden bf16 134.2MB, spans q..ao
  // bf16 copies of ql/kl/y for fattn, in a2b (a2b dead after last pinv iter's 1st GEMM)
  __hip_bfloat16* qlb = a2b;
  __hip_bfloat16* klb = a2b + (size_t)kBH * kM * kDH;
  __hip_bfloat16* ylb = a2b + 2 * (size_t)kBH * kM * kDH;
  // LN2 bf16 output: d_out is free scratch until MLP2's final write (>= 33.5 MB)
  __hip_bfloat16* hln2 = (__hip_bfloat16*)d_out;

  if (off > ws_size) return;  // deterministic guard

  detect_k<<<1, 256, 0, stream>>>((const unsigned*)d_in[0], dflag);

  auto cvt = [&](const void* src, float* dst, int n) {
    cvt_any_k<<<(n + 255) / 256, 256, 0, stream>>>(src, dst, n, dflag);
  };
  cvtT_k<<<(kD * kQKVC + 255) / 256, 256, 0, stream>>>(d_in[1], WqkvT, kD, kQKVC, dflag);
  cvtT_k<<<(kHD * kD + 255) / 256, 256, 0, stream>>>(d_in[2], WoutT, kHD, kD, dflag);
  cvtT_k<<<(kD * kD4 + 255) / 256, 256, 0, stream>>>(d_in[9], W1T, kD, kD4, dflag);
  cvtT_k<<<(kD4 * kD + 255) / 256, 256, 0, stream>>>(d_in[11], W2T, kD4, kD, dflag);
  cvt(d_in[3], bout_f, kD);
  cvt(d_in[4], convw_f, kH * kCK);
  cvt(d_in[5], g1_f, kD);
  cvt(d_in[6], be1_f, kD);
  cvt(d_in[7], g2_f, kD);
  cvt(d_in[8], be2_f, kD);
  cvt(d_in[10], b1_f, kD4);
  cvt(d_in[12], b2_f, kD);

  EpiArgs e0 = {};

  // LN1 -> hln (bf16)
  ln1_k<<<kBN, 256, 0, stream>>>(d_in[0], g1_f, be1_f, hln, dflag);

  // QKV: hln @ WqkvT^T (MFMA, scatter epilogue)
  EpiArgs eq = {};
  eq.oq = q; eq.ok = kk; eq.ov = vv;
  mgemm_k<EPI_QKV><<<dim3(kBN / 128, kQKVC / 128, 1), 256, 0, stream>>>(hln, kD, WqkvT, kD,
                                                                        nullptr, 0, kD, eq);

  landmark_k<<<(kBH * kM * kDH + 255) / 256, 256, 0, stream>>>(q, ql);
  landmark_k<<<(kBH * kM * kDH + 255) / 256, 256, 0, stream>>>(kk, kl);

  const long sQL = (long)kM * kDH, sA2 = (long)kM * kM;

  // sim2 = q_l @ k_l^T (f32) ; softmax
  gemm_k<EPI_F32, true, float, float><<<dim3(kM / 64, kM / 64, kBH), 256, 0, stream>>>(
      ql, kDH, sQL, kl, kDH, sQL, a2, kM, sA2, kDH, e0);
  softmax_k<<<kBH * kM, 256, 0, stream>>>(a2, kM);

  // pinv setup
  f32tob16_k<<<((int)kMat + 255) / 256, 256, 0, stream>>>(a2, a2b, (int)kMat);
  pinv_rowcol_k<<<kBH * kM, 256, 0, stream>>>(a2, rsum, csum);
  pinv_gmax_k<<<1, 256, 0, stream>>>(rsum, csum, gmax);
  pinv_init2_k<<<((int)kMat + 255) / 256, 256, 0, stream>>>(a2, gmax, mb(0), mb(1));

  // Newton-Schulz, transposed chain: every B-operand consumed as [N][K] via TRB.
  // Producers emit (eyeC*I - C)^T * eyeS for the next consumer (eye fused at write).
  {
    __hip_bfloat16 *Zc = mb(0), *ZcT = mb(1), *Zn = mb(6), *ZnT = mb(7);
    __hip_bfloat16 *T1 = mb(2), *T1E = mb(3), *T3E = mb(4), *P3E = mb(5);
    dim3 gP(kM / 128, kM / 128, kBH);
    for (int it = 0; it < 6; ++it) {
      // T1 = a2 @ Z ; also emit (7I - T1)^T
      mgemmT_k<true><<<gP, 256, 0, stream>>>(a2b, ZcT, T1, T1E, 7.0f, 1.0f, 1.0f);
      // T3 = T1 @ (7I - T1) ; emit only (15I - T3)^T
      mgemmT_k<false><<<gP, 256, 0, stream>>>(T1, T1E, nullptr, T3E, 15.0f, 1.0f, 1.0f);
      // P3 = T1 @ (15I - T3) ; emit only (13I - P3)^T
      mgemmT_k<false><<<gP, 256, 0, stream>>>(T1, T3E, nullptr, P3E, 13.0f, 1.0f, 1.0f);
      // Znext = 0.25 * Z @ (13I - P3) ; emit Znext and Znext^T
      mgemmT_k<true><<<gP, 256, 0, stream>>>(Zc, P3E, Zn, ZnT, 0.0f, -0.25f, 0.25f);
      __hip_bfloat16* tp;
      tp = Zc; Zc = Zn; Zn = tp;
      tp = ZcT; ZcT = ZnT; ZnT = tp;
    }
    // after 6 iters (even number of swaps) Zc == mb(0)
  }
  __hip_bfloat16* zfin = mb(0);

  // bf16 copies for fattn (a2b now dead)
  f32tob16_k<<<(kBH * kM * kDH + 255) / 256, 256, 0, stream>>>(ql, qlb, kBH * kM * kDH);
  f32tob16_k<<<(kBH * kM * kDH + 255) / 256, 256, 0, stream>>>(kl, klb, kBH * kM * kDH);

  // w3 = softmax(q_l @ k^T) @ v  (MFMA flash attention)
  fattn_k<true><<<kBH * (kM / 64), 256, 0, stream>>>(qlb, kk, vv, w3);

  // y = z @ w3 (f32 vector gemm; N=64)
  gemm_k<EPI_F32, false, __hip_bfloat16, float><<<dim3(kM / 64, 1, kBH), 256, 0, stream>>>(
      zfin, kM, sA2, w3, kDH, sQL, y, kDH, sQL, kM, e0);
  f32tob16_k<<<(kBH * kM * kDH + 255) / 256, 256, 0, stream>>>(y, ylb, kBH * kM * kDH);

  // ao = softmax(q @ k_l^T) @ y  (MFMA flash attention, merged layout)
  fattn_k<false><<<kBH * (kN / 64), 256, 0, stream>>>(q, klb, ylb, ao);

  // + depthwise conv residual (LDS-tiled)
  conv_add2_k<<<kBH * (kN / kCR), 256, 0, stream>>>(vv, convw_f, ao);

  // hbuf = ao @ WoutT^T + bout (MFMA, f32 out)
  EpiArgs ew = {}; ew.bias = bout_f;
  mgemm_k<EPI_BIAS_F32><<<dim3(kBN / 128, kD / 128, 1), 256, 0, stream>>>(ao, kHD, WoutT, kHD,
                                                                          hbuf, kD, kHD, ew);

  // LN2 materialized once as bf16 (d_out scratch); MLP1 = pure bf16 GEMM (+bias+GELU)
  ln2_k<<<kBN, 256, 0, stream>>>(hbuf, g2_f, be2_f, hln2);
  EpiArgs e1 = {}; e1.bias = b1_f; e1.obf = hidden;
  mgemm_k<EPI_GELU_BF16><<<dim3(kBN / 128, kD4 / 128, 1), 256, 0, stream>>>(
      hln2, kD, W1T, kD, nullptr, kD4, kD, e1);

  // MLP2 (+bias+residual -> flag-typed out)
  EpiArgs e2 = {}; e2.bias = b2_f; e2.res = hbuf; e2.ovoid = d_out; e2.flag = dflag;
  mgemm_k<EPI_RES_OUT><<<dim3(kBN / 128, kD / 128, 1), 256, 0, stream>>>(
      hidden, kD4, W2T, kD4, nullptr, kD, kD4, e2);
}

// Round 6
// 1406.867 us; speedup vs baseline: 2.6493x; 1.0321x over previous
//
#include <hip/hip_runtime.h>
#include <hip/hip_bf16.h>
#include <cmath>

#define DEV __device__ __forceinline__

namespace {

constexpr int kB = 8, kN = 4096, kD = 512, kH = 8, kDH = 64, kM = 256, kL = 16, kCK = 33;
constexpr int kBN = kB * kN;     // 32768
constexpr int kBH = kB * kH;     // 64
constexpr int kHD = kH * kDH;    // 512
constexpr int kD4 = 4 * kD;      // 2048
constexpr int kQKVC = 3 * kHD;   // 1536

typedef __attribute__((ext_vector_type(8))) short short8;
typedef __attribute__((ext_vector_type(4))) float f32x4;

DEV float toF(float x) { return x; }
DEV float toF(__hip_bfloat16 x) { return __bfloat162float(x); }
DEV __hip_bfloat16 f2b(float f) { return __float2bfloat16(f); }
DEV short f2s(float f) {
  __hip_bfloat16 h = __float2bfloat16(f);
  return *reinterpret_cast<short*>(&h);
}
DEV float us2f(unsigned short u) { return __uint_as_float((unsigned)u << 16); }
DEV unsigned short f2us(float f) {
  __hip_bfloat16 h = __float2bfloat16(f);
  return *reinterpret_cast<unsigned short*>(&h);
}

// async global->LDS, 16 B per lane; dest must be wave-linear (base + lane*16)
DEV void gload16(const void* g, void* l) {
  __builtin_amdgcn_global_load_lds(
      (const __attribute__((address_space(1))) unsigned*)g,
      (__attribute__((address_space(3))) unsigned*)l, 16, 0, 0);
}

DEV float waveSum(float v) {
#pragma unroll
  for (int o = 32; o > 0; o >>= 1) v += __shfl_down(v, o, 64);
  return v;
}
DEV float waveMax(float v) {
#pragma unroll
  for (int o = 32; o > 0; o >>= 1) v = fmaxf(v, __shfl_down(v, o, 64));
  return v;
}
DEV float blockSum(float v, float* sb) {
  v = waveSum(v);
  int lane = threadIdx.x & 63, w = threadIdx.x >> 6;
  __syncthreads();
  if (lane == 0) sb[w] = v;
  __syncthreads();
  return sb[0] + sb[1] + sb[2] + sb[3];
}
DEV float blockMax(float v, float* sb) {
  v = waveMax(v);
  int lane = threadIdx.x & 63, w = threadIdx.x >> 6;
  __syncthreads();
  if (lane == 0) sb[w] = v;
  __syncthreads();
  return fmaxf(fmaxf(sb[0], sb[1]), fmaxf(sb[2], sb[3]));
}

// ---------------- runtime dtype detection ----------------
__global__ __launch_bounds__(256) void detect_k(const unsigned* __restrict__ x,
                                                int* __restrict__ flag) {
  __shared__ int sc[4];
  int t = threadIdx.x;
  int cb = 0;
  for (int i = t; i < 4096; i += 256) {
    unsigned w = x[i];
    float b0 = __uint_as_float(w << 16);
    float b1 = __uint_as_float(w & 0xffff0000u);
    if (fabsf(b0) < 64.0f && (b0 == 0.0f || fabsf(b0) > 1e-20f)) cb++;
    if (fabsf(b1) < 64.0f && (b1 == 0.0f || fabsf(b1) > 1e-20f)) cb++;
  }
#pragma unroll
  for (int o = 32; o > 0; o >>= 1) cb += __shfl_down(cb, o, 64);
  if ((t & 63) == 0) sc[t >> 6] = cb;
  __syncthreads();
  if (t == 0) flag[0] = (sc[0] + sc[1] + sc[2] + sc[3] > 7373) ? 1 : 0;  // 1 = bf16 inputs
}

__global__ void cvt_any_k(const void* __restrict__ s, float* __restrict__ d, int n,
                          const int* __restrict__ flag) {
  int i = blockIdx.x * 256 + threadIdx.x;
  if (i >= n) return;
  if (*flag)
    d[i] = toF(((const __hip_bfloat16*)s)[i]);
  else
    d[i] = ((const float*)s)[i];
}

// weight [K][N] -> bf16 transposed [N][K]
__global__ void cvtT_k(const void* __restrict__ s, __hip_bfloat16* __restrict__ d, int K, int N,
                       const int* __restrict__ flag) {
  int i = blockIdx.x * 256 + threadIdx.x;
  if (i >= N * K) return;
  int n = i / K, k = i - n * K;
  float v = (*flag) ? toF(((const __hip_bfloat16*)s)[(long)k * N + n])
                    : ((const float*)s)[(long)k * N + n];
  d[i] = f2b(v);
}

__global__ void f32tob16_k(const float* __restrict__ s, __hip_bfloat16* __restrict__ d, int n) {
  int i = blockIdx.x * 256 + threadIdx.x;
  if (i < n) d[i] = f2b(s[i]);
}

// ---------------- LN kernels ----------------

__global__ __launch_bounds__(256) void ln1_k(const void* __restrict__ xv,
                                             const float* __restrict__ g,
                                             const float* __restrict__ be,
                                             __hip_bfloat16* __restrict__ o,
                                             const int* __restrict__ flag) {
  __shared__ float sb[4];
  size_t row = blockIdx.x;
  __hip_bfloat16* po = o + row * kD;
  int t = threadIdx.x;
  float v0, v1;
  if (*flag) {
    const __hip_bfloat16* pr = (const __hip_bfloat16*)xv + row * kD;
    v0 = toF(pr[t]);
    v1 = toF(pr[t + 256]);
  } else {
    const float* pr = (const float*)xv + row * kD;
    v0 = pr[t];
    v1 = pr[t + 256];
  }
  float s = blockSum(v0 + v1, sb);
  float ss = blockSum(v0 * v0 + v1 * v1, sb);
  float mu = s * (1.0f / kD);
  float var = ss * (1.0f / kD) - mu * mu;
  float rs = rsqrtf(var + 1e-5f);
  po[t] = f2b((v0 - mu) * rs * g[t] + be[t]);
  po[t + 256] = f2b((v1 - mu) * rs * g[t + 256] + be[t + 256]);
}

// LN2: f32 in -> bf16 out (materialized once; MLP1 consumes as plain bf16 GEMM A)
__global__ __launch_bounds__(256) void ln2_k(const float* __restrict__ x,
                                             const float* __restrict__ g,
                                             const float* __restrict__ be,
                                             __hip_bfloat16* __restrict__ o) {
  __shared__ float sb[4];
  size_t row = blockIdx.x;
  const float* pr = x + row * kD;
  __hip_bfloat16* po = o + row * kD;
  int t = threadIdx.x;
  float v0 = pr[t], v1 = pr[t + 256];
  float s = blockSum(v0 + v1, sb);
  float ss = blockSum(v0 * v0 + v1 * v1, sb);
  float mu = s * (1.0f / kD);
  float var = ss * (1.0f / kD) - mu * mu;
  float rs = rsqrtf(var + 1e-5f);
  po[t] = f2b((v0 - mu) * rs * g[t] + be[t]);
  po[t + 256] = f2b((v1 - mu) * rs * g[t + 256] + be[t + 256]);
}

// ---------------- small helpers ----------------

__global__ void landmark_k(const __hip_bfloat16* __restrict__ src, float* __restrict__ dst) {
  int i = blockIdx.x * 256 + threadIdx.x;
  if (i >= kBH * kM * kDH) return;
  int dh = i & 63, m = (i >> 6) & 255, bh = i >> 14;
  const __hip_bfloat16* p = src + ((size_t)bh * kN + m * kL) * kDH + dh;
  float s = 0.f;
#pragma unroll
  for (int l = 0; l < kL; ++l) s += toF(p[l * kDH]);
  dst[i] = s * (1.0f / kL);
}

__global__ __launch_bounds__(256) void softmax_k(float* __restrict__ X, int ncols) {
  __shared__ float sb[4];
  size_t row = blockIdx.x;
  float* p = X + row * ncols;
  int t = threadIdx.x;
  float mx = -1e30f;
  for (int c = t; c < ncols; c += 256) mx = fmaxf(mx, p[c]);
  mx = blockMax(mx, sb);
  float s = 0.f;
  for (int c = t; c < ncols; c += 256) {
    float e = expf(fminf(p[c] - mx, 0.0f));
    p[c] = e;
    s += e;
  }
  s = blockSum(s, sb);
  float inv = 1.0f / s;
  for (int c = t; c < ncols; c += 256) p[c] *= inv;
}

__global__ __launch_bounds__(256) void pinv_rowcol_k(const float* __restrict__ a2,
                                                     float* __restrict__ rsum,
                                                     float* __restrict__ csum) {
  __shared__ float sb[4];
  int bh = blockIdx.x >> 8, i = blockIdx.x & 255;
  const float* base = a2 + ((size_t)bh << 16);
  int t = threadIdx.x;
  float rs = blockSum(fabsf(base[i * kM + t]), sb);
  float cs = blockSum(fabsf(base[t * kM + i]), sb);
  if (t == 0) {
    rsum[blockIdx.x] = rs;
    csum[blockIdx.x] = cs;
  }
}

__global__ __launch_bounds__(256) void pinv_gmax_k(const float* __restrict__ rsum,
                                                   const float* __restrict__ csum,
                                                   float* __restrict__ gmax) {
  __shared__ float sb[4];
  int t = threadIdx.x;
  float a = 0.f, b = 0.f;
  for (int j = t; j < kBH * kM; j += 256) {
    a = fmaxf(a, rsum[j]);
    b = fmaxf(b, csum[j]);
  }
  a = blockMax(a, sb);
  b = blockMax(b, sb);
  if (t == 0) {
    gmax[0] = a;
    gmax[1] = b;
  }
}

// Z0 = a2^T * s (normal) and Z0^T = a2 * s (transposed copy for TRB consumption)
__global__ void pinv_init2_k(const float* __restrict__ a2, const float* __restrict__ gmax,
                             __hip_bfloat16* __restrict__ zn, __hip_bfloat16* __restrict__ zt) {
  int i = blockIdx.x * 256 + threadIdx.x;
  if (i >= kBH * kM * kM) return;
  int col = i & 255, r = (i >> 8) & 255, bh = i >> 16;
  float s = 1.0f / fmaxf(gmax[0] * gmax[1], 1e-30f);
  zn[i] = f2b(a2[((size_t)bh << 16) + col * kM + r] * s);
  zt[i] = f2b(a2[i] * s);
}

// ---------------- depthwise conv residual (LDS-tiled, vectorized) ----------------
constexpr int kCR = 128;            // output rows per block
constexpr int kCHA = kCK / 2;       // 16 halo
constexpr int kCW = kCR + 2 * kCHA; // 160 staged rows
constexpr int kCP = 72;             // LDS row stride in shorts

__global__ __launch_bounds__(256) void conv_add2_k(const __hip_bfloat16* __restrict__ v,
                                                   const float* __restrict__ w,
                                                   __hip_bfloat16* __restrict__ ao) {
  __shared__ short Vt[kCW * kCP];
  __shared__ float wsh[kCK];
  const int t = threadIdx.x;
  const int bh = blockIdx.x >> 5;            // kN / kCR = 32 segments
  const int n0 = (blockIdx.x & 31) * kCR;
  const int b = bh >> 3, h = bh & 7;
  if (t < kCK) wsh[t] = w[h * kCK + t];
  const __hip_bfloat16* vbase = v + (size_t)bh * kN * kDH;
#pragma unroll
  for (int u = 0; u < (kCW * 8 + 255) / 256; ++u) {
    const int idx = u * 256 + t;
    if (idx < kCW * 8) {
      const int r = idx >> 3, c8 = (idx & 7) * 8;
      const int n = n0 - kCHA + r;
      uint4 d = {0u, 0u, 0u, 0u};
      if (n >= 0 && n < kN) d = *(const uint4*)(vbase + (size_t)n * kDH + c8);
      *(uint4*)&Vt[r * kCP + c8] = d;
    }
  }
  __syncthreads();
  const int dh8 = (t & 7) * 8;
  const int rg = (t >> 3) * 4;               // 32 row-groups x 4 rows = 128
  float acc[4][8] = {};
#pragma unroll
  for (int wd = 0; wd < kCK + 3; ++wd) {     // 36-row sliding window
    short8 v8 = *(const short8*)&Vt[(rg + wd) * kCP + dh8];
    float f[8];
#pragma unroll
    for (int e = 0; e < 8; ++e) f[e] = us2f((unsigned short)v8[e]);
#pragma unroll
    for (int i = 0; i < 4; ++i) {
      const int tap = wd - i;
      if (tap >= 0 && tap < kCK) {
        const float wt = wsh[tap];
#pragma unroll
        for (int e = 0; e < 8; ++e) acc[i][e] = fmaf(f[e], wt, acc[i][e]);
      }
    }
  }
#pragma unroll
  for (int i = 0; i < 4; ++i) {
    const int n = n0 + rg + i;
    __hip_bfloat16* ap = ao + ((size_t)(b * kN + n)) * kHD + h * kDH + dh8;
    uint4 d = *(const uint4*)ap;
    const unsigned short* us = (const unsigned short*)&d;
    unsigned short ov[8];
#pragma unroll
    for (int e = 0; e < 8; ++e) ov[e] = f2us(us2f(us[e]) + acc[i][e]);
    *(uint4*)ap = *(const uint4*)ov;
  }
}

// ---------------- MFMA flash attention ----------------
// O = softmax(Q @ K^T) @ V, 64 Q-rows per block, KV tiles of 256, online softmax.
constexpr int FP = 72;  // LDS row pad in shorts (144 B stride: 16B-aligned, 2-way max on b128)

template <bool A3>  // true : attn3 — Q [bh][256][64], K/V [bh][4096][64], out w3 f32; grid kBH*4
                    // false: attn1 — Q [bh][4096][64], K/V [bh][256][64],
                    //        out ao bf16 scatter [b][n][h*64+dh]; grid kBH*64
__global__ __launch_bounds__(256, 1) void fattn_k(const __hip_bfloat16* __restrict__ Qp,
                                                  const __hip_bfloat16* __restrict__ Kp,
                                                  const __hip_bfloat16* __restrict__ Vp,
                                                  void* __restrict__ Op) {
  __shared__ __align__(16) char smem[111616];
  short* Ks = (short*)smem;                    // [256][FP]  36864 B
  short* Vs = (short*)(smem + 36864);          // [256][FP]  36864 B
  short* Ps = (short*)(smem + 73728);          // 4 x [64][FP] (per-wave P slab) 36864 B
  float* wred = (float*)(smem + 110592);       // [4][64] cross-wave max / lsum
  float* Comb = (float*)smem;                  // [4][64][64] f32 epilogue alias (64 KB)

  const int t = threadIdx.x;
  const int lane = t & 63, wave = t >> 6;
  const int l15 = lane & 15, quad = lane >> 4;
  const int bh = A3 ? (blockIdx.x >> 2) : (blockIdx.x >> 6);
  const int q0 = A3 ? ((blockIdx.x & 3) * 64) : ((blockIdx.x & 63) * 64);
  const int NTILES = A3 ? (kN / 256) : 1;
  short* Psw = Ps + wave * 64 * FP;

  // ---- Q fragments in registers ----
  short8 aq[4][2];
#pragma unroll
  for (int i = 0; i < 4; ++i) {
    const long qrow = (A3 ? ((long)bh * kM) : ((long)bh * kN)) + q0 + i * 16 + l15;
#pragma unroll
    for (int s = 0; s < 2; ++s)
      aq[i][s] = *(const short8*)(Qp + qrow * kDH + quad * 8 + s * 32);
  }

  f32x4 o[4][4] = {};
  float mrow[4][4], lrow[4][4];
#pragma unroll
  for (int i = 0; i < 4; ++i)
#pragma unroll
    for (int rg = 0; rg < 4; ++rg) {
      mrow[i][rg] = -1e30f;
      lrow[i][rg] = 0.f;
    }

  const long kvbase = (long)bh * (A3 ? kN : kM) * kDH;

  for (int tile = 0; tile < NTILES; ++tile) {
    // ---- stage K,V tile [256][64] -> LDS ----
    {
      const int r = t >> 2, c = (t & 3) * 16;
#pragma unroll
      for (int p = 0; p < 4; ++p) {
        const int rr = p * 64 + r;
        const long src = kvbase + (long)(tile * 256 + rr) * kDH + c;
        const uint4* ks = (const uint4*)(Kp + src);
        const uint4* vs = (const uint4*)(Vp + src);
        *(uint4*)&Ks[rr * FP + c] = ks[0];
        *(uint4*)&Ks[rr * FP + c + 8] = ks[1];
        *(uint4*)&Vs[rr * FP + c] = vs[0];
        *(uint4*)&Vs[rr * FP + c + 8] = vs[1];
      }
    }
    __syncthreads();

    // ---- S = Q @ K^T  (wave's 64x64 slab of the 64x256 tile) ----
    f32x4 sacc[4][4] = {};
#pragma unroll
    for (int s = 0; s < 2; ++s) {
      short8 bk[4];
#pragma unroll
      for (int j = 0; j < 4; ++j)
        bk[j] = *(const short8*)&Ks[(wave * 64 + j * 16 + l15) * FP + quad * 8 + s * 32];
#pragma unroll
      for (int i = 0; i < 4; ++i)
#pragma unroll
        for (int j = 0; j < 4; ++j)
          sacc[i][j] =
              __builtin_amdgcn_mfma_f32_16x16x32_bf16(aq[i][s], bk[j], sacc[i][j], 0, 0, 0);
    }

    // ---- per-row max: lane-local over j, then over l15 group, then cross-wave ----
    float pmax[4][4];
#pragma unroll
    for (int i = 0; i < 4; ++i)
#pragma unroll
      for (int rg = 0; rg < 4; ++rg) {
        float v = fmaxf(fmaxf(sacc[i][0][rg], sacc[i][1][rg]),
                        fmaxf(sacc[i][2][rg], sacc[i][3][rg]));
#pragma unroll
        for (int d = 1; d < 16; d <<= 1) v = fmaxf(v, __shfl_xor(v, d, 64));
        pmax[i][rg] = v;
      }
    if (l15 == 0) {
#pragma unroll
      for (int i = 0; i < 4; ++i)
#pragma unroll
        for (int rg = 0; rg < 4; ++rg)
          wred[wave * 64 + i * 16 + quad * 4 + rg] = pmax[i][rg];
    }
    __syncthreads();

    // ---- online rescale + exp + P repack (bf16, own-wave LDS slab) ----
#pragma unroll
    for (int i = 0; i < 4; ++i)
#pragma unroll
      for (int rg = 0; rg < 4; ++rg) {
        const int row = i * 16 + quad * 4 + rg;
        float tm =
            fmaxf(fmaxf(wred[row], wred[64 + row]), fmaxf(wred[128 + row], wred[192 + row]));
        float mn = fmaxf(mrow[i][rg], tm);
        float c = expf(mrow[i][rg] - mn);
        mrow[i][rg] = mn;
        lrow[i][rg] *= c;
#pragma unroll
        for (int j = 0; j < 4; ++j) o[i][j][rg] *= c;
      }
#pragma unroll
    for (int i = 0; i < 4; ++i)
#pragma unroll
      for (int rg = 0; rg < 4; ++rg) {
        float ls = 0.f;
#pragma unroll
        for (int j = 0; j < 4; ++j) {
          float e = expf(sacc[i][j][rg] - mrow[i][rg]);  // <= 0 exponent by construction
          ls += e;
          Psw[(i * 16 + quad * 4 + rg) * FP + j * 16 + l15] = f2s(e);
        }
#pragma unroll
        for (int d = 1; d < 16; d <<= 1) ls += __shfl_xor(ls, d, 64);
        lrow[i][rg] += ls;
      }

    // ---- O += P @ V ----
#pragma unroll
    for (int s = 0; s < 2; ++s) {
      short8 ap[4];
#pragma unroll
      for (int i = 0; i < 4; ++i)
        ap[i] = *(const short8*)&Psw[(i * 16 + l15) * FP + quad * 8 + s * 32];
      short8 bv[4];
#pragma unroll
      for (int j = 0; j < 4; ++j)
#pragma unroll
        for (int e = 0; e < 8; ++e)
          bv[j][e] = Vs[(wave * 64 + s * 32 + quad * 8 + e) * FP + j * 16 + l15];
#pragma unroll
      for (int i = 0; i < 4; ++i)
#pragma unroll
        for (int j = 0; j < 4; ++j)
          o[i][j] = __builtin_amdgcn_mfma_f32_16x16x32_bf16(ap[i], bv[j], o[i][j], 0, 0, 0);
    }
    __syncthreads();
  }

  // ---- cross-wave combine: O = sum_w O_w, l = sum_w l_w; write out ----
#pragma unroll
  for (int i = 0; i < 4; ++i)
#pragma unroll
    for (int j = 0; j < 4; ++j)
#pragma unroll
      for (int rg = 0; rg < 4; ++rg)
        Comb[wave * 4096 + (i * 16 + quad * 4 + rg) * 64 + j * 16 + l15] = o[i][j][rg];
  if (l15 == 0) {
#pragma unroll
    for (int i = 0; i < 4; ++i)
#pragma unroll
      for (int rg = 0; rg < 4; ++rg)
        wred[wave * 64 + i * 16 + quad * 4 + rg] = lrow[i][rg];
  }
  __syncthreads();
#pragma unroll
  for (int u = 0; u < 16; ++u) {
    const int idx = u * 256 + t;
    const int row = idx >> 6, dh = idx & 63;
    float v = Comb[idx] + Comb[4096 + idx] + Comb[8192 + idx] + Comb[12288 + idx];
    float linv = 1.0f / (wred[row] + wred[64 + row] + wred[128 + row] + wred[192 + row]);
    if constexpr (A3) {
      ((float*)Op)[((size_t)bh * kM + q0 + row) * kDH + dh] = v * linv;
    } else {
      const int b = bh >> 3, h = bh & 7;
      ((__hip_bfloat16*)Op)[((size_t)(b * kN + q0 + row)) * kHD + h * kDH + dh] =
          f2b(v * linv);
    }
  }
}

// ---------------- epilogue / arg pack ----------------
constexpr int EPI_QKV = 1, EPI_BIAS_F32 = 2, EPI_GELU_BF16 = 3, EPI_RES_OUT = 4;
constexpr int EPI_F32 = 0;

struct EpiArgs {
  const float* bias;
  const float* res;
  __hip_bfloat16* oq;
  __hip_bfloat16* ok;
  __hip_bfloat16* ov;
  __hip_bfloat16* obf;
  void* ovoid;
  const int* flag;
};

// ---------------- MFMA bf16 GEMM: 128x128 tile, BK=32, 4 waves, TRB only ----------------
// Double-buffered prefetch (T3-minimum): issue next K-step's global_load_lds before
// computing current; single barrier per K-step (compiler's vmcnt(0) at barrier waits
// on loads that were in flight during the whole MFMA window).
template <int EPI>
__global__ __launch_bounds__(256) void mgemm_k(const __hip_bfloat16* __restrict__ A, int lda,
                                               const __hip_bfloat16* __restrict__ B, int ldb,
                                               float* __restrict__ C, int ldc, int K,
                                               EpiArgs ep) {
  __shared__ short As[2][128 * 32];
  __shared__ short Bs[2][128 * 32];
  const int row0 = blockIdx.x * 128, col0 = blockIdx.y * 128;
  const int t = threadIdx.x;
  const int lane = t & 63, wave = t >> 6;
  const int wr = (wave >> 1) * 64, wc = (wave & 1) * 64;
  const int l15 = lane & 15, quad = lane >> 4;
  const int kc = (t & 3) * 8, mr = t >> 2;
  f32x4 acc[4][4] = {};
  // prologue: stage K-step 0 into buffer 0
#pragma unroll
  for (int p = 0; p < 2; ++p) {
    const int m = p * 64 + mr;
    gload16(A + (long)(row0 + m) * lda + kc, &As[0][p * 2048 + t * 8]);
    gload16(B + (long)(col0 + m) * ldb + kc, &Bs[0][p * 2048 + t * 8]);
  }
  __syncthreads();
  int cur = 0;
  for (int k0 = 0; k0 < K; k0 += 32) {
    if (k0 + 32 < K) {
#pragma unroll
      for (int p = 0; p < 2; ++p) {
        const int m = p * 64 + mr;
        gload16(A + (long)(row0 + m) * lda + k0 + 32 + kc, &As[cur ^ 1][p * 2048 + t * 8]);
        gload16(B + (long)(col0 + m) * ldb + k0 + 32 + kc, &Bs[cur ^ 1][p * 2048 + t * 8]);
      }
    }
    short8 af[4], bf[4];
#pragma unroll
    for (int i = 0; i < 4; ++i)
      af[i] = *(const short8*)(&As[cur][(wr + i * 16 + l15) * 32 + quad * 8]);
#pragma unroll
    for (int j = 0; j < 4; ++j)
      bf[j] = *(const short8*)(&Bs[cur][(wc + j * 16 + l15) * 32 + quad * 8]);
#pragma unroll
    for (int i = 0; i < 4; ++i)
#pragma unroll
      for (int j = 0; j < 4; ++j)
        acc[i][j] = __builtin_amdgcn_mfma_f32_16x16x32_bf16(af[i], bf[j], acc[i][j], 0, 0, 0);
    __syncthreads();
    cur ^= 1;
  }
  // ---- epilogue (C/D: col=lane&15, row=quad*4+reg) ----
#pragma unroll
  for (int i = 0; i < 4; ++i) {
#pragma unroll
    for (int j = 0; j < 4; ++j) {
#pragma unroll
      for (int rg = 0; rg < 4; ++rg) {
        int r = row0 + wr + i * 16 + quad * 4 + rg;
        int c = col0 + wc + j * 16 + l15;
        float v = acc[i][j][rg];
        if (EPI == EPI_QKV) {
          int three = c >> 9, h = (c >> 6) & 7, dh = c & 63;
          int b = r >> 12, n = r & (kN - 1);
          long dst = ((long)(b * kH + h) * kN + n) * kDH + dh;
          if (three == 0)
            ep.oq[dst] = f2b(v * 0.125f);
          else if (three == 1)
            ep.ok[dst] = f2b(v);
          else
            ep.ov[dst] = f2b(v);
        } else if (EPI == EPI_BIAS_F32) {
          C[(long)r * ldc + c] = v + ep.bias[c];
        } else if (EPI == EPI_GELU_BF16) {
          v += ep.bias[c];
          ep.obf[(long)r * ldc + c] =
              f2b(0.5f * v * (1.0f + erff(v * 0.70710678118654752f)));
        } else if (EPI == EPI_RES_OUT) {
          long idx = (long)r * ldc + c;
          float v2 = v + ep.bias[c] + ep.res[idx];
          if (!(v2 == v2)) v2 = 0.0f;
          if (*ep.flag)
            ((__hip_bfloat16*)ep.ovoid)[idx] = f2b(v2);
          else
            ((float*)ep.ovoid)[idx] = v2;
        }
      }
    }
  }
}

// ---------------- pinv MFMA GEMM: C = A @ Bst^T, batched over bh ----------------
// Double-buffered prefetch K-loop; transpose buffer aliases staging LDS (dead after loop).
// Outputs: optional normal C*oscl (bf16), and always the eye-transposed
//   Ct[c][r] = ((r==c)*eyeC - C[r][c]) * eyeS   (coalesced via LDS transpose).
template <bool WN>
__global__ __launch_bounds__(256) void mgemmT_k(const __hip_bfloat16* __restrict__ A,
                                                const __hip_bfloat16* __restrict__ B,
                                                __hip_bfloat16* __restrict__ Cn,
                                                __hip_bfloat16* __restrict__ Ct,
                                                float eyeC, float eyeS, float oscl) {
  constexpr int TS = 136;  // transpose buffer row stride (shorts)
  __shared__ __align__(16) short sm[128 * TS];  // 34816 B (staging 32 KB aliased inside)
  short* As0 = sm;
  short* As1 = sm + 4096;
  short* Bs0 = sm + 8192;
  short* Bs1 = sm + 12288;
  const long mbase = (long)blockIdx.z * ((long)kM * kM);
  const int row0 = blockIdx.x * 128, col0 = blockIdx.y * 128;
  const int t = threadIdx.x;
  const int lane = t & 63, wave = t >> 6;
  const int wr = (wave >> 1) * 64, wc = (wave & 1) * 64;
  const int l15 = lane & 15, quad = lane >> 4;
  const int kc = (t & 3) * 8, mr = t >> 2;
  short* Asb[2] = {As0, As1};
  short* Bsb[2] = {Bs0, Bs1};
  f32x4 acc[4][4] = {};
#pragma unroll
  for (int p = 0; p < 2; ++p) {
    const int m = p * 64 + mr;
    gload16(A + mbase + (long)(row0 + m) * kM + kc, &As0[p * 2048 + t * 8]);
    gload16(B + mbase + (long)(col0 + m) * kM + kc, &Bs0[p * 2048 + t * 8]);
  }
  __syncthreads();
  int cur = 0;
  for (int k0 = 0; k0 < kM; k0 += 32) {
    if (k0 + 32 < kM) {
#pragma unroll
      for (int p = 0; p < 2; ++p) {
        const int m = p * 64 + mr;
        gload16(A + mbase + (long)(row0 + m) * kM + k0 + 32 + kc,
                &Asb[cur ^ 1][p * 2048 + t * 8]);
        gload16(B + mbase + (long)(col0 + m) * kM + k0 + 32 + kc,
                &Bsb[cur ^ 1][p * 2048 + t * 8]);
      }
    }
    short8 af[4], bf[4];
#pragma unroll
    for (int i = 0; i < 4; ++i)
      af[i] = *(const short8*)(&Asb[cur][(wr + i * 16 + l15) * 32 + quad * 8]);
#pragma unroll
    for (int j = 0; j < 4; ++j)
      bf[j] = *(const short8*)(&Bsb[cur][(wc + j * 16 + l15) * 32 + quad * 8]);
#pragma unroll
    for (int i = 0; i < 4; ++i)
#pragma unroll
      for (int j = 0; j < 4; ++j)
        acc[i][j] = __builtin_amdgcn_mfma_f32_16x16x32_bf16(af[i], bf[j], acc[i][j], 0, 0, 0);
    __syncthreads();
    cur ^= 1;
  }
  // optional normal write
  if (WN) {
#pragma unroll
    for (int i = 0; i < 4; ++i)
#pragma unroll
      for (int j = 0; j < 4; ++j)
#pragma unroll
        for (int rg = 0; rg < 4; ++rg) {
          int r = row0 + wr + i * 16 + quad * 4 + rg;
          int c = col0 + wc + j * 16 + l15;
          Cn[mbase + (long)r * kM + c] = f2b(acc[i][j][rg] * oscl);
        }
  }
  // eye-transform + transpose deposit (packed b64: rg 0..3 contiguous along rl axis)
#pragma unroll
  for (int i = 0; i < 4; ++i)
#pragma unroll
    for (int j = 0; j < 4; ++j) {
      const int rl0 = wr + i * 16 + quad * 4;
      const int cl = wc + j * 16 + l15;
      const int r0 = row0 + rl0, c = col0 + cl;
      short pk[4];
#pragma unroll
      for (int rg = 0; rg < 4; ++rg) {
        float v = (((r0 + rg) == c) ? eyeC : 0.0f) - acc[i][j][rg];
        pk[rg] = f2s(v * eyeS);
      }
      *(ulong1*)&sm[cl * TS + rl0] = *(const ulong1*)pk;
    }
  __syncthreads();
#pragma unroll
  for (int u = 0; u < 8; ++u) {
    const int rowt = u * 16 + (t >> 4);   // row of C^T tile (= col of C), 0..127
    const int c8 = (t & 15) * 8;          // along r axis
    uint4 d = *(const uint4*)&sm[rowt * TS + c8];
    *(uint4*)(Ct + mbase + (long)(col0 + rowt) * kM + row0 + c8) = d;
  }
}

// ---------------- fp32 vector GEMM (for small/odd shapes: sim2, y) ----------------
template <int EPI, bool TRB, class TAT, class TBT>
__global__ __launch_bounds__(256) void gemm_k(const TAT* __restrict__ A, int lda, long sA,
                                              const TBT* __restrict__ B, int ldb, long sB,
                                              float* __restrict__ C, int ldc, long sC, int K,
                                              EpiArgs ep) {
  __shared__ float As[16][68];
  __shared__ float Bs[16][68];
  A += (long)blockIdx.z * sA;
  B += (long)blockIdx.z * sB;
  const long cbase = (long)blockIdx.z * sC;
  const int row0 = blockIdx.x * 64, col0 = blockIdx.y * 64;
  const int t = threadIdx.x;
  const int ty = t >> 4, tx = t & 15;
  float acc[4][4] = {{0.f, 0.f, 0.f, 0.f}, {0.f, 0.f, 0.f, 0.f},
                     {0.f, 0.f, 0.f, 0.f}, {0.f, 0.f, 0.f, 0.f}};
  const int ka = t & 15, ra = t >> 4;
  for (int k0 = 0; k0 < K; k0 += 16) {
#pragma unroll
    for (int j = 0; j < 4; ++j)
      As[ka][ra + 16 * j] = toF(A[(long)(row0 + ra + 16 * j) * lda + (k0 + ka)]);
    if (TRB) {
#pragma unroll
      for (int j = 0; j < 4; ++j)
        Bs[ka][ra + 16 * j] = toF(B[(long)(col0 + ra + 16 * j) * ldb + (k0 + ka)]);
    } else {
      const int jb = t & 63, kb = t >> 6;
#pragma unroll
      for (int j = 0; j < 4; ++j)
        Bs[kb + 4 * j][jb] = toF(B[(long)(k0 + kb + 4 * j) * ldb + (col0 + jb)]);
    }
    __syncthreads();
#pragma unroll
    for (int kk = 0; kk < 16; ++kk) {
      float av[4], bv[4];
#pragma unroll
      for (int i = 0; i < 4; ++i) av[i] = As[kk][ty * 4 + i];
#pragma unroll
      for (int j = 0; j < 4; ++j) bv[j] = Bs[kk][tx * 4 + j];
#pragma unroll
      for (int i = 0; i < 4; ++i)
#pragma unroll
        for (int j = 0; j < 4; ++j) acc[i][j] += av[i] * bv[j];
    }
    __syncthreads();
  }
#pragma unroll
  for (int i = 0; i < 4; ++i) {
    int r = row0 + ty * 4 + i;
#pragma unroll
    for (int j = 0; j < 4; ++j) {
      int c = col0 + tx * 4 + j;
      C[cbase + (long)r * ldc + c] = acc[i][j];
    }
  }
}

}  // namespace

extern "C" void kernel_launch(void* const* d_in, const int* in_sizes, int n_in, void* d_out,
                              int out_size, void* d_ws, size_t ws_size, hipStream_t stream) {
  (void)in_sizes; (void)n_in; (void)out_size;

  char* base = (char*)d_ws;
  size_t off = 0;
  auto alloc = [&](size_t bytes) {
    char* p = base + off;
    off = (off + bytes + 255) & ~(size_t)255;
    return p;
  };
  const size_t kMat = (size_t)kBH * kM * kM;  // elements per pinv matrix set
  float* a2 = (float*)alloc(kMat * 4);        // 16.78 MB
  __hip_bfloat16* mb0 = (__hip_bfloat16*)alloc(kMat * 2 * 8);  // 8 bf16 matrix sets, 67.1 MB
  __hip_bfloat16* a2b = (__hip_bfloat16*)alloc(kMat * 2);      // 8.39 MB
  // bf16 qkv + attn-out region (hosts MLP hidden late: 134.2 MB contiguous)
  __hip_bfloat16* q = (__hip_bfloat16*)alloc((size_t)kBH * kN * kDH * 2);
  __hip_bfloat16* kk = (__hip_bfloat16*)alloc((size_t)kBH * kN * kDH * 2);
  __hip_bfloat16* vv = (__hip_bfloat16*)alloc((size_t)kBH * kN * kDH * 2);
  __hip_bfloat16* ao = (__hip_bfloat16*)alloc((size_t)kBN * kHD * 2);
  float* ql = (float*)alloc((size_t)kBH * kM * kDH * 4);
  float* kl = (float*)alloc((size_t)kBH * kM * kDH * 4);
  float* w3 = (float*)alloc((size_t)kBH * kM * kDH * 4);
  float* y = (float*)alloc((size_t)kBH * kM * kDH * 4);
  float* rsum = (float*)alloc((size_t)kBH * kM * 4);
  float* csum = (float*)alloc((size_t)kBH * kM * 4);
  float* gmax = (float*)alloc(256);
  int* dflag = (int*)alloc(256);
  // transposed bf16 weights
  __hip_bfloat16* WqkvT = (__hip_bfloat16*)alloc((size_t)kQKVC * kD * 2);
  __hip_bfloat16* WoutT = (__hip_bfloat16*)alloc((size_t)kD * kHD * 2);
  __hip_bfloat16* W1T = (__hip_bfloat16*)alloc((size_t)kD4 * kD * 2);
  __hip_bfloat16* W2T = (__hip_bfloat16*)alloc((size_t)kD * kD4 * 2);
  float* bout_f = (float*)alloc(kD * 4);
  float* b1_f = (float*)alloc(kD4 * 4);
  float* b2_f = (float*)alloc(kD * 4);
  float* convw_f = (float*)alloc(kH * kCK * 4);
  float* g1_f = (float*)alloc(kD * 4);
  float* be1_f = (float*)alloc(kD * 4);
  float* g2_f = (float*)alloc(kD * 4);
  float* be2_f = (float*)alloc(kD * 4);
  auto mb = [&](int i) { return mb0 + (size_t)i * kMat; };
  // lifetime-disjoint aliases
  __hip_bfloat16* hln = (__hip_bfloat16*)a2;  // LN1 out 33.5MB: a2+mb0+mb1, dead pre-sim2
  float* hbuf = a2;                           // Wout out f32 67.1MB: a2+mb0..mb5
  __hip_bfloat16* hidden = q;                 // MLP hidden bf16 134.2MB, spans q..ao
  // bf16 copies of ql/kl/y for fattn, in a2b (a2b dead after last pinv iter's 1st GEMM)
  __hip_bfloat16* qlb = a2b;
  __hip_bfloat16* klb = a2b + (size_t)kBH * kM * kDH;
  __hip_bfloat16* ylb = a2b + 2 * (size_t)kBH * kM * kDH;
  // LN2 bf16 output: d_out is free scratch until MLP2's final write (>= 33.5 MB)
  __hip_bfloat16* hln2 = (__hip_bfloat16*)d_out;

  if (off > ws_size) return;  // deterministic guard

  detect_k<<<1, 256, 0, stream>>>((const unsigned*)d_in[0], dflag);

  auto cvt = [&](const void* src, float* dst, int n) {
    cvt_any_k<<<(n + 255) / 256, 256, 0, stream>>>(src, dst, n, dflag);
  };
  cvtT_k<<<(kD * kQKVC + 255) / 256, 256, 0, stream>>>(d_in[1], WqkvT, kD, kQKVC, dflag);
  cvtT_k<<<(kHD * kD + 255) / 256, 256, 0, stream>>>(d_in[2], WoutT, kHD, kD, dflag);
  cvtT_k<<<(kD * kD4 + 255) / 256, 256, 0, stream>>>(d_in[9], W1T, kD, kD4, dflag);
  cvtT_k<<<(kD4 * kD + 255) / 256, 256, 0, stream>>>(d_in[11], W2T, kD4, kD, dflag);
  cvt(d_in[3], bout_f, kD);
  cvt(d_in[4], convw_f, kH * kCK);
  cvt(d_in[5], g1_f, kD);
  cvt(d_in[6], be1_f, kD);
  cvt(d_in[7], g2_f, kD);
  cvt(d_in[8], be2_f, kD);
  cvt(d_in[10], b1_f, kD4);
  cvt(d_in[12], b2_f, kD);

  EpiArgs e0 = {};

  // LN1 -> hln (bf16)
  ln1_k<<<kBN, 256, 0, stream>>>(d_in[0], g1_f, be1_f, hln, dflag);

  // QKV: hln @ WqkvT^T (MFMA, scatter epilogue)
  EpiArgs eq = {};
  eq.oq = q; eq.ok = kk; eq.ov = vv;
  mgemm_k<EPI_QKV><<<dim3(kBN / 128, kQKVC / 128, 1), 256, 0, stream>>>(hln, kD, WqkvT, kD,
                                                                        nullptr, 0, kD, eq);

  landmark_k<<<(kBH * kM * kDH + 255) / 256, 256, 0, stream>>>(q, ql);
  landmark_k<<<(kBH * kM * kDH + 255) / 256, 256, 0, stream>>>(kk, kl);

  const long sQL = (long)kM * kDH, sA2 = (long)kM * kM;

  // sim2 = q_l @ k_l^T (f32) ; softmax
  gemm_k<EPI_F32, true, float, float><<<dim3(kM / 64, kM / 64, kBH), 256, 0, stream>>>(
      ql, kDH, sQL, kl, kDH, sQL, a2, kM, sA2, kDH, e0);
  softmax_k<<<kBH * kM, 256, 0, stream>>>(a2, kM);

  // pinv setup
  f32tob16_k<<<((int)kMat + 255) / 256, 256, 0, stream>>>(a2, a2b, (int)kMat);
  pinv_rowcol_k<<<kBH * kM, 256, 0, stream>>>(a2, rsum, csum);
  pinv_gmax_k<<<1, 256, 0, stream>>>(rsum, csum, gmax);
  pinv_init2_k<<<((int)kMat + 255) / 256, 256, 0, stream>>>(a2, gmax, mb(0), mb(1));

  // Newton-Schulz, transposed chain: every B-operand consumed as [N][K] via TRB.
  // Producers emit (eyeC*I - C)^T * eyeS for the next consumer (eye fused at write).
  {
    __hip_bfloat16 *Zc = mb(0), *ZcT = mb(1), *Zn = mb(6), *ZnT = mb(7);
    __hip_bfloat16 *T1 = mb(2), *T1E = mb(3), *T3E = mb(4), *P3E = mb(5);
    dim3 gP(kM / 128, kM / 128, kBH);
    for (int it = 0; it < 6; ++it) {
      // T1 = a2 @ Z ; also emit (7I - T1)^T
      mgemmT_k<true><<<gP, 256, 0, stream>>>(a2b, ZcT, T1, T1E, 7.0f, 1.0f, 1.0f);
      // T3 = T1 @ (7I - T1) ; emit only (15I - T3)^T
      mgemmT_k<false><<<gP, 256, 0, stream>>>(T1, T1E, nullptr, T3E, 15.0f, 1.0f, 1.0f);
      // P3 = T1 @ (15I - T3) ; emit only (13I - P3)^T
      mgemmT_k<false><<<gP, 256, 0, stream>>>(T1, T3E, nullptr, P3E, 13.0f, 1.0f, 1.0f);
      // Znext = 0.25 * Z @ (13I - P3) ; emit Znext and Znext^T
      mgemmT_k<true><<<gP, 256, 0, stream>>>(Zc, P3E, Zn, ZnT, 0.0f, -0.25f, 0.25f);
      __hip_bfloat16* tp;
      tp = Zc; Zc = Zn; Zn = tp;
      tp = ZcT; ZcT = ZnT; ZnT = tp;
    }
    // after 6 iters (even number of swaps) Zc == mb(0)
  }
  __hip_bfloat16* zfin = mb(0);

  // bf16 copies for fattn (a2b now dead)
  f32tob16_k<<<(kBH * kM * kDH + 255) / 256, 256, 0, stream>>>(ql, qlb, kBH * kM * kDH);
  f32tob16_k<<<(kBH * kM * kDH + 255) / 256, 256, 0, stream>>>(kl, klb, kBH * kM * kDH);

  // w3 = softmax(q_l @ k^T) @ v  (MFMA flash attention)
  fattn_k<true><<<kBH * (kM / 64), 256, 0, stream>>>(qlb, kk, vv, w3);

  // y = z @ w3 (f32 vector gemm; N=64)
  gemm_k<EPI_F32, false, __hip_bfloat16, float><<<dim3(kM / 64, 1, kBH), 256, 0, stream>>>(
      zfin, kM, sA2, w3, kDH, sQL, y, kDH, sQL, kM, e0);
  f32tob16_k<<<(kBH * kM * kDH + 255) / 256, 256, 0, stream>>>(y, ylb, kBH * kM * kDH);

  // ao = softmax(q @ k_l^T) @ y  (MFMA flash attention, merged layout)
  fattn_k<false><<<kBH * (kN / 64), 256, 0, stream>>>(q, klb, ylb, ao);

  // + depthwise conv residual (LDS-tiled)
  conv_add2_k<<<kBH * (kN / kCR), 256, 0, stream>>>(vv, convw_f, ao);

  // hbuf = ao @ WoutT^T + bout (MFMA, f32 out)
  EpiArgs ew = {}; ew.bias = bout_f;
  mgemm_k<EPI_BIAS_F32><<<dim3(kBN / 128, kD / 128, 1), 256, 0, stream>>>(ao, kHD, WoutT, kHD,
                                                                          hbuf, kD, kHD, ew);

  // LN2 materialized once as bf16 (d_out scratch); MLP1 = pure bf16 GEMM (+bias+GELU)
  ln2_k<<<kBN, 256, 0, stream>>>(hbuf, g2_f, be2_f, hln2);
  EpiArgs e1 = {}; e1.bias = b1_f; e1.obf = hidden;
  mgemm_k<EPI_GELU_BF16><<<dim3(kBN / 128, kD4 / 128, 1), 256, 0, stream>>>(
      hln2, kD, W1T, kD, nullptr, kD4, kD, e1);

  // MLP2 (+bias+residual -> flag-typed out)
  EpiArgs e2 = {}; e2.bias = b2_f; e2.res = hbuf; e2.ovoid = d_out; e2.flag = dflag;
  mgemm_k<EPI_RES_OUT><<<dim3(kBN / 128, kD / 128, 1), 256, 0, stream>>>(
      hidden, kD4, W2T, kD4, nullptr, kD, kD4, e2);
}